// Round 1
// baseline (731.011 us; speedup 1.0000x reference)
//
#include <hip/hip_runtime.h>
#include <stdint.h>

#define N 2048
#define DIN 128
#define H 64
#define OUTD 7

__device__ __forceinline__ float leaky(float x){ return x > 0.f ? x : 0.1f*x; }

__device__ __forceinline__ float waveRedSum(float v){
  #pragma unroll
  for (int o = 32; o > 0; o >>= 1) v += __shfl_xor(v, o, 64);
  return v;
}

__device__ __forceinline__ unsigned long long shflx64(unsigned long long v, int m){
  unsigned int lo = (unsigned int)v, hi = (unsigned int)(v >> 32);
  lo = (unsigned int)__shfl_xor((int)lo, m, 64);
  hi = (unsigned int)__shfl_xor((int)hi, m, 64);
  return ((unsigned long long)hi << 32) | lo;
}

// ---------- row sums of A -> dA = (rowsum + 1e-10)^-0.5 ----------
__global__ void k_rowsum(const float* __restrict__ A, float* __restrict__ dA){
  int i = blockIdx.x;
  const float4* row = (const float4*)(A + (size_t)i * N);
  float s = 0.f;
  for (int u = threadIdx.x; u < N/4; u += 256){
    float4 v = row[u];
    s += v.x + v.y + v.z + v.w;
  }
  __shared__ float red[4];
  s = waveRedSum(s);
  int wid = threadIdx.x >> 6, lane = threadIdx.x & 63;
  if (lane == 0) red[wid] = s;
  __syncthreads();
  if (threadIdx.x == 0){
    float t = red[0] + red[1] + red[2] + red[3];
    dA[i] = 1.0f / sqrtf(t + 1e-10f);
  }
}

// ---------- h = leaky(x @ W1^T + b1); also sq, hsum, hs = dA*h ----------
__global__ void k_h(const float* __restrict__ x, const float* __restrict__ W1,
                    const float* __restrict__ b1, const float* __restrict__ dA,
                    float* __restrict__ h, float* __restrict__ hs,
                    float* __restrict__ sq, float* __restrict__ hsum){
  int i = blockIdx.x, t = threadIdx.x;
  __shared__ float xr[DIN];
  xr[t]      = x[(size_t)i*DIN + t];
  xr[t + 64] = x[(size_t)i*DIN + t + 64];
  __syncthreads();
  float acc = b1[t];
  const float4* w  = (const float4*)(W1 + (size_t)t*DIN);
  const float4* xv = (const float4*)xr;
  #pragma unroll
  for (int c = 0; c < DIN/4; c++){
    float4 a = xv[c], b = w[c];
    acc += a.x*b.x + a.y*b.y + a.z*b.z + a.w*b.w;
  }
  float hv = leaky(acc);
  h [(size_t)i*H + t] = hv;
  hs[(size_t)i*H + t] = dA[i]*hv;
  float s2 = waveRedSum(hv*hv);
  float s1 = waveRedSum(hv);
  if (t == 0){ sq[i] = s2; hsum[i] = s1; }
}

// ---------- DOT = h @ h^T  (128x128 tile, 8x8 per thread, K=64) ----------
__global__ __launch_bounds__(256) void k_gram(const float* __restrict__ h,
                                              float* __restrict__ DOT){
  __shared__ float at[32][132];
  __shared__ float bt[32][132];
  int bi = blockIdx.x, bj = blockIdx.y;
  int tid = threadIdx.x;
  int rg = tid >> 4, cg = tid & 15;
  float acc[8][8] = {};
  for (int kc = 0; kc < 64; kc += 32){
    for (int u = tid; u < 1024; u += 256){
      int row = u >> 3, k4 = u & 7;
      float4 v = *(const float4*)(h + (size_t)(bi*128 + row)*H + kc + k4*4);
      at[k4*4+0][row] = v.x; at[k4*4+1][row] = v.y;
      at[k4*4+2][row] = v.z; at[k4*4+3][row] = v.w;
    }
    for (int u = tid; u < 1024; u += 256){
      int row = u >> 3, k4 = u & 7;
      float4 v = *(const float4*)(h + (size_t)(bj*128 + row)*H + kc + k4*4);
      bt[k4*4+0][row] = v.x; bt[k4*4+1][row] = v.y;
      bt[k4*4+2][row] = v.z; bt[k4*4+3][row] = v.w;
    }
    __syncthreads();
    for (int k = 0; k < 32; k++){
      float a[8], b[8];
      *(float4*)&a[0] = *(const float4*)&at[k][rg*8];
      *(float4*)&a[4] = *(const float4*)&at[k][rg*8+4];
      *(float4*)&b[0] = *(const float4*)&bt[k][cg*8];
      *(float4*)&b[4] = *(const float4*)&bt[k][cg*8+4];
      #pragma unroll
      for (int ii = 0; ii < 8; ii++)
        #pragma unroll
        for (int jj = 0; jj < 8; jj++)
          acc[ii][jj] += a[ii]*b[jj];
    }
    __syncthreads();
  }
  #pragma unroll
  for (int ii = 0; ii < 8; ii++){
    int r = bi*128 + rg*8 + ii;
    float* out = DOT + (size_t)r*N + bj*128 + cg*8;
    *(float4*)(out)   = make_float4(acc[ii][0], acc[ii][1], acc[ii][2], acc[ii][3]);
    *(float4*)(out+4) = make_float4(acc[ii][4], acc[ii][5], acc[ii][6], acc[ii][7]);
  }
}

// ---------- per-row top-4 of heat kernel (min of sq_j - 2*dot), + cos vals ----------
__global__ __launch_bounds__(256) void k_topk(const float* __restrict__ DOT,
      const float* __restrict__ sq, const float* __restrict__ hsum,
      int* __restrict__ nidx, float* __restrict__ ncos){
  int i = blockIdx.x, tid = threadIdx.x;
  __shared__ unsigned long long cand[1024];
  const float4* row = (const float4*)(DOT + (size_t)i * N);
  const float4* sq4 = (const float4*)sq;
  unsigned long long best[4] = {~0ULL, ~0ULL, ~0ULL, ~0ULL};
  #pragma unroll
  for (int blk = 0; blk < 2; blk++){
    int u = tid + blk*256;
    float4 d = row[u];
    float4 s = sq4[u];
    float kv[4] = { s.x - 2.f*d.x, s.y - 2.f*d.y, s.z - 2.f*d.z, s.w - 2.f*d.w };
    #pragma unroll
    for (int e = 0; e < 4; e++){
      unsigned int j = (unsigned int)(u*4 + e);
      unsigned int uk = __float_as_uint(kv[e]);
      uk = (uk & 0x80000000u) ? ~uk : (uk | 0x80000000u);
      unsigned long long c = ((unsigned long long)uk << 32) | j;
      if (c < best[3]){
        best[3] = c;
        unsigned long long t0;
        if (best[3] < best[2]){ t0 = best[2]; best[2] = best[3]; best[3] = t0; }
        if (best[2] < best[1]){ t0 = best[1]; best[1] = best[2]; best[2] = t0; }
        if (best[1] < best[0]){ t0 = best[0]; best[0] = best[1]; best[1] = t0; }
      }
    }
  }
  // lane-major candidate layout to avoid LDS bank collisions in merge
  #pragma unroll
  for (int e = 0; e < 4; e++) cand[e*256 + tid] = best[e];
  __syncthreads();
  if (tid < 64){
    unsigned long long loc[16];
    #pragma unroll
    for (int e = 0; e < 16; e++) loc[e] = cand[e*64 + tid];
    unsigned long long w0=~0ULL, w1=~0ULL, w2=~0ULL, w3=~0ULL;
    #pragma unroll
    for (int r = 0; r < 4; r++){
      unsigned long long m = loc[0];
      #pragma unroll
      for (int e = 1; e < 16; e++) m = (loc[e] < m) ? loc[e] : m;
      unsigned long long g = m;
      #pragma unroll
      for (int o = 32; o > 0; o >>= 1){
        unsigned long long other = shflx64(g, o);
        if (other < g) g = other;
      }
      #pragma unroll
      for (int e = 0; e < 16; e++) if (loc[e] == g) loc[e] = ~0ULL;
      if (r == 0) w0 = g; else if (r == 1) w1 = g; else if (r == 2) w2 = g; else w3 = g;
    }
    if (tid < 4){
      unsigned long long w = (tid==0) ? w0 : (tid==1) ? w1 : (tid==2) ? w2 : w3;
      unsigned int j = (unsigned int)w;
      unsigned int uk = (unsigned int)(w >> 32);
      float key = (uk & 0x80000000u) ? __uint_as_float(uk ^ 0x80000000u)
                                     : __uint_as_float(~uk);
      float sqj = sq[j];
      float dot = (sqj - key) * 0.5f;
      float hni = sqrtf(sq[i]), hnj = sqrtf(sqj);
      float cosv = dot/(hni*hnj)
                 + 1e-10f*(hsum[i]/hni + hsum[j]/hnj)
                 + 64.0f*1e-20f;
      nidx[i*4 + tid] = (int)j;
      ncos[i*4 + tid] = cosv;
    }
  }
}

// ---------- df = (sum of masked cos row + 1e-10)^-0.5 ----------
__global__ void k_df(const float* __restrict__ ncos, float* __restrict__ df){
  int i = blockIdx.x*256 + threadIdx.x;
  if (i < N){
    float s = ncos[i*4] + ncos[i*4+1] + ncos[i*4+2] + ncos[i*4+3];
    df[i] = 1.f / sqrtf(s + 1e-10f);
  }
}

// ---------- generic C += A @ B (A 2048x2048, B 2048xBN), K-split + atomics ----------
template<int BN>
__global__ void k_gemm(const float* __restrict__ A, const float* __restrict__ B,
                       float* __restrict__ C, int KC){
  constexpr int NT = 16*(BN/8);
  constexpr int CG = BN/8;
  __shared__ float at[32][132];
  __shared__ float bs[32][BN+4];
  int bm = blockIdx.x, ks = blockIdx.y;
  int tid = threadIdx.x;
  int rg = tid / CG, cg = tid % CG;
  int m0 = bm*128, kbase = ks*KC;
  float acc[8][8] = {};
  for (int kc = 0; kc < KC; kc += 32){
    for (int u = tid; u < 1024; u += NT){
      int row = u >> 3, k4 = u & 7;
      float4 v = *(const float4*)(A + (size_t)(m0+row)*N + kbase + kc + k4*4);
      at[k4*4+0][row] = v.x; at[k4*4+1][row] = v.y;
      at[k4*4+2][row] = v.z; at[k4*4+3][row] = v.w;
    }
    for (int u = tid; u < 32*(BN/4); u += NT){
      int kr = u / (BN/4), c4 = u % (BN/4);
      *(float4*)&bs[kr][c4*4] = *(const float4*)(B + (size_t)(kbase+kc+kr)*BN + c4*4);
    }
    __syncthreads();
    for (int k = 0; k < 32; k++){
      float a[8], b[8];
      *(float4*)&a[0] = *(const float4*)&at[k][rg*8];
      *(float4*)&a[4] = *(const float4*)&at[k][rg*8+4];
      *(float4*)&b[0] = *(const float4*)&bs[k][cg*8];
      *(float4*)&b[4] = *(const float4*)&bs[k][cg*8+4];
      #pragma unroll
      for (int ii = 0; ii < 8; ii++)
        #pragma unroll
        for (int jj = 0; jj < 8; jj++)
          acc[ii][jj] += a[ii]*b[jj];
    }
    __syncthreads();
  }
  #pragma unroll
  for (int ii = 0; ii < 8; ii++)
    #pragma unroll
    for (int jj = 0; jj < 8; jj++)
      atomicAdd(&C[(size_t)(m0 + rg*8 + ii)*BN + cg*8 + jj], acc[ii][jj]);
}

// ---------- f-side layer 1: v = Af@h; z1f, z1cf ----------
__global__ void k_f1(const float* __restrict__ h, const int* __restrict__ nidx,
                     const float* __restrict__ ncos, const float* __restrict__ df,
                     const float* __restrict__ WF1, const float* __restrict__ bF1,
                     const float* __restrict__ WC1, const float* __restrict__ bC1,
                     float* __restrict__ z1f, float* __restrict__ z1cf){
  int i = blockIdx.x, t = threadIdx.x;
  __shared__ float v[H];
  int j0 = nidx[i*4], j1 = nidx[i*4+1], j2 = nidx[i*4+2], j3 = nidx[i*4+3];
  float di = df[i];
  float w0 = ncos[i*4]  *di*df[j0];
  float w1 = ncos[i*4+1]*di*df[j1];
  float w2 = ncos[i*4+2]*di*df[j2];
  float w3 = ncos[i*4+3]*di*df[j3];
  v[t] = w0*h[(size_t)j0*H+t] + w1*h[(size_t)j1*H+t]
       + w2*h[(size_t)j2*H+t] + w3*h[(size_t)j3*H+t];
  __syncthreads();
  float a1 = bF1[t], a2 = bC1[t];
  const float4* wf = (const float4*)(WF1 + (size_t)t*H);
  const float4* wc = (const float4*)(WC1 + (size_t)t*H);
  const float4* vv = (const float4*)v;
  #pragma unroll
  for (int c = 0; c < 16; c++){
    float4 x = vv[c], f = wf[c], g = wc[c];
    a1 += x.x*f.x + x.y*f.y + x.z*f.z + x.w*f.w;
    a2 += x.x*g.x + x.y*g.y + x.z*g.z + x.w*g.w;
  }
  z1f [(size_t)i*H+t] = leaky(a1);
  z1cf[(size_t)i*H+t] = leaky(a2);
}

// ---------- t-side layer 1: u = dA*Y1; z1t/z1ct -> Zs (pre-scaled by dA) ----------
__global__ void k_t1(const float* __restrict__ Y1, const float* __restrict__ dA,
                     const float* __restrict__ WT1, const float* __restrict__ bT1,
                     const float* __restrict__ WC1, const float* __restrict__ bC1,
                     float* __restrict__ Zs){
  int i = blockIdx.x, t = threadIdx.x;
  __shared__ float u[H];
  float di = dA[i];
  u[t] = di * Y1[(size_t)i*H + t];
  __syncthreads();
  float a1 = bT1[t], a2 = bC1[t];
  const float4* wt = (const float4*)(WT1 + (size_t)t*H);
  const float4* wc = (const float4*)(WC1 + (size_t)t*H);
  const float4* vv = (const float4*)u;
  #pragma unroll
  for (int c = 0; c < 16; c++){
    float4 x = vv[c], f = wt[c], g = wc[c];
    a1 += x.x*f.x + x.y*f.y + x.z*f.z + x.w*f.w;
    a2 += x.x*g.x + x.y*g.y + x.z*g.z + x.w*g.w;
  }
  Zs[(size_t)i*128 + t]      = di*leaky(a1);
  Zs[(size_t)i*128 + 64 + t] = di*leaky(a2);
}

// ---------- f-side layer 2: zf, zcf, Lcf ----------
__global__ void k_f2(const float* __restrict__ z1f, const float* __restrict__ z1cf,
                     const int* __restrict__ nidx, const float* __restrict__ ncos,
                     const float* __restrict__ df,
                     const float* __restrict__ WF2, const float* __restrict__ bF2,
                     const float* __restrict__ WC2, const float* __restrict__ bC2,
                     float* __restrict__ zf, float* __restrict__ zcf,
                     float* __restrict__ Lcf){
  int i = blockIdx.x, tid = threadIdx.x, w = tid >> 6, t = tid & 63;
  __shared__ float v[2][H];
  int j0 = nidx[i*4], j1 = nidx[i*4+1], j2 = nidx[i*4+2], j3 = nidx[i*4+3];
  float di = df[i];
  float w0 = ncos[i*4]  *di*df[j0];
  float w1 = ncos[i*4+1]*di*df[j1];
  float w2 = ncos[i*4+2]*di*df[j2];
  float w3 = ncos[i*4+3]*di*df[j3];
  const float* src = w ? z1cf : z1f;
  v[w][t] = w0*src[(size_t)j0*H+t] + w1*src[(size_t)j1*H+t]
          + w2*src[(size_t)j2*H+t] + w3*src[(size_t)j3*H+t];
  __syncthreads();
  const float* WM = w ? WC2 : WF2;
  const float* bb = w ? bC2 : bF2;
  float a = bb[t];
  const float4* wm = (const float4*)(WM + (size_t)t*H);
  const float4* vv = (const float4*)v[w];
  #pragma unroll
  for (int c = 0; c < 16; c++){
    float4 x = vv[c], f = wm[c];
    a += x.x*f.x + x.y*f.y + x.z*f.z + x.w*f.w;
  }
  float val = leaky(a);
  if (!w){
    zf[(size_t)i*H+t] = val;
  } else {
    zcf[(size_t)i*H+t] = val;
    float s = waveRedSum(val*val);
    float m = sqrtf(s*(1.f/64.f)) + 1e-10f;
    Lcf[(size_t)i*H+t] = val/m;
  }
}

// ---------- t-side layer 2: zt, zct, Lct ----------
__global__ void k_t2(const float* __restrict__ Y2, const float* __restrict__ dA,
                     const float* __restrict__ WT2, const float* __restrict__ bT2,
                     const float* __restrict__ WC2, const float* __restrict__ bC2,
                     float* __restrict__ zt, float* __restrict__ zct,
                     float* __restrict__ Lct){
  int i = blockIdx.x, tid = threadIdx.x, w = tid >> 6, t = tid & 63;
  __shared__ float u[2][H];
  float di = dA[i];
  u[w][t] = di * Y2[(size_t)i*128 + w*64 + t];
  __syncthreads();
  const float* WM = w ? WC2 : WT2;
  const float* bb = w ? bC2 : bT2;
  float a = bb[t];
  const float4* wm = (const float4*)(WM + (size_t)t*H);
  const float4* vv = (const float4*)u[w];
  #pragma unroll
  for (int c = 0; c < 16; c++){
    float4 x = vv[c], f = wm[c];
    a += x.x*f.x + x.y*f.y + x.z*f.z + x.w*f.w;
  }
  float val = leaky(a);
  if (!w){
    zt[(size_t)i*H+t] = val;
  } else {
    zct[(size_t)i*H+t] = val;
    float s = waveRedSum(val*val);
    float m = sqrtf(s*(1.f/64.f)) + 1e-10f;
    Lct[(size_t)i*H+t] = val/m;
  }
}

// ---------- global 64x64 reductions for Lc / Ld ----------
__global__ __launch_bounds__(256) void k_reduce(const float* __restrict__ zt,
     const float* __restrict__ zct, const float* __restrict__ zf,
     const float* __restrict__ zcf, const float* __restrict__ Lcf,
     const float* __restrict__ Lct, float* __restrict__ red){
  __shared__ float rz[6][H];
  int tid = threadIdx.x;
  int d = tid >> 2;
  int e0 = (tid & 3) * 16;
  float aStc[16] = {}, aSfc[16] = {}, aCff[16] = {}, aCft[16] = {}, aCtt[16] = {};
  float c0 = 0, c1 = 0, c2 = 0, c3 = 0;
  int r0 = blockIdx.x * 16;
  for (int r = 0; r < 16; r++){
    int row = r0 + r;
    for (int u = tid; u < 6*H; u += 256){
      int seg = u >> 6, dd = u & 63;
      const float* p = (seg==0)?zt:(seg==1)?zct:(seg==2)?zf:(seg==3)?zcf:(seg==4)?Lcf:Lct;
      rz[seg][dd] = p[(size_t)row*H + dd];
    }
    __syncthreads();
    float vt = rz[0][d], vf = rz[2][d], lf = rz[4][d], lt = rz[5][d];
    #pragma unroll
    for (int e = 0; e < 16; e++){
      float bct = rz[1][e0+e], bcf = rz[3][e0+e], blf = rz[4][e0+e], blt = rz[5][e0+e];
      aStc[e] += vt*bct;  aSfc[e] += vf*bcf;
      aCff[e] += lf*blf;  aCft[e] += lf*blt;  aCtt[e] += lt*blt;
    }
    if (tid < 64){ c0 += rz[0][tid]; c1 += rz[1][tid]; c2 += rz[2][tid]; c3 += rz[3][tid]; }
    __syncthreads();
  }
  #pragma unroll
  for (int e = 0; e < 16; e++){
    int idx = d*64 + e0 + e;
    atomicAdd(&red[idx],          aStc[e]);
    atomicAdd(&red[4096  + idx],  aSfc[e]);
    atomicAdd(&red[8192  + idx],  aCff[e]);
    atomicAdd(&red[12288 + idx],  aCft[e]);
    atomicAdd(&red[16384 + idx],  aCtt[e]);
  }
  if (tid < 64){
    atomicAdd(&red[20480 + tid], c0);
    atomicAdd(&red[20544 + tid], c1);
    atomicAdd(&red[20608 + tid], c2);
    atomicAdd(&red[20672 + tid], c3);
  }
}

// ---------- attention + output projection ----------
__global__ void k_out(const float* __restrict__ zf, const float* __restrict__ zt,
                      const float* __restrict__ zcf, const float* __restrict__ zct,
                      const float* __restrict__ Wa, const float* __restrict__ ba,
                      const float* __restrict__ q, const float* __restrict__ W2,
                      const float* __restrict__ b2, float* __restrict__ out){
  int i = blockIdx.x, t = threadIdx.x;
  __shared__ float z[3][H];
  __shared__ float zagg[H];
  float vzf = zf[(size_t)i*H+t], vzt = zt[(size_t)i*H+t];
  float vzc = 0.5f*(zcf[(size_t)i*H+t] + zct[(size_t)i*H+t]);
  z[0][t] = vzf; z[1][t] = vzt; z[2][t] = vzc;
  __syncthreads();
  float qt = q[t], bat = ba[t];
  const float4* wa = (const float4*)(Wa + (size_t)t*H);
  float e[3];
  #pragma unroll
  for (int kk = 0; kk < 3; kk++){
    float a = bat;
    const float4* zz = (const float4*)z[kk];
    #pragma unroll
    for (int c = 0; c < 16; c++){
      float4 zv = zz[c], wv = wa[c];
      a += zv.x*wv.x + zv.y*wv.y + zv.z*wv.z + zv.w*wv.w;
    }
    float wk = tanhf(a);
    e[kk] = waveRedSum(wk*qt);
  }
  float mx = fmaxf(e[0], fmaxf(e[1], e[2]));
  float x0 = expf(e[0]-mx), x1 = expf(e[1]-mx), x2 = expf(e[2]-mx);
  float inv = 1.f/(x0+x1+x2);
  float a0 = x0*inv, a1 = x1*inv, a2 = x2*inv;
  zagg[t] = a0*vzf + a1*vzt + a2*vzc;
  __syncthreads();
  if (t < OUTD){
    float a = b2[t];
    const float* w2r = W2 + (size_t)t*H;
    #pragma unroll
    for (int c = 0; c < H; c++) a += zagg[c]*w2r[c];
    out[(size_t)i*OUTD + t] = a;
  }
}

// ---------- final scalars Lc, Ld ----------
__global__ void k_final(const float* __restrict__ red, float* __restrict__ out2){
  int tid = threadIdx.x;
  const float* Stc = red;
  const float* Sfc = red + 4096;
  const float* Cff = red + 8192;
  const float* Cft = red + 12288;
  const float* Ctt = red + 16384;
  const float* cst = red + 20480;
  const float* csct= red + 20544;
  const float* csf = red + 20608;
  const float* cscf= red + 20672;
  float sCff=0, sCft=0, sCtt=0, sM1=0, sM2=0;
  for (int u = tid*16; u < tid*16+16; u++){
    int d = u >> 6, e = u & 63;
    float m1 = Stc[u] - cst[d]*csct[e]*(1.f/2048.f);
    float m2 = Sfc[u] - csf[d]*cscf[e]*(1.f/2048.f);
    sM1 += m1*m1; sM2 += m2*m2;
    float cf = Cff[u], cx = Cft[u], ct = Ctt[u];
    sCff += cf*cf; sCft += cx*cx; sCtt += ct*ct;
  }
  __shared__ float rd[5][4];
  sCff = waveRedSum(sCff); sCft = waveRedSum(sCft); sCtt = waveRedSum(sCtt);
  sM1 = waveRedSum(sM1);   sM2 = waveRedSum(sM2);
  int w = tid >> 6, lane = tid & 63;
  if (lane == 0){ rd[0][w]=sCff; rd[1][w]=sCft; rd[2][w]=sCtt; rd[3][w]=sM1; rd[4][w]=sM2; }
  __syncthreads();
  if (tid == 0){
    float A0 = rd[0][0]+rd[0][1]+rd[0][2]+rd[0][3];
    float A1 = rd[1][0]+rd[1][1]+rd[1][2]+rd[1][3];
    float A2 = rd[2][0]+rd[2][1]+rd[2][2]+rd[2][3];
    float M1 = rd[3][0]+rd[3][1]+rd[3][2]+rd[3][3];
    float M2 = rd[4][0]+rd[4][1]+rd[4][2]+rd[4][3];
    out2[0] = (A0 - 2.f*A1 + A2) * (1.f/(2048.f*2048.f));
    out2[1] = (M1 + M2) * (1.f/(2047.f*2047.f));
  }
}

extern "C" void kernel_launch(void* const* d_in, const int* in_sizes, int n_in,
                              void* d_out, int out_size, void* d_ws, size_t ws_size,
                              hipStream_t stream) {
  const float* x   = (const float*)d_in[0];
  const float* A   = (const float*)d_in[1];
  // d_in[2] = k (always 4, hardcoded)
  const float* W1  = (const float*)d_in[3];
  const float* b1  = (const float*)d_in[4];
  const float* WF1 = (const float*)d_in[5];
  const float* bF1 = (const float*)d_in[6];
  const float* WF2 = (const float*)d_in[7];
  const float* bF2 = (const float*)d_in[8];
  const float* WT1 = (const float*)d_in[9];
  const float* bT1 = (const float*)d_in[10];
  const float* WT2 = (const float*)d_in[11];
  const float* bT2 = (const float*)d_in[12];
  const float* WC1 = (const float*)d_in[13];
  const float* bC1 = (const float*)d_in[14];
  const float* WC2 = (const float*)d_in[15];
  const float* bC2 = (const float*)d_in[16];
  const float* Wa  = (const float*)d_in[17];
  const float* ba  = (const float*)d_in[18];
  const float* q   = (const float*)d_in[19];
  const float* W2  = (const float*)d_in[20];
  const float* b2  = (const float*)d_in[21];
  float* out = (float*)d_out;

  float* W = (float*)d_ws;
  // persistent area
  float* h_   = W;                    // N*H
  float* hs   = h_  + N*H;            // N*H
  float* dA   = hs  + N*H;            // N
  float* sq   = dA  + N;              // N
  float* hsum = sq  + N;              // N
  float* df   = hsum+ N;              // N
  int*   nidx = (int*)(df + N);       // N*4
  float* ncos = (float*)(nidx + N*4); // N*4
  float* red  = ncos + N*4;           // 20736
  size_t RB   = (size_t)(red + 20736 - W);
  RB = (RB + 15) & ~(size_t)15;       // 16-float align
  float* DOT  = W + RB;               // N*N (reused after k_topk:)
  float* Y1   = DOT;                  // N*H
  float* Zs   = DOT + N*H;            // N*128
  float* Y2   = Zs  + N*128;          // N*128
  float* z1f  = Y2  + N*128;          // N*H
  float* z1cf = z1f + N*H;
  float* zf   = z1cf+ N*H;
  float* zcf  = zf  + N*H;
  float* zt   = zcf + N*H;
  float* zct  = zt  + N*H;
  float* Lcf  = zct + N*H;
  float* Lct  = Lcf + N*H;

  hipMemsetAsync(red, 0, 20736*sizeof(float), stream);

  k_rowsum<<<N, 256, 0, stream>>>(A, dA);
  k_h<<<N, 64, 0, stream>>>(x, W1, b1, dA, h_, hs, sq, hsum);
  k_gram<<<dim3(16,16), 256, 0, stream>>>(h_, DOT);
  k_topk<<<N, 256, 0, stream>>>(DOT, sq, hsum, nidx, ncos);
  k_df<<<8, 256, 0, stream>>>(ncos, df);

  // DOT dead now; zero Y1/Zs/Y2 area (Y1: N*H, Zs: N*128, Y2: N*128)
  hipMemsetAsync(Y1, 0, (size_t)(N*H + N*128 + N*128)*sizeof(float), stream);

  k_gemm<64><<<dim3(16,32), 128, 0, stream>>>(A, hs, Y1, 64);
  k_f1<<<N, 64, 0, stream>>>(h_, nidx, ncos, df, WF1, bF1, WC1, bC1, z1f, z1cf);
  k_t1<<<N, 64, 0, stream>>>(Y1, dA, WT1, bT1, WC1, bC1, Zs);
  k_gemm<128><<<dim3(16,16), 256, 0, stream>>>(A, Zs, Y2, 128);
  k_f2<<<N, 128, 0, stream>>>(z1f, z1cf, nidx, ncos, df, WF2, bF2, WC2, bC2, zf, zcf, Lcf);
  k_t2<<<N, 128, 0, stream>>>(Y2, dA, WT2, bT2, WC2, bC2, zt, zct, Lct);
  k_reduce<<<128, 256, 0, stream>>>(zt, zct, zf, zcf, Lcf, Lct, red);
  k_out<<<N, 64, 0, stream>>>(zf, zt, zcf, zct, Wa, ba, q, W2, b2, out);
  k_final<<<1, 256, 0, stream>>>(red, out + (size_t)N*OUTD);
}

// Round 2
// 393.216 us; speedup vs baseline: 1.8591x; 1.8591x over previous
//
#include <hip/hip_runtime.h>
#include <stdint.h>

#define N 2048
#define DIN 128
#define H 64
#define OUTD 7
#define RP 32   // k_reduce partial blocks

__device__ __forceinline__ float leaky(float x){ return x > 0.f ? x : 0.1f*x; }

__device__ __forceinline__ float waveRedSum(float v){
  #pragma unroll
  for (int o = 32; o > 0; o >>= 1) v += __shfl_xor(v, o, 64);
  return v;
}

__device__ __forceinline__ unsigned long long shflx64(unsigned long long v, int m){
  unsigned int lo = (unsigned int)v, hi = (unsigned int)(v >> 32);
  lo = (unsigned int)__shfl_xor((int)lo, m, 64);
  hi = (unsigned int)__shfl_xor((int)hi, m, 64);
  return ((unsigned long long)hi << 32) | lo;
}

// ---------- row sums of A -> dA = (rowsum + 1e-10)^-0.5 ----------
__global__ void k_rowsum(const float* __restrict__ A, float* __restrict__ dA){
  int i = blockIdx.x;
  const float4* row = (const float4*)(A + (size_t)i * N);
  float s = 0.f;
  for (int u = threadIdx.x; u < N/4; u += 256){
    float4 v = row[u];
    s += v.x + v.y + v.z + v.w;
  }
  __shared__ float red[4];
  s = waveRedSum(s);
  int wid = threadIdx.x >> 6, lane = threadIdx.x & 63;
  if (lane == 0) red[wid] = s;
  __syncthreads();
  if (threadIdx.x == 0){
    float t = red[0] + red[1] + red[2] + red[3];
    dA[i] = 1.0f / sqrtf(t + 1e-10f);
  }
}

// ---------- h = leaky(x @ W1^T + b1); also sq, hsum, hs = dA*h ----------
__global__ void k_h(const float* __restrict__ x, const float* __restrict__ W1,
                    const float* __restrict__ b1, const float* __restrict__ dA,
                    float* __restrict__ h, float* __restrict__ hs,
                    float* __restrict__ sq, float* __restrict__ hsum){
  int i = blockIdx.x, t = threadIdx.x;
  __shared__ float xr[DIN];
  xr[t]      = x[(size_t)i*DIN + t];
  xr[t + 64] = x[(size_t)i*DIN + t + 64];
  __syncthreads();
  float acc = b1[t];
  const float4* w  = (const float4*)(W1 + (size_t)t*DIN);
  const float4* xv = (const float4*)xr;
  #pragma unroll
  for (int c = 0; c < DIN/4; c++){
    float4 a = xv[c], b = w[c];
    acc += a.x*b.x + a.y*b.y + a.z*b.z + a.w*b.w;
  }
  float hv = leaky(acc);
  h [(size_t)i*H + t] = hv;
  hs[(size_t)i*H + t] = dA[i]*hv;
  float s2 = waveRedSum(hv*hv);
  float s1 = waveRedSum(hv);
  if (t == 0){ sq[i] = s2; hsum[i] = s1; }
}

// ---------- DOT = h @ h^T  (128x128 tile, 8x8 per thread, K=64) ----------
__global__ __launch_bounds__(256) void k_gram(const float* __restrict__ h,
                                              float* __restrict__ DOT){
  __shared__ float at[32][132];
  __shared__ float bt[32][132];
  int bi = blockIdx.x, bj = blockIdx.y;
  int tid = threadIdx.x;
  int rg = tid >> 4, cg = tid & 15;
  float acc[8][8] = {};
  for (int kc = 0; kc < 64; kc += 32){
    for (int u = tid; u < 1024; u += 256){
      int row = u >> 3, k4 = u & 7;
      float4 v = *(const float4*)(h + (size_t)(bi*128 + row)*H + kc + k4*4);
      at[k4*4+0][row] = v.x; at[k4*4+1][row] = v.y;
      at[k4*4+2][row] = v.z; at[k4*4+3][row] = v.w;
    }
    for (int u = tid; u < 1024; u += 256){
      int row = u >> 3, k4 = u & 7;
      float4 v = *(const float4*)(h + (size_t)(bj*128 + row)*H + kc + k4*4);
      bt[k4*4+0][row] = v.x; bt[k4*4+1][row] = v.y;
      bt[k4*4+2][row] = v.z; bt[k4*4+3][row] = v.w;
    }
    __syncthreads();
    for (int k = 0; k < 32; k++){
      float a[8], b[8];
      *(float4*)&a[0] = *(const float4*)&at[k][rg*8];
      *(float4*)&a[4] = *(const float4*)&at[k][rg*8+4];
      *(float4*)&b[0] = *(const float4*)&bt[k][cg*8];
      *(float4*)&b[4] = *(const float4*)&bt[k][cg*8+4];
      #pragma unroll
      for (int ii = 0; ii < 8; ii++)
        #pragma unroll
        for (int jj = 0; jj < 8; jj++)
          acc[ii][jj] += a[ii]*b[jj];
    }
    __syncthreads();
  }
  #pragma unroll
  for (int ii = 0; ii < 8; ii++){
    int r = bi*128 + rg*8 + ii;
    float* out = DOT + (size_t)r*N + bj*128 + cg*8;
    *(float4*)(out)   = make_float4(acc[ii][0], acc[ii][1], acc[ii][2], acc[ii][3]);
    *(float4*)(out+4) = make_float4(acc[ii][4], acc[ii][5], acc[ii][6], acc[ii][7]);
  }
}

// ---------- per-row top-4 of heat kernel (min of sq_j - 2*dot), + cos vals ----------
__global__ __launch_bounds__(256) void k_topk(const float* __restrict__ DOT,
      const float* __restrict__ sq, const float* __restrict__ hsum,
      int* __restrict__ nidx, float* __restrict__ ncos){
  int i = blockIdx.x, tid = threadIdx.x;
  __shared__ unsigned long long cand[1024];
  const float4* row = (const float4*)(DOT + (size_t)i * N);
  const float4* sq4 = (const float4*)sq;
  unsigned long long best[4] = {~0ULL, ~0ULL, ~0ULL, ~0ULL};
  #pragma unroll
  for (int blk = 0; blk < 2; blk++){
    int u = tid + blk*256;
    float4 d = row[u];
    float4 s = sq4[u];
    float kv[4] = { s.x - 2.f*d.x, s.y - 2.f*d.y, s.z - 2.f*d.z, s.w - 2.f*d.w };
    #pragma unroll
    for (int e = 0; e < 4; e++){
      unsigned int j = (unsigned int)(u*4 + e);
      unsigned int uk = __float_as_uint(kv[e]);
      uk = (uk & 0x80000000u) ? ~uk : (uk | 0x80000000u);
      unsigned long long c = ((unsigned long long)uk << 32) | j;
      if (c < best[3]){
        best[3] = c;
        unsigned long long t0;
        if (best[3] < best[2]){ t0 = best[2]; best[2] = best[3]; best[3] = t0; }
        if (best[2] < best[1]){ t0 = best[1]; best[1] = best[2]; best[2] = t0; }
        if (best[1] < best[0]){ t0 = best[0]; best[0] = best[1]; best[1] = t0; }
      }
    }
  }
  #pragma unroll
  for (int e = 0; e < 4; e++) cand[e*256 + tid] = best[e];
  __syncthreads();
  if (tid < 64){
    unsigned long long loc[16];
    #pragma unroll
    for (int e = 0; e < 16; e++) loc[e] = cand[e*64 + tid];
    unsigned long long w0=~0ULL, w1=~0ULL, w2=~0ULL, w3=~0ULL;
    #pragma unroll
    for (int r = 0; r < 4; r++){
      unsigned long long m = loc[0];
      #pragma unroll
      for (int e = 1; e < 16; e++) m = (loc[e] < m) ? loc[e] : m;
      unsigned long long g = m;
      #pragma unroll
      for (int o = 32; o > 0; o >>= 1){
        unsigned long long other = shflx64(g, o);
        if (other < g) g = other;
      }
      #pragma unroll
      for (int e = 0; e < 16; e++) if (loc[e] == g) loc[e] = ~0ULL;
      if (r == 0) w0 = g; else if (r == 1) w1 = g; else if (r == 2) w2 = g; else w3 = g;
    }
    if (tid < 4){
      unsigned long long w = (tid==0) ? w0 : (tid==1) ? w1 : (tid==2) ? w2 : w3;
      unsigned int j = (unsigned int)w;
      unsigned int uk = (unsigned int)(w >> 32);
      float key = (uk & 0x80000000u) ? __uint_as_float(uk ^ 0x80000000u)
                                     : __uint_as_float(~uk);
      float sqj = sq[j];
      float dot = (sqj - key) * 0.5f;
      float hni = sqrtf(sq[i]), hnj = sqrtf(sqj);
      float cosv = dot/(hni*hnj)
                 + 1e-10f*(hsum[i]/hni + hsum[j]/hnj)
                 + 64.0f*1e-20f;
      nidx[i*4 + tid] = (int)j;
      ncos[i*4 + tid] = cosv;
    }
  }
}

// ---------- df = (sum of masked cos row + 1e-10)^-0.5 ----------
__global__ void k_df(const float* __restrict__ ncos, float* __restrict__ df){
  int i = blockIdx.x*256 + threadIdx.x;
  if (i < N){
    float s = ncos[i*4] + ncos[i*4+1] + ncos[i*4+2] + ncos[i*4+3];
    df[i] = 1.f / sqrtf(s + 1e-10f);
  }
}

// ---------- C_partial[ks] = A[:, ksl] @ B[ksl, :]  (NO atomics; plain stores) ----------
template<int BM, int BN, int TM, int TN>
__global__ __launch_bounds__((BM/TM)*(BN/TN)) void k_gemm(
    const float* __restrict__ A, const float* __restrict__ B,
    float* __restrict__ Cp, int KC){
  constexpr int NT = (BM/TM)*(BN/TN);
  constexpr int CG = BN/TN;
  __shared__ float at[32][BM+4];
  __shared__ float bs[32][BN+4];
  int bm = blockIdx.x, ks = blockIdx.y;
  int tid = threadIdx.x;
  int rg = tid / CG, cg = tid % CG;
  int m0 = bm*BM, kbase = ks*KC;
  float acc[TM][TN] = {};
  for (int kc = 0; kc < KC; kc += 32){
    for (int u = tid; u < BM*8; u += NT){
      int row = u >> 3, k4 = u & 7;
      float4 v = *(const float4*)(A + (size_t)(m0+row)*N + kbase + kc + k4*4);
      at[k4*4+0][row] = v.x; at[k4*4+1][row] = v.y;
      at[k4*4+2][row] = v.z; at[k4*4+3][row] = v.w;
    }
    for (int u = tid; u < 32*(BN/4); u += NT){
      int kr = u / (BN/4), c4 = u % (BN/4);
      *(float4*)&bs[kr][c4*4] = *(const float4*)(B + (size_t)(kbase+kc+kr)*BN + c4*4);
    }
    __syncthreads();
    for (int k = 0; k < 32; k++){
      float a[TM], b[TN];
      #pragma unroll
      for (int ii = 0; ii < TM/4; ii++)
        *(float4*)&a[ii*4] = *(const float4*)&at[k][rg*TM + ii*4];
      #pragma unroll
      for (int jj = 0; jj < TN/4; jj++)
        *(float4*)&b[jj*4] = *(const float4*)&bs[k][cg*TN + jj*4];
      #pragma unroll
      for (int ii = 0; ii < TM; ii++)
        #pragma unroll
        for (int jj = 0; jj < TN; jj++)
          acc[ii][jj] += a[ii]*b[jj];
    }
    __syncthreads();
  }
  float* C = Cp + (size_t)ks * N * BN;
  #pragma unroll
  for (int ii = 0; ii < TM; ii++)
    #pragma unroll
    for (int jj = 0; jj < TN/4; jj++)
      *(float4*)&C[(size_t)(m0 + rg*TM + ii)*BN + cg*TN + jj*4] =
        make_float4(acc[ii][jj*4], acc[ii][jj*4+1], acc[ii][jj*4+2], acc[ii][jj*4+3]);
}

// ---------- f-side layer 1: v = Af@h; z1f, z1cf ----------
__global__ void k_f1(const float* __restrict__ h, const int* __restrict__ nidx,
                     const float* __restrict__ ncos, const float* __restrict__ df,
                     const float* __restrict__ WF1, const float* __restrict__ bF1,
                     const float* __restrict__ WC1, const float* __restrict__ bC1,
                     float* __restrict__ z1f, float* __restrict__ z1cf){
  int i = blockIdx.x, t = threadIdx.x;
  __shared__ float v[H];
  int j0 = nidx[i*4], j1 = nidx[i*4+1], j2 = nidx[i*4+2], j3 = nidx[i*4+3];
  float di = df[i];
  float w0 = ncos[i*4]  *di*df[j0];
  float w1 = ncos[i*4+1]*di*df[j1];
  float w2 = ncos[i*4+2]*di*df[j2];
  float w3 = ncos[i*4+3]*di*df[j3];
  v[t] = w0*h[(size_t)j0*H+t] + w1*h[(size_t)j1*H+t]
       + w2*h[(size_t)j2*H+t] + w3*h[(size_t)j3*H+t];
  __syncthreads();
  float a1 = bF1[t], a2 = bC1[t];
  const float4* wf = (const float4*)(WF1 + (size_t)t*H);
  const float4* wc = (const float4*)(WC1 + (size_t)t*H);
  const float4* vv = (const float4*)v;
  #pragma unroll
  for (int c = 0; c < 16; c++){
    float4 x = vv[c], f = wf[c], g = wc[c];
    a1 += x.x*f.x + x.y*f.y + x.z*f.z + x.w*f.w;
    a2 += x.x*g.x + x.y*g.y + x.z*g.z + x.w*g.w;
  }
  z1f [(size_t)i*H+t] = leaky(a1);
  z1cf[(size_t)i*H+t] = leaky(a2);
}

// ---------- t-side layer 1: u = dA*sum(Y1 partials); Zs (pre-scaled by dA) ----------
__global__ void k_t1(const float* __restrict__ Y1p, const float* __restrict__ dA,
                     const float* __restrict__ WT1, const float* __restrict__ bT1,
                     const float* __restrict__ WC1, const float* __restrict__ bC1,
                     float* __restrict__ Zs){
  int i = blockIdx.x, t = threadIdx.x;
  __shared__ float u[H];
  float di = dA[i];
  float y = 0.f;
  #pragma unroll
  for (int p = 0; p < 8; p++) y += Y1p[(size_t)p*(N*H) + (size_t)i*H + t];
  u[t] = di * y;
  __syncthreads();
  float a1 = bT1[t], a2 = bC1[t];
  const float4* wt = (const float4*)(WT1 + (size_t)t*H);
  const float4* wc = (const float4*)(WC1 + (size_t)t*H);
  const float4* vv = (const float4*)u;
  #pragma unroll
  for (int c = 0; c < 16; c++){
    float4 x = vv[c], f = wt[c], g = wc[c];
    a1 += x.x*f.x + x.y*f.y + x.z*f.z + x.w*f.w;
    a2 += x.x*g.x + x.y*g.y + x.z*g.z + x.w*g.w;
  }
  Zs[(size_t)i*128 + t]      = di*leaky(a1);
  Zs[(size_t)i*128 + 64 + t] = di*leaky(a2);
}

// ---------- f-side layer 2: zf, zcf, Lcf ----------
__global__ void k_f2(const float* __restrict__ z1f, const float* __restrict__ z1cf,
                     const int* __restrict__ nidx, const float* __restrict__ ncos,
                     const float* __restrict__ df,
                     const float* __restrict__ WF2, const float* __restrict__ bF2,
                     const float* __restrict__ WC2, const float* __restrict__ bC2,
                     float* __restrict__ zf, float* __restrict__ zcf,
                     float* __restrict__ Lcf){
  int i = blockIdx.x, tid = threadIdx.x, w = tid >> 6, t = tid & 63;
  __shared__ float v[2][H];
  int j0 = nidx[i*4], j1 = nidx[i*4+1], j2 = nidx[i*4+2], j3 = nidx[i*4+3];
  float di = df[i];
  float w0 = ncos[i*4]  *di*df[j0];
  float w1 = ncos[i*4+1]*di*df[j1];
  float w2 = ncos[i*4+2]*di*df[j2];
  float w3 = ncos[i*4+3]*di*df[j3];
  const float* src = w ? z1cf : z1f;
  v[w][t] = w0*src[(size_t)j0*H+t] + w1*src[(size_t)j1*H+t]
          + w2*src[(size_t)j2*H+t] + w3*src[(size_t)j3*H+t];
  __syncthreads();
  const float* WM = w ? WC2 : WF2;
  const float* bb = w ? bC2 : bF2;
  float a = bb[t];
  const float4* wm = (const float4*)(WM + (size_t)t*H);
  const float4* vv = (const float4*)v[w];
  #pragma unroll
  for (int c = 0; c < 16; c++){
    float4 x = vv[c], f = wm[c];
    a += x.x*f.x + x.y*f.y + x.z*f.z + x.w*f.w;
  }
  float val = leaky(a);
  if (!w){
    zf[(size_t)i*H+t] = val;
  } else {
    zcf[(size_t)i*H+t] = val;
    float s = waveRedSum(val*val);
    float m = sqrtf(s*(1.f/64.f)) + 1e-10f;
    Lcf[(size_t)i*H+t] = val/m;
  }
}

// ---------- t-side layer 2: zt, zct, Lct ----------
__global__ void k_t2(const float* __restrict__ Y2p, const float* __restrict__ dA,
                     const float* __restrict__ WT2, const float* __restrict__ bT2,
                     const float* __restrict__ WC2, const float* __restrict__ bC2,
                     float* __restrict__ zt, float* __restrict__ zct,
                     float* __restrict__ Lct){
  int i = blockIdx.x, tid = threadIdx.x, w = tid >> 6, t = tid & 63;
  __shared__ float u[2][H];
  float di = dA[i];
  float y = 0.f;
  #pragma unroll
  for (int p = 0; p < 4; p++) y += Y2p[(size_t)p*(N*128) + (size_t)i*128 + w*64 + t];
  u[w][t] = di * y;
  __syncthreads();
  const float* WM = w ? WC2 : WT2;
  const float* bb = w ? bC2 : bT2;
  float a = bb[t];
  const float4* wm = (const float4*)(WM + (size_t)t*H);
  const float4* vv = (const float4*)u[w];
  #pragma unroll
  for (int c = 0; c < 16; c++){
    float4 x = vv[c], f = wm[c];
    a += x.x*f.x + x.y*f.y + x.z*f.z + x.w*f.w;
  }
  float val = leaky(a);
  if (!w){
    zt[(size_t)i*H+t] = val;
  } else {
    zct[(size_t)i*H+t] = val;
    float s = waveRedSum(val*val);
    float m = sqrtf(s*(1.f/64.f)) + 1e-10f;
    Lct[(size_t)i*H+t] = val/m;
  }
}

// ---------- 64x64 reductions for Lc / Ld: per-block partials, NO atomics ----------
__global__ __launch_bounds__(256) void k_reduce(const float* __restrict__ zt,
     const float* __restrict__ zct, const float* __restrict__ zf,
     const float* __restrict__ zcf, const float* __restrict__ Lcf,
     const float* __restrict__ Lct, float* __restrict__ redP){
  __shared__ float rz[8][6][H];
  int tid = threadIdx.x;
  int d = tid >> 2;
  int e0 = (tid & 3) * 16;
  float aStc[16] = {}, aSfc[16] = {}, aCff[16] = {}, aCft[16] = {}, aCtt[16] = {};
  float c0 = 0, c1 = 0, c2 = 0, c3 = 0;
  int r0 = blockIdx.x * (N/RP);
  for (int rb = 0; rb < N/RP; rb += 8){
    for (int u = tid; u < 8*6*H; u += 256){
      int dd = u & 63, s = u >> 6, seg = s % 6, rl = s / 6;
      const float* p = (seg==0)?zt:(seg==1)?zct:(seg==2)?zf:(seg==3)?zcf:(seg==4)?Lcf:Lct;
      rz[rl][seg][dd] = p[(size_t)(r0+rb+rl)*H + dd];
    }
    __syncthreads();
    #pragma unroll
    for (int rr = 0; rr < 8; rr++){
      float vt = rz[rr][0][d], vf = rz[rr][2][d], lf = rz[rr][4][d], lt = rz[rr][5][d];
      #pragma unroll
      for (int e = 0; e < 16; e++){
        float bct = rz[rr][1][e0+e], bcf = rz[rr][3][e0+e];
        float blf = rz[rr][4][e0+e], blt = rz[rr][5][e0+e];
        aStc[e] += vt*bct;  aSfc[e] += vf*bcf;
        aCff[e] += lf*blf;  aCft[e] += lf*blt;  aCtt[e] += lt*blt;
      }
      if (tid < 64){
        c0 += rz[rr][0][tid]; c1 += rz[rr][1][tid];
        c2 += rz[rr][2][tid]; c3 += rz[rr][3][tid];
      }
    }
    __syncthreads();
  }
  float* rp = redP + (size_t)blockIdx.x * 20736;
  #pragma unroll
  for (int e = 0; e < 16; e++){
    int idx = d*64 + e0 + e;
    rp[idx]          = aStc[e];
    rp[4096  + idx]  = aSfc[e];
    rp[8192  + idx]  = aCff[e];
    rp[12288 + idx]  = aCft[e];
    rp[16384 + idx]  = aCtt[e];
  }
  if (tid < 64){
    rp[20480 + tid] = c0;
    rp[20544 + tid] = c1;
    rp[20608 + tid] = c2;
    rp[20672 + tid] = c3;
  }
}

// ---------- sum RP partial slabs into red ----------
__global__ void k_combine(const float* __restrict__ redP, float* __restrict__ red){
  int idx = blockIdx.x*256 + threadIdx.x;
  if (idx < 20736){
    float s = 0.f;
    #pragma unroll
    for (int p = 0; p < RP; p++) s += redP[(size_t)p*20736 + idx];
    red[idx] = s;
  }
}

// ---------- attention + output projection ----------
__global__ void k_out(const float* __restrict__ zf, const float* __restrict__ zt,
                      const float* __restrict__ zcf, const float* __restrict__ zct,
                      const float* __restrict__ Wa, const float* __restrict__ ba,
                      const float* __restrict__ q, const float* __restrict__ W2,
                      const float* __restrict__ b2, float* __restrict__ out){
  int i = blockIdx.x, t = threadIdx.x;
  __shared__ float z[3][H];
  __shared__ float zagg[H];
  float vzf = zf[(size_t)i*H+t], vzt = zt[(size_t)i*H+t];
  float vzc = 0.5f*(zcf[(size_t)i*H+t] + zct[(size_t)i*H+t]);
  z[0][t] = vzf; z[1][t] = vzt; z[2][t] = vzc;
  __syncthreads();
  float qt = q[t], bat = ba[t];
  const float4* wa = (const float4*)(Wa + (size_t)t*H);
  float e[3];
  #pragma unroll
  for (int kk = 0; kk < 3; kk++){
    float a = bat;
    const float4* zz = (const float4*)z[kk];
    #pragma unroll
    for (int c = 0; c < 16; c++){
      float4 zv = zz[c], wv = wa[c];
      a += zv.x*wv.x + zv.y*wv.y + zv.z*wv.z + zv.w*wv.w;
    }
    float wk = tanhf(a);
    e[kk] = waveRedSum(wk*qt);
  }
  float mx = fmaxf(e[0], fmaxf(e[1], e[2]));
  float x0 = expf(e[0]-mx), x1 = expf(e[1]-mx), x2 = expf(e[2]-mx);
  float inv = 1.f/(x0+x1+x2);
  float a0 = x0*inv, a1 = x1*inv, a2 = x2*inv;
  zagg[t] = a0*vzf + a1*vzt + a2*vzc;
  __syncthreads();
  if (t < OUTD){
    float a = b2[t];
    const float* w2r = W2 + (size_t)t*H;
    #pragma unroll
    for (int c = 0; c < H; c++) a += zagg[c]*w2r[c];
    out[(size_t)i*OUTD + t] = a;
  }
}

// ---------- final scalars Lc, Ld ----------
__global__ void k_final(const float* __restrict__ red, float* __restrict__ out2){
  int tid = threadIdx.x;
  const float* Stc = red;
  const float* Sfc = red + 4096;
  const float* Cff = red + 8192;
  const float* Cft = red + 12288;
  const float* Ctt = red + 16384;
  const float* cst = red + 20480;
  const float* csct= red + 20544;
  const float* csf = red + 20608;
  const float* cscf= red + 20672;
  float sCff=0, sCft=0, sCtt=0, sM1=0, sM2=0;
  for (int u = tid*16; u < tid*16+16; u++){
    int d = u >> 6, e = u & 63;
    float m1 = Stc[u] - cst[d]*csct[e]*(1.f/2048.f);
    float m2 = Sfc[u] - csf[d]*cscf[e]*(1.f/2048.f);
    sM1 += m1*m1; sM2 += m2*m2;
    float cf = Cff[u], cx = Cft[u], ct = Ctt[u];
    sCff += cf*cf; sCft += cx*cx; sCtt += ct*ct;
  }
  __shared__ float rd[5][4];
  sCff = waveRedSum(sCff); sCft = waveRedSum(sCft); sCtt = waveRedSum(sCtt);
  sM1 = waveRedSum(sM1);   sM2 = waveRedSum(sM2);
  int w = tid >> 6, lane = tid & 63;
  if (lane == 0){ rd[0][w]=sCff; rd[1][w]=sCft; rd[2][w]=sCtt; rd[3][w]=sM1; rd[4][w]=sM2; }
  __syncthreads();
  if (tid == 0){
    float A0 = rd[0][0]+rd[0][1]+rd[0][2]+rd[0][3];
    float A1 = rd[1][0]+rd[1][1]+rd[1][2]+rd[1][3];
    float A2 = rd[2][0]+rd[2][1]+rd[2][2]+rd[2][3];
    float M1 = rd[3][0]+rd[3][1]+rd[3][2]+rd[3][3];
    float M2 = rd[4][0]+rd[4][1]+rd[4][2]+rd[4][3];
    out2[0] = (A0 - 2.f*A1 + A2) * (1.f/(2048.f*2048.f));
    out2[1] = (M1 + M2) * (1.f/(2047.f*2047.f));
  }
}

extern "C" void kernel_launch(void* const* d_in, const int* in_sizes, int n_in,
                              void* d_out, int out_size, void* d_ws, size_t ws_size,
                              hipStream_t stream) {
  const float* x   = (const float*)d_in[0];
  const float* A   = (const float*)d_in[1];
  const float* W1  = (const float*)d_in[3];
  const float* b1  = (const float*)d_in[4];
  const float* WF1 = (const float*)d_in[5];
  const float* bF1 = (const float*)d_in[6];
  const float* WF2 = (const float*)d_in[7];
  const float* bF2 = (const float*)d_in[8];
  const float* WT1 = (const float*)d_in[9];
  const float* bT1 = (const float*)d_in[10];
  const float* WT2 = (const float*)d_in[11];
  const float* bT2 = (const float*)d_in[12];
  const float* WC1 = (const float*)d_in[13];
  const float* bC1 = (const float*)d_in[14];
  const float* WC2 = (const float*)d_in[15];
  const float* bC2 = (const float*)d_in[16];
  const float* Wa  = (const float*)d_in[17];
  const float* ba  = (const float*)d_in[18];
  const float* q   = (const float*)d_in[19];
  const float* W2  = (const float*)d_in[20];
  const float* b2  = (const float*)d_in[21];
  float* out = (float*)d_out;

  float* W = (float*)d_ws;
  // persistent area
  float* h_   = W;                    // N*H
  float* hs   = h_  + N*H;            // N*H
  float* dA   = hs  + N*H;            // N
  float* sq   = dA  + N;              // N
  float* hsum = sq  + N;              // N
  float* df   = hsum+ N;              // N
  int*   nidx = (int*)(df + N);       // N*4
  float* ncos = (float*)(nidx + N*4); // N*4
  float* red  = ncos + N*4;           // 20736
  size_t RB   = (size_t)(red + 20736 - W);
  RB = (RB + 15) & ~(size_t)15;       // 16-float align
  float* DOT  = W + RB;               // N*N; dead after k_topk, reused:
  float* Y1p  = DOT;                  // 8 * N*H   = 1,048,576
  float* Zs   = Y1p + 8*(size_t)N*H;  // N*128     =   262,144
  float* Y2p  = Zs  + (size_t)N*128;  // 4 * N*128 = 1,048,576
  float* z1f  = Y2p + 4*(size_t)N*128;
  float* z1cf = z1f + N*H;
  float* zf   = z1cf+ N*H;
  float* zcf  = zf  + N*H;
  float* zt   = zcf + N*H;
  float* zct  = zt  + N*H;
  float* Lcf  = zct + N*H;
  float* Lct  = Lcf + N*H;
  float* redP = Lct + N*H;            // RP * 20736 = 663,552 (total 4,071,424 <= N*N)

  k_rowsum<<<N, 256, 0, stream>>>(A, dA);
  k_h<<<N, 64, 0, stream>>>(x, W1, b1, dA, h_, hs, sq, hsum);
  k_gram<<<dim3(16,16), 256, 0, stream>>>(h_, DOT);
  k_topk<<<N, 256, 0, stream>>>(DOT, sq, hsum, nidx, ncos);
  k_df<<<8, 256, 0, stream>>>(ncos, df);

  k_gemm<64,64,4,4><<<dim3(32,8), 256, 0, stream>>>(A, hs, Y1p, 256);
  k_f1<<<N, 64, 0, stream>>>(h_, nidx, ncos, df, WF1, bF1, WC1, bC1, z1f, z1cf);
  k_t1<<<N, 64, 0, stream>>>(Y1p, dA, WT1, bT1, WC1, bC1, Zs);
  k_gemm<64,128,4,8><<<dim3(32,4), 256, 0, stream>>>(A, Zs, Y2p, 512);
  k_f2<<<N, 128, 0, stream>>>(z1f, z1cf, nidx, ncos, df, WF2, bF2, WC2, bC2, zf, zcf, Lcf);
  k_t2<<<N, 128, 0, stream>>>(Y2p, dA, WT2, bT2, WC2, bC2, zt, zct, Lct);
  k_reduce<<<RP, 256, 0, stream>>>(zt, zct, zf, zcf, Lcf, Lct, redP);
  k_combine<<<81, 256, 0, stream>>>(redP, red);
  k_out<<<N, 64, 0, stream>>>(zf, zt, zcf, zct, Wa, ba, q, W2, b2, out);
  k_final<<<1, 256, 0, stream>>>(red, out + (size_t)N*OUTD);
}

// Round 3
// 318.000 us; speedup vs baseline: 2.2988x; 1.2365x over previous
//
#include <hip/hip_runtime.h>
#include <stdint.h>

#define N 2048
#define DIN 128
#define H 64
#define OUTD 7
#define RP 128   // k_reduce partial blocks (16 rows each)

// Z6 row layout: [zt(64) | zct(64) | zf(64) | zcf(64) | Lcf(64) | Lct(64)]
#define Z_ZT  0
#define Z_ZCT 64
#define Z_ZF  128
#define Z_ZCF 192
#define Z_LCF 256
#define Z_LCT 320

__device__ __forceinline__ float leaky(float x){ return x > 0.f ? x : 0.1f*x; }

__device__ __forceinline__ float waveRedSum(float v){
  #pragma unroll
  for (int o = 32; o > 0; o >>= 1) v += __shfl_xor(v, o, 64);
  return v;
}

__device__ __forceinline__ unsigned long long shflx64(unsigned long long v, int m){
  unsigned int lo = (unsigned int)v, hi = (unsigned int)(v >> 32);
  lo = (unsigned int)__shfl_xor((int)lo, m, 64);
  hi = (unsigned int)__shfl_xor((int)hi, m, 64);
  return ((unsigned long long)hi << 32) | lo;
}

// ---------- row sums of A -> dA = (rowsum + 1e-10)^-0.5 ----------
__global__ void k_rowsum(const float* __restrict__ A, float* __restrict__ dA){
  int i = blockIdx.x;
  const float4* row = (const float4*)(A + (size_t)i * N);
  float s = 0.f;
  for (int u = threadIdx.x; u < N/4; u += 256){
    float4 v = row[u];
    s += v.x + v.y + v.z + v.w;
  }
  __shared__ float red[4];
  s = waveRedSum(s);
  int wid = threadIdx.x >> 6, lane = threadIdx.x & 63;
  if (lane == 0) red[wid] = s;
  __syncthreads();
  if (threadIdx.x == 0){
    float t = red[0] + red[1] + red[2] + red[3];
    dA[i] = 1.0f / sqrtf(t + 1e-10f);
  }
}

// ---------- h = leaky(x @ W1^T + b1); also sq, hsum, hs = dA*h ----------
__global__ void k_h(const float* __restrict__ x, const float* __restrict__ W1,
                    const float* __restrict__ b1, const float* __restrict__ dA,
                    float* __restrict__ h, float* __restrict__ hs,
                    float* __restrict__ sq, float* __restrict__ hsum){
  int i = blockIdx.x, t = threadIdx.x;
  __shared__ float xr[DIN];
  xr[t]      = x[(size_t)i*DIN + t];
  xr[t + 64] = x[(size_t)i*DIN + t + 64];
  __syncthreads();
  float acc = b1[t];
  const float4* w  = (const float4*)(W1 + (size_t)t*DIN);
  const float4* xv = (const float4*)xr;
  #pragma unroll
  for (int c = 0; c < DIN/4; c++){
    float4 a = xv[c], b = w[c];
    acc += a.x*b.x + a.y*b.y + a.z*b.z + a.w*b.w;
  }
  float hv = leaky(acc);
  h [(size_t)i*H + t] = hv;
  hs[(size_t)i*H + t] = dA[i]*hv;
  float s2 = waveRedSum(hv*hv);
  float s1 = waveRedSum(hv);
  if (t == 0){ sq[i] = s2; hsum[i] = s1; }
}

// ---------- DOT = h @ h^T  (128x128 tile, 8x8 per thread, K=64) ----------
__global__ __launch_bounds__(256) void k_gram(const float* __restrict__ h,
                                              float* __restrict__ DOT){
  __shared__ float at[32][132];
  __shared__ float bt[32][132];
  int bi = blockIdx.x, bj = blockIdx.y;
  int tid = threadIdx.x;
  int rg = tid >> 4, cg = tid & 15;
  float acc[8][8] = {};
  for (int kc = 0; kc < 64; kc += 32){
    for (int u = tid; u < 1024; u += 256){
      int row = u >> 3, k4 = u & 7;
      float4 v = *(const float4*)(h + (size_t)(bi*128 + row)*H + kc + k4*4);
      at[k4*4+0][row] = v.x; at[k4*4+1][row] = v.y;
      at[k4*4+2][row] = v.z; at[k4*4+3][row] = v.w;
    }
    for (int u = tid; u < 1024; u += 256){
      int row = u >> 3, k4 = u & 7;
      float4 v = *(const float4*)(h + (size_t)(bj*128 + row)*H + kc + k4*4);
      bt[k4*4+0][row] = v.x; bt[k4*4+1][row] = v.y;
      bt[k4*4+2][row] = v.z; bt[k4*4+3][row] = v.w;
    }
    __syncthreads();
    for (int k = 0; k < 32; k++){
      float a[8], b[8];
      *(float4*)&a[0] = *(const float4*)&at[k][rg*8];
      *(float4*)&a[4] = *(const float4*)&at[k][rg*8+4];
      *(float4*)&b[0] = *(const float4*)&bt[k][cg*8];
      *(float4*)&b[4] = *(const float4*)&bt[k][cg*8+4];
      #pragma unroll
      for (int ii = 0; ii < 8; ii++)
        #pragma unroll
        for (int jj = 0; jj < 8; jj++)
          acc[ii][jj] += a[ii]*b[jj];
    }
    __syncthreads();
  }
  #pragma unroll
  for (int ii = 0; ii < 8; ii++){
    int r = bi*128 + rg*8 + ii;
    float* out = DOT + (size_t)r*N + bj*128 + cg*8;
    *(float4*)(out)   = make_float4(acc[ii][0], acc[ii][1], acc[ii][2], acc[ii][3]);
    *(float4*)(out+4) = make_float4(acc[ii][4], acc[ii][5], acc[ii][6], acc[ii][7]);
  }
}

// ---------- per-row top-4 of heat kernel (min of sq_j - 2*dot), + cos vals ----------
__global__ __launch_bounds__(256) void k_topk(const float* __restrict__ DOT,
      const float* __restrict__ sq, const float* __restrict__ hsum,
      int* __restrict__ nidx, float* __restrict__ ncos){
  int i = blockIdx.x, tid = threadIdx.x;
  __shared__ unsigned long long cand[1024];
  const float4* row = (const float4*)(DOT + (size_t)i * N);
  const float4* sq4 = (const float4*)sq;
  unsigned long long best[4] = {~0ULL, ~0ULL, ~0ULL, ~0ULL};
  #pragma unroll
  for (int blk = 0; blk < 2; blk++){
    int u = tid + blk*256;
    float4 d = row[u];
    float4 s = sq4[u];
    float kv[4] = { s.x - 2.f*d.x, s.y - 2.f*d.y, s.z - 2.f*d.z, s.w - 2.f*d.w };
    #pragma unroll
    for (int e = 0; e < 4; e++){
      unsigned int j = (unsigned int)(u*4 + e);
      unsigned int uk = __float_as_uint(kv[e]);
      uk = (uk & 0x80000000u) ? ~uk : (uk | 0x80000000u);
      unsigned long long c = ((unsigned long long)uk << 32) | j;
      if (c < best[3]){
        best[3] = c;
        unsigned long long t0;
        if (best[3] < best[2]){ t0 = best[2]; best[2] = best[3]; best[3] = t0; }
        if (best[2] < best[1]){ t0 = best[1]; best[1] = best[2]; best[2] = t0; }
        if (best[1] < best[0]){ t0 = best[0]; best[0] = best[1]; best[1] = t0; }
      }
    }
  }
  #pragma unroll
  for (int e = 0; e < 4; e++) cand[e*256 + tid] = best[e];
  __syncthreads();
  if (tid < 64){
    unsigned long long loc[16];
    #pragma unroll
    for (int e = 0; e < 16; e++) loc[e] = cand[e*64 + tid];
    unsigned long long w0=~0ULL, w1=~0ULL, w2=~0ULL, w3=~0ULL;
    #pragma unroll
    for (int r = 0; r < 4; r++){
      unsigned long long m = loc[0];
      #pragma unroll
      for (int e = 1; e < 16; e++) m = (loc[e] < m) ? loc[e] : m;
      unsigned long long g = m;
      #pragma unroll
      for (int o = 32; o > 0; o >>= 1){
        unsigned long long other = shflx64(g, o);
        if (other < g) g = other;
      }
      #pragma unroll
      for (int e = 0; e < 16; e++) if (loc[e] == g) loc[e] = ~0ULL;
      if (r == 0) w0 = g; else if (r == 1) w1 = g; else if (r == 2) w2 = g; else w3 = g;
    }
    if (tid < 4){
      unsigned long long w = (tid==0) ? w0 : (tid==1) ? w1 : (tid==2) ? w2 : w3;
      unsigned int j = (unsigned int)w;
      unsigned int uk = (unsigned int)(w >> 32);
      float key = (uk & 0x80000000u) ? __uint_as_float(uk ^ 0x80000000u)
                                     : __uint_as_float(~uk);
      float sqj = sq[j];
      float dot = (sqj - key) * 0.5f;
      float hni = sqrtf(sq[i]), hnj = sqrtf(sqj);
      float cosv = dot/(hni*hnj)
                 + 1e-10f*(hsum[i]/hni + hsum[j]/hnj)
                 + 64.0f*1e-20f;
      nidx[i*4 + tid] = (int)j;
      ncos[i*4 + tid] = cosv;
    }
  }
}

// ---------- df = (sum of masked cos row + 1e-10)^-0.5 ----------
__global__ void k_df(const float* __restrict__ ncos, float* __restrict__ df){
  int i = blockIdx.x*256 + threadIdx.x;
  if (i < N){
    float s = ncos[i*4] + ncos[i*4+1] + ncos[i*4+2] + ncos[i*4+3];
    df[i] = 1.f / sqrtf(s + 1e-10f);
  }
}

// ---------- C_partial[ks] = A[:, ksl] @ B[ksl, :]  (NO atomics; plain stores) ----------
template<int BM, int BN, int TM, int TN>
__global__ __launch_bounds__((BM/TM)*(BN/TN)) void k_gemm(
    const float* __restrict__ A, const float* __restrict__ B,
    float* __restrict__ Cp, int KC){
  constexpr int NT = (BM/TM)*(BN/TN);
  constexpr int CG = BN/TN;
  __shared__ float at[32][BM+4];
  __shared__ float bs[32][BN+4];
  int bm = blockIdx.x, ks = blockIdx.y;
  int tid = threadIdx.x;
  int rg = tid / CG, cg = tid % CG;
  int m0 = bm*BM, kbase = ks*KC;
  float acc[TM][TN] = {};
  for (int kc = 0; kc < KC; kc += 32){
    for (int u = tid; u < BM*8; u += NT){
      int row = u >> 3, k4 = u & 7;
      float4 v = *(const float4*)(A + (size_t)(m0+row)*N + kbase + kc + k4*4);
      at[k4*4+0][row] = v.x; at[k4*4+1][row] = v.y;
      at[k4*4+2][row] = v.z; at[k4*4+3][row] = v.w;
    }
    for (int u = tid; u < 32*(BN/4); u += NT){
      int kr = u / (BN/4), c4 = u % (BN/4);
      *(float4*)&bs[kr][c4*4] = *(const float4*)(B + (size_t)(kbase+kc+kr)*BN + c4*4);
    }
    __syncthreads();
    for (int k = 0; k < 32; k++){
      float a[TM], b[TN];
      #pragma unroll
      for (int ii = 0; ii < TM/4; ii++)
        *(float4*)&a[ii*4] = *(const float4*)&at[k][rg*TM + ii*4];
      #pragma unroll
      for (int jj = 0; jj < TN/4; jj++)
        *(float4*)&b[jj*4] = *(const float4*)&bs[k][cg*TN + jj*4];
      #pragma unroll
      for (int ii = 0; ii < TM; ii++)
        #pragma unroll
        for (int jj = 0; jj < TN; jj++)
          acc[ii][jj] += a[ii]*b[jj];
    }
    __syncthreads();
  }
  float* C = Cp + (size_t)ks * N * BN;
  #pragma unroll
  for (int ii = 0; ii < TM; ii++)
    #pragma unroll
    for (int jj = 0; jj < TN/4; jj++)
      *(float4*)&C[(size_t)(m0 + rg*TM + ii)*BN + cg*TN + jj*4] =
        make_float4(acc[ii][jj*4], acc[ii][jj*4+1], acc[ii][jj*4+2], acc[ii][jj*4+3]);
}

// ---------- f-side layer 1: v = Af@h; z1f, z1cf ----------
__global__ void k_f1(const float* __restrict__ h, const int* __restrict__ nidx,
                     const float* __restrict__ ncos, const float* __restrict__ df,
                     const float* __restrict__ WF1, const float* __restrict__ bF1,
                     const float* __restrict__ WC1, const float* __restrict__ bC1,
                     float* __restrict__ z1f, float* __restrict__ z1cf){
  int i = blockIdx.x, t = threadIdx.x;
  __shared__ float v[H];
  int j0 = nidx[i*4], j1 = nidx[i*4+1], j2 = nidx[i*4+2], j3 = nidx[i*4+3];
  float di = df[i];
  float w0 = ncos[i*4]  *di*df[j0];
  float w1 = ncos[i*4+1]*di*df[j1];
  float w2 = ncos[i*4+2]*di*df[j2];
  float w3 = ncos[i*4+3]*di*df[j3];
  v[t] = w0*h[(size_t)j0*H+t] + w1*h[(size_t)j1*H+t]
       + w2*h[(size_t)j2*H+t] + w3*h[(size_t)j3*H+t];
  __syncthreads();
  float a1 = bF1[t], a2 = bC1[t];
  const float4* wf = (const float4*)(WF1 + (size_t)t*H);
  const float4* wc = (const float4*)(WC1 + (size_t)t*H);
  const float4* vv = (const float4*)v;
  #pragma unroll
  for (int c = 0; c < 16; c++){
    float4 x = vv[c], f = wf[c], g = wc[c];
    a1 += x.x*f.x + x.y*f.y + x.z*f.z + x.w*f.w;
    a2 += x.x*g.x + x.y*g.y + x.z*g.z + x.w*g.w;
  }
  z1f [(size_t)i*H+t] = leaky(a1);
  z1cf[(size_t)i*H+t] = leaky(a2);
}

// ---------- t-side layer 1: u = dA*sum(Y1 partials); Zs (pre-scaled by dA) ----------
__global__ void k_t1(const float* __restrict__ Y1p, const float* __restrict__ dA,
                     const float* __restrict__ WT1, const float* __restrict__ bT1,
                     const float* __restrict__ WC1, const float* __restrict__ bC1,
                     float* __restrict__ Zs){
  int i = blockIdx.x, t = threadIdx.x;
  __shared__ float u[H];
  float di = dA[i];
  float y = 0.f;
  #pragma unroll
  for (int p = 0; p < 8; p++) y += Y1p[(size_t)p*(N*H) + (size_t)i*H + t];
  u[t] = di * y;
  __syncthreads();
  float a1 = bT1[t], a2 = bC1[t];
  const float4* wt = (const float4*)(WT1 + (size_t)t*H);
  const float4* wc = (const float4*)(WC1 + (size_t)t*H);
  const float4* vv = (const float4*)u;
  #pragma unroll
  for (int c = 0; c < 16; c++){
    float4 x = vv[c], f = wt[c], g = wc[c];
    a1 += x.x*f.x + x.y*f.y + x.z*f.z + x.w*f.w;
    a2 += x.x*g.x + x.y*g.y + x.z*g.z + x.w*g.w;
  }
  Zs[(size_t)i*128 + t]      = di*leaky(a1);
  Zs[(size_t)i*128 + 64 + t] = di*leaky(a2);
}

// ---------- f-side layer 2: zf, zcf, Lcf -> Z6 ----------
__global__ void k_f2(const float* __restrict__ z1f, const float* __restrict__ z1cf,
                     const int* __restrict__ nidx, const float* __restrict__ ncos,
                     const float* __restrict__ df,
                     const float* __restrict__ WF2, const float* __restrict__ bF2,
                     const float* __restrict__ WC2, const float* __restrict__ bC2,
                     float* __restrict__ Z6){
  int i = blockIdx.x, tid = threadIdx.x, w = tid >> 6, t = tid & 63;
  __shared__ float v[2][H];
  int j0 = nidx[i*4], j1 = nidx[i*4+1], j2 = nidx[i*4+2], j3 = nidx[i*4+3];
  float di = df[i];
  float w0 = ncos[i*4]  *di*df[j0];
  float w1 = ncos[i*4+1]*di*df[j1];
  float w2 = ncos[i*4+2]*di*df[j2];
  float w3 = ncos[i*4+3]*di*df[j3];
  const float* src = w ? z1cf : z1f;
  v[w][t] = w0*src[(size_t)j0*H+t] + w1*src[(size_t)j1*H+t]
          + w2*src[(size_t)j2*H+t] + w3*src[(size_t)j3*H+t];
  __syncthreads();
  const float* WM = w ? WC2 : WF2;
  const float* bb = w ? bC2 : bF2;
  float a = bb[t];
  const float4* wm = (const float4*)(WM + (size_t)t*H);
  const float4* vv = (const float4*)v[w];
  #pragma unroll
  for (int c = 0; c < 16; c++){
    float4 x = vv[c], f = wm[c];
    a += x.x*f.x + x.y*f.y + x.z*f.z + x.w*f.w;
  }
  float val = leaky(a);
  float* zr = Z6 + (size_t)i*384;
  if (!w){
    zr[Z_ZF + t] = val;
  } else {
    zr[Z_ZCF + t] = val;
    float s = waveRedSum(val*val);
    float m = sqrtf(s*(1.f/64.f)) + 1e-10f;
    zr[Z_LCF + t] = val/m;
  }
}

// ---------- t-side layer 2: zt, zct, Lct -> Z6 ----------
__global__ void k_t2(const float* __restrict__ Y2p, const float* __restrict__ dA,
                     const float* __restrict__ WT2, const float* __restrict__ bT2,
                     const float* __restrict__ WC2, const float* __restrict__ bC2,
                     float* __restrict__ Z6){
  int i = blockIdx.x, tid = threadIdx.x, w = tid >> 6, t = tid & 63;
  __shared__ float u[2][H];
  float di = dA[i];
  float y = 0.f;
  #pragma unroll
  for (int p = 0; p < 4; p++) y += Y2p[(size_t)p*(N*128) + (size_t)i*128 + w*64 + t];
  u[w][t] = di * y;
  __syncthreads();
  const float* WM = w ? WC2 : WT2;
  const float* bb = w ? bC2 : bT2;
  float a = bb[t];
  const float4* wm = (const float4*)(WM + (size_t)t*H);
  const float4* vv = (const float4*)u[w];
  #pragma unroll
  for (int c = 0; c < 16; c++){
    float4 x = vv[c], f = wm[c];
    a += x.x*f.x + x.y*f.y + x.z*f.z + x.w*f.w;
  }
  float val = leaky(a);
  float* zr = Z6 + (size_t)i*384;
  if (!w){
    zr[Z_ZT + t] = val;
  } else {
    zr[Z_ZCT + t] = val;
    float s = waveRedSum(val*val);
    float m = sqrtf(s*(1.f/64.f)) + 1e-10f;
    zr[Z_LCT + t] = val/m;
  }
}

// ---------- 64x64 reductions: 128 blocks x 16 rows, coalesced Z6 stage ----------
__global__ __launch_bounds__(256) void k_reduce(const float* __restrict__ Z6,
                                                float* __restrict__ redP){
  __shared__ float rz[16*384];
  int tid = threadIdx.x;
  int d0 = (tid >> 3) * 2;     // 0..62 step 2
  int e0 = (tid & 7) * 8;      // 0..56 step 8
  float aStc[2][8] = {}, aSfc[2][8] = {}, aCff[2][8] = {}, aCft[2][8] = {}, aCtt[2][8] = {};
  float c0 = 0, c1 = 0, c2 = 0, c3 = 0;
  int r0 = blockIdx.x * 16;
  // coalesced stage: 16 rows x 384 floats = 1536 float4
  const float4* src = (const float4*)(Z6 + (size_t)r0 * 384);
  float4* dst = (float4*)rz;
  #pragma unroll
  for (int u = 0; u < 6; u++) dst[tid + u*256] = src[tid + u*256];
  __syncthreads();
  for (int rr = 0; rr < 16; rr++){
    const float* bp = rz + rr*384;
    float vt0 = bp[Z_ZT +d0], vt1 = bp[Z_ZT +d0+1];
    float vf0 = bp[Z_ZF +d0], vf1 = bp[Z_ZF +d0+1];
    float lf0 = bp[Z_LCF+d0], lf1 = bp[Z_LCF+d0+1];
    float lt0 = bp[Z_LCT+d0], lt1 = bp[Z_LCT+d0+1];
    float bct[8], bcf[8], blf[8], blt[8];
    *(float4*)&bct[0] = *(const float4*)&bp[Z_ZCT+e0];
    *(float4*)&bct[4] = *(const float4*)&bp[Z_ZCT+e0+4];
    *(float4*)&bcf[0] = *(const float4*)&bp[Z_ZCF+e0];
    *(float4*)&bcf[4] = *(const float4*)&bp[Z_ZCF+e0+4];
    *(float4*)&blf[0] = *(const float4*)&bp[Z_LCF+e0];
    *(float4*)&blf[4] = *(const float4*)&bp[Z_LCF+e0+4];
    *(float4*)&blt[0] = *(const float4*)&bp[Z_LCT+e0];
    *(float4*)&blt[4] = *(const float4*)&bp[Z_LCT+e0+4];
    #pragma unroll
    for (int e = 0; e < 8; e++){
      aStc[0][e] += vt0*bct[e];  aStc[1][e] += vt1*bct[e];
      aSfc[0][e] += vf0*bcf[e];  aSfc[1][e] += vf1*bcf[e];
      aCff[0][e] += lf0*blf[e];  aCff[1][e] += lf1*blf[e];
      aCft[0][e] += lf0*blt[e];  aCft[1][e] += lf1*blt[e];
      aCtt[0][e] += lt0*blt[e];  aCtt[1][e] += lt1*blt[e];
    }
    if (tid < 64){
      c0 += bp[Z_ZT + tid]; c1 += bp[Z_ZCT + tid];
      c2 += bp[Z_ZF + tid]; c3 += bp[Z_ZCF + tid];
    }
  }
  float* rp = redP + (size_t)blockIdx.x * 20736;
  #pragma unroll
  for (int dd = 0; dd < 2; dd++){
    int idx = (d0+dd)*64 + e0;
    *(float4*)&rp[idx]           = make_float4(aStc[dd][0],aStc[dd][1],aStc[dd][2],aStc[dd][3]);
    *(float4*)&rp[idx+4]         = make_float4(aStc[dd][4],aStc[dd][5],aStc[dd][6],aStc[dd][7]);
    *(float4*)&rp[4096 +idx]     = make_float4(aSfc[dd][0],aSfc[dd][1],aSfc[dd][2],aSfc[dd][3]);
    *(float4*)&rp[4096 +idx+4]   = make_float4(aSfc[dd][4],aSfc[dd][5],aSfc[dd][6],aSfc[dd][7]);
    *(float4*)&rp[8192 +idx]     = make_float4(aCff[dd][0],aCff[dd][1],aCff[dd][2],aCff[dd][3]);
    *(float4*)&rp[8192 +idx+4]   = make_float4(aCff[dd][4],aCff[dd][5],aCff[dd][6],aCff[dd][7]);
    *(float4*)&rp[12288+idx]     = make_float4(aCft[dd][0],aCft[dd][1],aCft[dd][2],aCft[dd][3]);
    *(float4*)&rp[12288+idx+4]   = make_float4(aCft[dd][4],aCft[dd][5],aCft[dd][6],aCft[dd][7]);
    *(float4*)&rp[16384+idx]     = make_float4(aCtt[dd][0],aCtt[dd][1],aCtt[dd][2],aCtt[dd][3]);
    *(float4*)&rp[16384+idx+4]   = make_float4(aCtt[dd][4],aCtt[dd][5],aCtt[dd][6],aCtt[dd][7]);
  }
  if (tid < 64){
    rp[20480 + tid] = c0;
    rp[20544 + tid] = c1;
    rp[20608 + tid] = c2;
    rp[20672 + tid] = c3;
  }
}

// ---------- sum RP partial slabs into red ----------
__global__ void k_combine(const float* __restrict__ redP, float* __restrict__ red){
  int idx = blockIdx.x*256 + threadIdx.x;
  if (idx < 20736){
    float s = 0.f;
    #pragma unroll 8
    for (int p = 0; p < RP; p++) s += redP[(size_t)p*20736 + idx];
    red[idx] = s;
  }
}

// ---------- attention + output projection (reads Z6) ----------
__global__ void k_out(const float* __restrict__ Z6,
                      const float* __restrict__ Wa, const float* __restrict__ ba,
                      const float* __restrict__ q, const float* __restrict__ W2,
                      const float* __restrict__ b2, float* __restrict__ out){
  int i = blockIdx.x, t = threadIdx.x;
  __shared__ float z[3][H];
  __shared__ float zagg[H];
  const float* zr = Z6 + (size_t)i*384;
  float vzf = zr[Z_ZF + t], vzt = zr[Z_ZT + t];
  float vzc = 0.5f*(zr[Z_ZCF + t] + zr[Z_ZCT + t]);
  z[0][t] = vzf; z[1][t] = vzt; z[2][t] = vzc;
  __syncthreads();
  float qt = q[t], bat = ba[t];
  const float4* wa = (const float4*)(Wa + (size_t)t*H);
  float e[3];
  #pragma unroll
  for (int kk = 0; kk < 3; kk++){
    float a = bat;
    const float4* zz = (const float4*)z[kk];
    #pragma unroll
    for (int c = 0; c < 16; c++){
      float4 zv = zz[c], wv = wa[c];
      a += zv.x*wv.x + zv.y*wv.y + zv.z*wv.z + zv.w*wv.w;
    }
    float wk = tanhf(a);
    e[kk] = waveRedSum(wk*qt);
  }
  float mx = fmaxf(e[0], fmaxf(e[1], e[2]));
  float x0 = expf(e[0]-mx), x1 = expf(e[1]-mx), x2 = expf(e[2]-mx);
  float inv = 1.f/(x0+x1+x2);
  float a0 = x0*inv, a1 = x1*inv, a2 = x2*inv;
  zagg[t] = a0*vzf + a1*vzt + a2*vzc;
  __syncthreads();
  if (t < OUTD){
    float a = b2[t];
    const float* w2r = W2 + (size_t)t*H;
    #pragma unroll
    for (int c = 0; c < H; c++) a += zagg[c]*w2r[c];
    out[(size_t)i*OUTD + t] = a;
  }
}

// ---------- final scalars Lc, Ld ----------
__global__ void k_final(const float* __restrict__ red, float* __restrict__ out2){
  int tid = threadIdx.x;
  const float* Stc = red;
  const float* Sfc = red + 4096;
  const float* Cff = red + 8192;
  const float* Cft = red + 12288;
  const float* Ctt = red + 16384;
  const float* cst = red + 20480;
  const float* csct= red + 20544;
  const float* csf = red + 20608;
  const float* cscf= red + 20672;
  float sCff=0, sCft=0, sCtt=0, sM1=0, sM2=0;
  for (int u = tid*16; u < tid*16+16; u++){
    int d = u >> 6, e = u & 63;
    float m1 = Stc[u] - cst[d]*csct[e]*(1.f/2048.f);
    float m2 = Sfc[u] - csf[d]*cscf[e]*(1.f/2048.f);
    sM1 += m1*m1; sM2 += m2*m2;
    float cf = Cff[u], cx = Cft[u], ct = Ctt[u];
    sCff += cf*cf; sCft += cx*cx; sCtt += ct*ct;
  }
  __shared__ float rd[5][4];
  sCff = waveRedSum(sCff); sCft = waveRedSum(sCft); sCtt = waveRedSum(sCtt);
  sM1 = waveRedSum(sM1);   sM2 = waveRedSum(sM2);
  int w = tid >> 6, lane = tid & 63;
  if (lane == 0){ rd[0][w]=sCff; rd[1][w]=sCft; rd[2][w]=sCtt; rd[3][w]=sM1; rd[4][w]=sM2; }
  __syncthreads();
  if (tid == 0){
    float A0 = rd[0][0]+rd[0][1]+rd[0][2]+rd[0][3];
    float A1 = rd[1][0]+rd[1][1]+rd[1][2]+rd[1][3];
    float A2 = rd[2][0]+rd[2][1]+rd[2][2]+rd[2][3];
    float M1 = rd[3][0]+rd[3][1]+rd[3][2]+rd[3][3];
    float M2 = rd[4][0]+rd[4][1]+rd[4][2]+rd[4][3];
    out2[0] = (A0 - 2.f*A1 + A2) * (1.f/(2048.f*2048.f));
    out2[1] = (M1 + M2) * (1.f/(2047.f*2047.f));
  }
}

extern "C" void kernel_launch(void* const* d_in, const int* in_sizes, int n_in,
                              void* d_out, int out_size, void* d_ws, size_t ws_size,
                              hipStream_t stream) {
  const float* x   = (const float*)d_in[0];
  const float* A   = (const float*)d_in[1];
  const float* W1  = (const float*)d_in[3];
  const float* b1  = (const float*)d_in[4];
  const float* WF1 = (const float*)d_in[5];
  const float* bF1 = (const float*)d_in[6];
  const float* WF2 = (const float*)d_in[7];
  const float* bF2 = (const float*)d_in[8];
  const float* WT1 = (const float*)d_in[9];
  const float* bT1 = (const float*)d_in[10];
  const float* WT2 = (const float*)d_in[11];
  const float* bT2 = (const float*)d_in[12];
  const float* WC1 = (const float*)d_in[13];
  const float* bC1 = (const float*)d_in[14];
  const float* WC2 = (const float*)d_in[15];
  const float* bC2 = (const float*)d_in[16];
  const float* Wa  = (const float*)d_in[17];
  const float* ba  = (const float*)d_in[18];
  const float* q   = (const float*)d_in[19];
  const float* W2  = (const float*)d_in[20];
  const float* b2  = (const float*)d_in[21];
  float* out = (float*)d_out;

  float* W = (float*)d_ws;
  // persistent area
  float* h_   = W;                    // N*H
  float* hs   = h_  + N*H;            // N*H
  float* dA   = hs  + N*H;            // N
  float* sq   = dA  + N;              // N
  float* hsum = sq  + N;              // N
  float* df   = hsum+ N;              // N
  int*   nidx = (int*)(df + N);       // N*4
  float* ncos = (float*)(nidx + N*4); // N*4
  float* red  = ncos + N*4;           // 20736
  size_t RB   = (size_t)(red + 20736 - W);
  RB = (RB + 15) & ~(size_t)15;       // 16-float align
  float* DOT  = W + RB;               // N*N; dead after k_topk, overlaid:
  float* Z6   = DOT;                  // N*384            =   786,432  (live to end)
  float* Y1p  = Z6  + (size_t)N*384;  // 8 * N*H          = 1,048,576
  float* Zs   = Y1p + 8*(size_t)N*H;  // N*128            =   262,144
  float* Y2p  = Zs  + (size_t)N*128;  // 4 * N*128        = 1,048,576
  float* z1f  = Y2p + 4*(size_t)N*128;// N*H              =   131,072
  float* z1cf = z1f + N*H;            // N*H              =   131,072
  // redP overlays Y1p..z1cf (all dead before k_reduce): RP*20736 = 2,654,208
  // region available: 4,194,304 - 786,432 = 3,407,872  -> fits
  float* redP = Y1p;

  k_rowsum<<<N, 256, 0, stream>>>(A, dA);
  k_h<<<N, 64, 0, stream>>>(x, W1, b1, dA, h_, hs, sq, hsum);
  k_gram<<<dim3(16,16), 256, 0, stream>>>(h_, DOT);
  k_topk<<<N, 256, 0, stream>>>(DOT, sq, hsum, nidx, ncos);
  k_df<<<8, 256, 0, stream>>>(ncos, df);

  k_gemm<64,64,4,4><<<dim3(32,8), 256, 0, stream>>>(A, hs, Y1p, 256);
  k_f1<<<N, 64, 0, stream>>>(h_, nidx, ncos, df, WF1, bF1, WC1, bC1, z1f, z1cf);
  k_t1<<<N, 64, 0, stream>>>(Y1p, dA, WT1, bT1, WC1, bC1, Zs);
  k_gemm<64,128,4,8><<<dim3(32,4), 256, 0, stream>>>(A, Zs, Y2p, 512);
  k_f2<<<N, 128, 0, stream>>>(z1f, z1cf, nidx, ncos, df, WF2, bF2, WC2, bC2, Z6);
  k_t2<<<N, 128, 0, stream>>>(Y2p, dA, WT2, bT2, WC2, bC2, Z6);
  k_reduce<<<RP, 256, 0, stream>>>(Z6, redP);
  k_combine<<<81, 256, 0, stream>>>(redP, red);
  k_out<<<N, 64, 0, stream>>>(Z6, Wa, ba, q, W2, b2, out);
  k_final<<<1, 256, 0, stream>>>(red, out + (size_t)N*OUTD);
}

// Round 4
// 311.001 us; speedup vs baseline: 2.3505x; 1.0225x over previous
//
#include <hip/hip_runtime.h>
#include <stdint.h>

#define N 2048
#define DIN 128
#define H 64
#define OUTD 7
#define RP 64    // k_reduce partial blocks (32 rows each)
#define S1 8     // gemm1 K-splits
#define S2 8     // gemm2 K-splits

// Z6 row layout: [zt(64) | zct(64) | zf(64) | zcf(64) | Lcf(64) | Lct(64)]
#define Z_ZT  0
#define Z_ZCT 64
#define Z_ZF  128
#define Z_ZCF 192
#define Z_LCF 256
#define Z_LCT 320

__device__ __forceinline__ float leaky(float x){ return x > 0.f ? x : 0.1f*x; }

__device__ __forceinline__ float waveRedSum(float v){
  #pragma unroll
  for (int o = 32; o > 0; o >>= 1) v += __shfl_xor(v, o, 64);
  return v;
}

__device__ __forceinline__ unsigned long long shflx64(unsigned long long v, int m){
  unsigned int lo = (unsigned int)v, hi = (unsigned int)(v >> 32);
  lo = (unsigned int)__shfl_xor((int)lo, m, 64);
  hi = (unsigned int)__shfl_xor((int)hi, m, 64);
  return ((unsigned long long)hi << 32) | lo;
}

// ---------- row sums of A -> dA = (rowsum + 1e-10)^-0.5 ----------
__global__ void k_rowsum(const float* __restrict__ A, float* __restrict__ dA){
  int i = blockIdx.x;
  const float4* row = (const float4*)(A + (size_t)i * N);
  float s = 0.f;
  for (int u = threadIdx.x; u < N/4; u += 256){
    float4 v = row[u];
    s += v.x + v.y + v.z + v.w;
  }
  __shared__ float red[4];
  s = waveRedSum(s);
  int wid = threadIdx.x >> 6, lane = threadIdx.x & 63;
  if (lane == 0) red[wid] = s;
  __syncthreads();
  if (threadIdx.x == 0){
    float t = red[0] + red[1] + red[2] + red[3];
    dA[i] = 1.0f / sqrtf(t + 1e-10f);
  }
}

// ---------- h = leaky(x @ W1^T + b1); also sq, hsum, hs = dA*h ----------
__global__ void k_h(const float* __restrict__ x, const float* __restrict__ W1,
                    const float* __restrict__ b1, const float* __restrict__ dA,
                    float* __restrict__ h, float* __restrict__ hs,
                    float* __restrict__ sq, float* __restrict__ hsum){
  int i = blockIdx.x, t = threadIdx.x;
  __shared__ float xr[DIN];
  xr[t]      = x[(size_t)i*DIN + t];
  xr[t + 64] = x[(size_t)i*DIN + t + 64];
  __syncthreads();
  float acc = b1[t];
  const float4* w  = (const float4*)(W1 + (size_t)t*DIN);
  const float4* xv = (const float4*)xr;
  #pragma unroll
  for (int c = 0; c < DIN/4; c++){
    float4 a = xv[c], b = w[c];
    acc += a.x*b.x + a.y*b.y + a.z*b.z + a.w*b.w;
  }
  float hv = leaky(acc);
  h [(size_t)i*H + t] = hv;
  hs[(size_t)i*H + t] = dA[i]*hv;
  float s2 = waveRedSum(hv*hv);
  float s1 = waveRedSum(hv);
  if (t == 0){ sq[i] = s2; hsum[i] = s1; }
}

// ---------- DOT = h @ h^T  (128x128 tile, 8x8 per thread, K=64) ----------
__global__ __launch_bounds__(256) void k_gram(const float* __restrict__ h,
                                              float* __restrict__ DOT){
  __shared__ float at[32][132];
  __shared__ float bt[32][132];
  int bi = blockIdx.x, bj = blockIdx.y;
  int tid = threadIdx.x;
  int rg = tid >> 4, cg = tid & 15;
  float acc[8][8] = {};
  for (int kc = 0; kc < 64; kc += 32){
    for (int u = tid; u < 1024; u += 256){
      int row = u >> 3, k4 = u & 7;
      float4 v = *(const float4*)(h + (size_t)(bi*128 + row)*H + kc + k4*4);
      at[k4*4+0][row] = v.x; at[k4*4+1][row] = v.y;
      at[k4*4+2][row] = v.z; at[k4*4+3][row] = v.w;
    }
    for (int u = tid; u < 1024; u += 256){
      int row = u >> 3, k4 = u & 7;
      float4 v = *(const float4*)(h + (size_t)(bj*128 + row)*H + kc + k4*4);
      bt[k4*4+0][row] = v.x; bt[k4*4+1][row] = v.y;
      bt[k4*4+2][row] = v.z; bt[k4*4+3][row] = v.w;
    }
    __syncthreads();
    for (int k = 0; k < 32; k++){
      float a[8], b[8];
      *(float4*)&a[0] = *(const float4*)&at[k][rg*8];
      *(float4*)&a[4] = *(const float4*)&at[k][rg*8+4];
      *(float4*)&b[0] = *(const float4*)&bt[k][cg*8];
      *(float4*)&b[4] = *(const float4*)&bt[k][cg*8+4];
      #pragma unroll
      for (int ii = 0; ii < 8; ii++)
        #pragma unroll
        for (int jj = 0; jj < 8; jj++)
          acc[ii][jj] += a[ii]*b[jj];
    }
    __syncthreads();
  }
  #pragma unroll
  for (int ii = 0; ii < 8; ii++){
    int r = bi*128 + rg*8 + ii;
    float* out = DOT + (size_t)r*N + bj*128 + cg*8;
    *(float4*)(out)   = make_float4(acc[ii][0], acc[ii][1], acc[ii][2], acc[ii][3]);
    *(float4*)(out+4) = make_float4(acc[ii][4], acc[ii][5], acc[ii][6], acc[ii][7]);
  }
}

// ---------- per-row top-4 + cos vals + df (fused) ----------
__global__ __launch_bounds__(256) void k_topk(const float* __restrict__ DOT,
      const float* __restrict__ sq, const float* __restrict__ hsum,
      int* __restrict__ nidx, float* __restrict__ ncos, float* __restrict__ df){
  int i = blockIdx.x, tid = threadIdx.x;
  __shared__ unsigned long long cand[1024];
  const float4* row = (const float4*)(DOT + (size_t)i * N);
  const float4* sq4 = (const float4*)sq;
  unsigned long long best[4] = {~0ULL, ~0ULL, ~0ULL, ~0ULL};
  #pragma unroll
  for (int blk = 0; blk < 2; blk++){
    int u = tid + blk*256;
    float4 d = row[u];
    float4 s = sq4[u];
    float kv[4] = { s.x - 2.f*d.x, s.y - 2.f*d.y, s.z - 2.f*d.z, s.w - 2.f*d.w };
    #pragma unroll
    for (int e = 0; e < 4; e++){
      unsigned int j = (unsigned int)(u*4 + e);
      unsigned int uk = __float_as_uint(kv[e]);
      uk = (uk & 0x80000000u) ? ~uk : (uk | 0x80000000u);
      unsigned long long c = ((unsigned long long)uk << 32) | j;
      if (c < best[3]){
        best[3] = c;
        unsigned long long t0;
        if (best[3] < best[2]){ t0 = best[2]; best[2] = best[3]; best[3] = t0; }
        if (best[2] < best[1]){ t0 = best[1]; best[1] = best[2]; best[2] = t0; }
        if (best[1] < best[0]){ t0 = best[0]; best[0] = best[1]; best[1] = t0; }
      }
    }
  }
  #pragma unroll
  for (int e = 0; e < 4; e++) cand[e*256 + tid] = best[e];
  __syncthreads();
  if (tid < 64){
    unsigned long long loc[16];
    #pragma unroll
    for (int e = 0; e < 16; e++) loc[e] = cand[e*64 + tid];
    unsigned long long w0=~0ULL, w1=~0ULL, w2=~0ULL, w3=~0ULL;
    #pragma unroll
    for (int r = 0; r < 4; r++){
      unsigned long long m = loc[0];
      #pragma unroll
      for (int e = 1; e < 16; e++) m = (loc[e] < m) ? loc[e] : m;
      unsigned long long g = m;
      #pragma unroll
      for (int o = 32; o > 0; o >>= 1){
        unsigned long long other = shflx64(g, o);
        if (other < g) g = other;
      }
      #pragma unroll
      for (int e = 0; e < 16; e++) if (loc[e] == g) loc[e] = ~0ULL;
      if (r == 0) w0 = g; else if (r == 1) w1 = g; else if (r == 2) w2 = g; else w3 = g;
    }
    float myc = 0.f;
    if (tid < 4){
      unsigned long long w = (tid==0) ? w0 : (tid==1) ? w1 : (tid==2) ? w2 : w3;
      unsigned int j = (unsigned int)w;
      unsigned int uk = (unsigned int)(w >> 32);
      float key = (uk & 0x80000000u) ? __uint_as_float(uk ^ 0x80000000u)
                                     : __uint_as_float(~uk);
      float sqj = sq[j];
      float dot = (sqj - key) * 0.5f;
      float hni = sqrtf(sq[i]), hnj = sqrtf(sqj);
      float cosv = dot/(hni*hnj)
                 + 1e-10f*(hsum[i]/hni + hsum[j]/hnj)
                 + 64.0f*1e-20f;
      nidx[i*4 + tid] = (int)j;
      ncos[i*4 + tid] = cosv;
      myc = cosv;
    }
    // sum cosv over lanes 0..3 -> df
    myc += __shfl_xor(myc, 1, 64);
    myc += __shfl_xor(myc, 2, 64);
    if (tid == 0) df[i] = 1.f / sqrtf(myc + 1e-10f);
  }
}

// ---------- C_partial[ks] = A[:, ksl] @ B[ksl, :]  (plain stores) ----------
template<int BM, int BN, int TM, int TN>
__global__ __launch_bounds__((BM/TM)*(BN/TN)) void k_gemm(
    const float* __restrict__ A, const float* __restrict__ B,
    float* __restrict__ Cp, int KC){
  constexpr int NT = (BM/TM)*(BN/TN);
  constexpr int CG = BN/TN;
  __shared__ float at[32][BM+4];
  __shared__ float bs[32][BN+4];
  int bm = blockIdx.x, ks = blockIdx.y;
  int tid = threadIdx.x;
  int rg = tid / CG, cg = tid % CG;
  int m0 = bm*BM, kbase = ks*KC;
  float acc[TM][TN] = {};
  for (int kc = 0; kc < KC; kc += 32){
    for (int u = tid; u < BM*8; u += NT){
      int row = u >> 3, k4 = u & 7;
      float4 v = *(const float4*)(A + (size_t)(m0+row)*N + kbase + kc + k4*4);
      at[k4*4+0][row] = v.x; at[k4*4+1][row] = v.y;
      at[k4*4+2][row] = v.z; at[k4*4+3][row] = v.w;
    }
    for (int u = tid; u < 32*(BN/4); u += NT){
      int kr = u / (BN/4), c4 = u % (BN/4);
      *(float4*)&bs[kr][c4*4] = *(const float4*)(B + (size_t)(kbase+kc+kr)*BN + c4*4);
    }
    __syncthreads();
    for (int k = 0; k < 32; k++){
      float a[TM], b[TN];
      #pragma unroll
      for (int ii = 0; ii < TM/4; ii++)
        *(float4*)&a[ii*4] = *(const float4*)&at[k][rg*TM + ii*4];
      #pragma unroll
      for (int jj = 0; jj < TN/4; jj++)
        *(float4*)&b[jj*4] = *(const float4*)&bs[k][cg*TN + jj*4];
      #pragma unroll
      for (int ii = 0; ii < TM; ii++)
        #pragma unroll
        for (int jj = 0; jj < TN; jj++)
          acc[ii][jj] += a[ii]*b[jj];
    }
    __syncthreads();
  }
  float* C = Cp + (size_t)ks * N * BN;
  #pragma unroll
  for (int ii = 0; ii < TM; ii++)
    #pragma unroll
    for (int jj = 0; jj < TN/4; jj++)
      *(float4*)&C[(size_t)(m0 + rg*TM + ii)*BN + cg*TN + jj*4] =
        make_float4(acc[ii][jj*4], acc[ii][jj*4+1], acc[ii][jj*4+2], acc[ii][jj*4+3]);
}

// ---------- layer 1 fused: wave0 = f-side (z1f,z1cf), wave1 = t-side (Zs) ----------
__global__ void k_z1(const float* __restrict__ h, const int* __restrict__ nidx,
                     const float* __restrict__ ncos, const float* __restrict__ df,
                     const float* __restrict__ Y1p, const float* __restrict__ dA,
                     const float* __restrict__ WF1, const float* __restrict__ bF1,
                     const float* __restrict__ WC1, const float* __restrict__ bC1,
                     const float* __restrict__ WT1, const float* __restrict__ bT1,
                     float* __restrict__ z1f, float* __restrict__ z1cf,
                     float* __restrict__ Zs){
  int i = blockIdx.x, tid = threadIdx.x, w = tid >> 6, t = tid & 63;
  __shared__ float vu[2][H];
  if (w == 0){
    int j0 = nidx[i*4], j1 = nidx[i*4+1], j2 = nidx[i*4+2], j3 = nidx[i*4+3];
    float di = df[i];
    float w0 = ncos[i*4]  *di*df[j0];
    float w1 = ncos[i*4+1]*di*df[j1];
    float w2 = ncos[i*4+2]*di*df[j2];
    float w3 = ncos[i*4+3]*di*df[j3];
    vu[0][t] = w0*h[(size_t)j0*H+t] + w1*h[(size_t)j1*H+t]
             + w2*h[(size_t)j2*H+t] + w3*h[(size_t)j3*H+t];
  } else {
    float y = 0.f;
    #pragma unroll
    for (int p = 0; p < S1; p++) y += Y1p[(size_t)p*(N*H) + (size_t)i*H + t];
    vu[1][t] = dA[i] * y;
  }
  __syncthreads();
  const float* Wx = (w == 0) ? WF1 : WT1;
  const float* bx = (w == 0) ? bF1 : bT1;
  float a1 = bx[t], a2 = bC1[t];
  const float4* wx = (const float4*)(Wx + (size_t)t*H);
  const float4* wc = (const float4*)(WC1 + (size_t)t*H);
  const float4* vv = (const float4*)vu[w];
  #pragma unroll
  for (int c = 0; c < 16; c++){
    float4 x = vv[c], f = wx[c], g = wc[c];
    a1 += x.x*f.x + x.y*f.y + x.z*f.z + x.w*f.w;
    a2 += x.x*g.x + x.y*g.y + x.z*g.z + x.w*g.w;
  }
  if (w == 0){
    z1f [(size_t)i*H+t] = leaky(a1);
    z1cf[(size_t)i*H+t] = leaky(a2);
  } else {
    float di = dA[i];
    Zs[(size_t)i*128 + t]      = di*leaky(a1);
    Zs[(size_t)i*128 + 64 + t] = di*leaky(a2);
  }
}

// ---------- layer 2 fused: waves = (zf | zcf+Lcf | zt | zct+Lct) -> Z6 ----------
__global__ void k_z2(const float* __restrict__ z1f, const float* __restrict__ z1cf,
                     const int* __restrict__ nidx, const float* __restrict__ ncos,
                     const float* __restrict__ df,
                     const float* __restrict__ Y2p, const float* __restrict__ dA,
                     const float* __restrict__ WF2, const float* __restrict__ bF2,
                     const float* __restrict__ WC2, const float* __restrict__ bC2,
                     const float* __restrict__ WT2, const float* __restrict__ bT2,
                     float* __restrict__ Z6){
  int i = blockIdx.x, tid = threadIdx.x, w = tid >> 6, t = tid & 63;
  __shared__ float v[4][H];
  if (w < 2){
    int j0 = nidx[i*4], j1 = nidx[i*4+1], j2 = nidx[i*4+2], j3 = nidx[i*4+3];
    float di = df[i];
    float w0 = ncos[i*4]  *di*df[j0];
    float w1 = ncos[i*4+1]*di*df[j1];
    float w2 = ncos[i*4+2]*di*df[j2];
    float w3 = ncos[i*4+3]*di*df[j3];
    const float* src = (w == 0) ? z1f : z1cf;
    v[w][t] = w0*src[(size_t)j0*H+t] + w1*src[(size_t)j1*H+t]
            + w2*src[(size_t)j2*H+t] + w3*src[(size_t)j3*H+t];
  } else {
    int off = (w == 2) ? 0 : 64;
    float y = 0.f;
    #pragma unroll
    for (int p = 0; p < S2; p++) y += Y2p[(size_t)p*(N*128) + (size_t)i*128 + off + t];
    v[w][t] = dA[i] * y;
  }
  __syncthreads();
  const float* WM = (w == 0) ? WF2 : (w == 2) ? WT2 : WC2;
  const float* bb = (w == 0) ? bF2 : (w == 2) ? bT2 : bC2;
  float a = bb[t];
  const float4* wm = (const float4*)(WM + (size_t)t*H);
  const float4* vv = (const float4*)v[w];
  #pragma unroll
  for (int c = 0; c < 16; c++){
    float4 x = vv[c], f = wm[c];
    a += x.x*f.x + x.y*f.y + x.z*f.z + x.w*f.w;
  }
  float val = leaky(a);
  float* zr = Z6 + (size_t)i*384;
  if (w == 0){
    zr[Z_ZF + t] = val;
  } else if (w == 2){
    zr[Z_ZT + t] = val;
  } else {
    zr[(w == 1) ? Z_ZCF + t : Z_ZCT + t] = val;
    float s = waveRedSum(val*val);
    float m = sqrtf(s*(1.f/64.f)) + 1e-10f;
    zr[(w == 1) ? Z_LCF + t : Z_LCT + t] = val/m;
  }
}

// ---------- 64x64 reductions: RP blocks x 32 rows, coalesced Z6 stage ----------
__global__ __launch_bounds__(256) void k_reduce(const float* __restrict__ Z6,
                                                float* __restrict__ redP){
  __shared__ float rz[16*384];
  int tid = threadIdx.x;
  int d0 = (tid >> 3) * 2;     // 0..62 step 2
  int e0 = (tid & 7) * 8;      // 0..56 step 8
  float aStc[2][8] = {}, aSfc[2][8] = {}, aCff[2][8] = {}, aCft[2][8] = {}, aCtt[2][8] = {};
  float c0 = 0, c1 = 0, c2 = 0, c3 = 0;
  for (int st = 0; st < 2; st++){
    int r0 = blockIdx.x * 32 + st*16;
    const float4* src = (const float4*)(Z6 + (size_t)r0 * 384);
    float4* dst = (float4*)rz;
    #pragma unroll
    for (int u = 0; u < 6; u++) dst[tid + u*256] = src[tid + u*256];
    __syncthreads();
    for (int rr = 0; rr < 16; rr++){
      const float* bp = rz + rr*384;
      float vt0 = bp[Z_ZT +d0], vt1 = bp[Z_ZT +d0+1];
      float vf0 = bp[Z_ZF +d0], vf1 = bp[Z_ZF +d0+1];
      float lf0 = bp[Z_LCF+d0], lf1 = bp[Z_LCF+d0+1];
      float lt0 = bp[Z_LCT+d0], lt1 = bp[Z_LCT+d0+1];
      float bct[8], bcf[8], blf[8], blt[8];
      *(float4*)&bct[0] = *(const float4*)&bp[Z_ZCT+e0];
      *(float4*)&bct[4] = *(const float4*)&bp[Z_ZCT+e0+4];
      *(float4*)&bcf[0] = *(const float4*)&bp[Z_ZCF+e0];
      *(float4*)&bcf[4] = *(const float4*)&bp[Z_ZCF+e0+4];
      *(float4*)&blf[0] = *(const float4*)&bp[Z_LCF+e0];
      *(float4*)&blf[4] = *(const float4*)&bp[Z_LCF+e0+4];
      *(float4*)&blt[0] = *(const float4*)&bp[Z_LCT+e0];
      *(float4*)&blt[4] = *(const float4*)&bp[Z_LCT+e0+4];
      #pragma unroll
      for (int e = 0; e < 8; e++){
        aStc[0][e] += vt0*bct[e];  aStc[1][e] += vt1*bct[e];
        aSfc[0][e] += vf0*bcf[e];  aSfc[1][e] += vf1*bcf[e];
        aCff[0][e] += lf0*blf[e];  aCff[1][e] += lf1*blf[e];
        aCft[0][e] += lf0*blt[e];  aCft[1][e] += lf1*blt[e];
        aCtt[0][e] += lt0*blt[e];  aCtt[1][e] += lt1*blt[e];
      }
      if (tid < 64){
        c0 += bp[Z_ZT + tid]; c1 += bp[Z_ZCT + tid];
        c2 += bp[Z_ZF + tid]; c3 += bp[Z_ZCF + tid];
      }
    }
    __syncthreads();
  }
  float* rp = redP + (size_t)blockIdx.x * 20736;
  #pragma unroll
  for (int dd = 0; dd < 2; dd++){
    int idx = (d0+dd)*64 + e0;
    *(float4*)&rp[idx]           = make_float4(aStc[dd][0],aStc[dd][1],aStc[dd][2],aStc[dd][3]);
    *(float4*)&rp[idx+4]         = make_float4(aStc[dd][4],aStc[dd][5],aStc[dd][6],aStc[dd][7]);
    *(float4*)&rp[4096 +idx]     = make_float4(aSfc[dd][0],aSfc[dd][1],aSfc[dd][2],aSfc[dd][3]);
    *(float4*)&rp[4096 +idx+4]   = make_float4(aSfc[dd][4],aSfc[dd][5],aSfc[dd][6],aSfc[dd][7]);
    *(float4*)&rp[8192 +idx]     = make_float4(aCff[dd][0],aCff[dd][1],aCff[dd][2],aCff[dd][3]);
    *(float4*)&rp[8192 +idx+4]   = make_float4(aCff[dd][4],aCff[dd][5],aCff[dd][6],aCff[dd][7]);
    *(float4*)&rp[12288+idx]     = make_float4(aCft[dd][0],aCft[dd][1],aCft[dd][2],aCft[dd][3]);
    *(float4*)&rp[12288+idx+4]   = make_float4(aCft[dd][4],aCft[dd][5],aCft[dd][6],aCft[dd][7]);
    *(float4*)&rp[16384+idx]     = make_float4(aCtt[dd][0],aCtt[dd][1],aCtt[dd][2],aCtt[dd][3]);
    *(float4*)&rp[16384+idx+4]   = make_float4(aCtt[dd][4],aCtt[dd][5],aCtt[dd][6],aCtt[dd][7]);
  }
  if (tid < 64){
    rp[20480 + tid] = c0;
    rp[20544 + tid] = c1;
    rp[20608 + tid] = c2;
    rp[20672 + tid] = c3;
  }
}

// ---------- sum RP partial slabs into red ----------
__global__ void k_combine(const float* __restrict__ redP, float* __restrict__ red){
  int idx = blockIdx.x*256 + threadIdx.x;
  if (idx < 20736){
    float s = 0.f;
    #pragma unroll 8
    for (int p = 0; p < RP; p++) s += redP[(size_t)p*20736 + idx];
    red[idx] = s;
  }
}

// ---------- attention + output projection (reads Z6) ----------
__global__ void k_out(const float* __restrict__ Z6,
                      const float* __restrict__ Wa, const float* __restrict__ ba,
                      const float* __restrict__ q, const float* __restrict__ W2,
                      const float* __restrict__ b2, float* __restrict__ out){
  int i = blockIdx.x, t = threadIdx.x;
  __shared__ float z[3][H];
  __shared__ float zagg[H];
  const float* zr = Z6 + (size_t)i*384;
  float vzf = zr[Z_ZF + t], vzt = zr[Z_ZT + t];
  float vzc = 0.5f*(zr[Z_ZCF + t] + zr[Z_ZCT + t]);
  z[0][t] = vzf; z[1][t] = vzt; z[2][t] = vzc;
  __syncthreads();
  float qt = q[t], bat = ba[t];
  const float4* wa = (const float4*)(Wa + (size_t)t*H);
  float e[3];
  #pragma unroll
  for (int kk = 0; kk < 3; kk++){
    float a = bat;
    const float4* zz = (const float4*)z[kk];
    #pragma unroll
    for (int c = 0; c < 16; c++){
      float4 zv = zz[c], wv = wa[c];
      a += zv.x*wv.x + zv.y*wv.y + zv.z*wv.z + zv.w*wv.w;
    }
    float wk = tanhf(a);
    e[kk] = waveRedSum(wk*qt);
  }
  float mx = fmaxf(e[0], fmaxf(e[1], e[2]));
  float x0 = expf(e[0]-mx), x1 = expf(e[1]-mx), x2 = expf(e[2]-mx);
  float inv = 1.f/(x0+x1+x2);
  float a0 = x0*inv, a1 = x1*inv, a2 = x2*inv;
  zagg[t] = a0*vzf + a1*vzt + a2*vzc;
  __syncthreads();
  if (t < OUTD){
    float a = b2[t];
    const float* w2r = W2 + (size_t)t*H;
    #pragma unroll
    for (int c = 0; c < H; c++) a += zagg[c]*w2r[c];
    out[(size_t)i*OUTD + t] = a;
  }
}

// ---------- final scalars Lc, Ld ----------
__global__ void k_final(const float* __restrict__ red, float* __restrict__ out2){
  int tid = threadIdx.x;
  const float* Stc = red;
  const float* Sfc = red + 4096;
  const float* Cff = red + 8192;
  const float* Cft = red + 12288;
  const float* Ctt = red + 16384;
  const float* cst = red + 20480;
  const float* csct= red + 20544;
  const float* csf = red + 20608;
  const float* cscf= red + 20672;
  float sCff=0, sCft=0, sCtt=0, sM1=0, sM2=0;
  for (int u = tid*16; u < tid*16+16; u++){
    int d = u >> 6, e = u & 63;
    float m1 = Stc[u] - cst[d]*csct[e]*(1.f/2048.f);
    float m2 = Sfc[u] - csf[d]*cscf[e]*(1.f/2048.f);
    sM1 += m1*m1; sM2 += m2*m2;
    float cf = Cff[u], cx = Cft[u], ct = Ctt[u];
    sCff += cf*cf; sCft += cx*cx; sCtt += ct*ct;
  }
  __shared__ float rd[5][4];
  sCff = waveRedSum(sCff); sCft = waveRedSum(sCft); sCtt = waveRedSum(sCtt);
  sM1 = waveRedSum(sM1);   sM2 = waveRedSum(sM2);
  int w = tid >> 6, lane = tid & 63;
  if (lane == 0){ rd[0][w]=sCff; rd[1][w]=sCft; rd[2][w]=sCtt; rd[3][w]=sM1; rd[4][w]=sM2; }
  __syncthreads();
  if (tid == 0){
    float A0 = rd[0][0]+rd[0][1]+rd[0][2]+rd[0][3];
    float A1 = rd[1][0]+rd[1][1]+rd[1][2]+rd[1][3];
    float A2 = rd[2][0]+rd[2][1]+rd[2][2]+rd[2][3];
    float M1 = rd[3][0]+rd[3][1]+rd[3][2]+rd[3][3];
    float M2 = rd[4][0]+rd[4][1]+rd[4][2]+rd[4][3];
    out2[0] = (A0 - 2.f*A1 + A2) * (1.f/(2048.f*2048.f));
    out2[1] = (M1 + M2) * (1.f/(2047.f*2047.f));
  }
}

extern "C" void kernel_launch(void* const* d_in, const int* in_sizes, int n_in,
                              void* d_out, int out_size, void* d_ws, size_t ws_size,
                              hipStream_t stream) {
  const float* x   = (const float*)d_in[0];
  const float* A   = (const float*)d_in[1];
  const float* W1  = (const float*)d_in[3];
  const float* b1  = (const float*)d_in[4];
  const float* WF1 = (const float*)d_in[5];
  const float* bF1 = (const float*)d_in[6];
  const float* WF2 = (const float*)d_in[7];
  const float* bF2 = (const float*)d_in[8];
  const float* WT1 = (const float*)d_in[9];
  const float* bT1 = (const float*)d_in[10];
  const float* WT2 = (const float*)d_in[11];
  const float* bT2 = (const float*)d_in[12];
  const float* WC1 = (const float*)d_in[13];
  const float* bC1 = (const float*)d_in[14];
  const float* WC2 = (const float*)d_in[15];
  const float* bC2 = (const float*)d_in[16];
  const float* Wa  = (const float*)d_in[17];
  const float* ba  = (const float*)d_in[18];
  const float* q   = (const float*)d_in[19];
  const float* W2  = (const float*)d_in[20];
  const float* b2  = (const float*)d_in[21];
  float* out = (float*)d_out;

  float* W = (float*)d_ws;
  // persistent area
  float* h_   = W;                    // N*H
  float* hs   = h_  + N*H;            // N*H
  float* dA   = hs  + N*H;            // N
  float* sq   = dA  + N;              // N
  float* hsum = sq  + N;              // N
  float* df   = hsum+ N;              // N
  int*   nidx = (int*)(df + N);       // N*4
  float* ncos = (float*)(nidx + N*4); // N*4
  float* red  = ncos + N*4;           // 20736
  size_t RB   = (size_t)(red + 20736 - W);
  RB = (RB + 15) & ~(size_t)15;       // 16-float align
  float* DOT  = W + RB;               // N*N; dead after k_topk, overlaid:
  float* Z6   = DOT;                  // N*384               =   786,432 (live to end)
  float* P    = Z6  + (size_t)N*384;  // 2,097,152 shared partial pool
  float* Y1p  = P;                    // S1 * N*H  = 1,048,576 (dead after k_z1)
  float* Y2p  = P;                    // S2 * N*128 = 2,097,152 (dead after k_z2)
  float* redP = P;                    // RP * 20736 = 1,327,104 (after k_z2)
  float* Zs   = P   + 2097152;        // N*128 = 262,144
  float* z1f  = Zs  + (size_t)N*128;  // N*H
  float* z1cf = z1f + N*H;            // N*H   (ends at 3,407,872 <= N*N)

  k_rowsum<<<N, 256, 0, stream>>>(A, dA);
  k_h<<<N, 64, 0, stream>>>(x, W1, b1, dA, h_, hs, sq, hsum);
  k_gram<<<dim3(16,16), 256, 0, stream>>>(h_, DOT);
  k_topk<<<N, 256, 0, stream>>>(DOT, sq, hsum, nidx, ncos, df);

  k_gemm<64,64,4,4><<<dim3(32,S1), 256, 0, stream>>>(A, hs, Y1p, N/S1);
  k_z1<<<N, 128, 0, stream>>>(h_, nidx, ncos, df, Y1p, dA,
                              WF1, bF1, WC1, bC1, WT1, bT1, z1f, z1cf, Zs);
  k_gemm<64,128,4,8><<<dim3(32,S2), 256, 0, stream>>>(A, Zs, Y2p, N/S2);
  k_z2<<<N, 256, 0, stream>>>(z1f, z1cf, nidx, ncos, df, Y2p, dA,
                              WF2, bF2, WC2, bC2, WT2, bT2, Z6);
  k_reduce<<<RP, 256, 0, stream>>>(Z6, redP);
  k_combine<<<81, 256, 0, stream>>>(redP, red);
  k_out<<<N, 64, 0, stream>>>(Z6, Wa, ba, q, W2, b2, out);
  k_final<<<1, 256, 0, stream>>>(red, out + (size_t)N*OUTD);
}

// Round 5
// 256.758 us; speedup vs baseline: 2.8471x; 1.2113x over previous
//
#include <hip/hip_runtime.h>
#include <stdint.h>

#define N 2048
#define DIN 128
#define H 64
#define OUTD 7
#define RS 32    // k_reduce row-splits per product
#define S1 8     // gemm1 K-splits
#define S2 8     // gemm2 K-splits

// Z6 row layout: [zt(64) | zct(64) | zf(64) | zcf(64) | Lcf(64) | Lct(64)]
#define Z_ZT  0
#define Z_ZCT 64
#define Z_ZF  128
#define Z_ZCF 192
#define Z_LCF 256
#define Z_LCT 320

__device__ __forceinline__ float leaky(float x){ return x > 0.f ? x : 0.1f*x; }

__device__ __forceinline__ float waveRedSum(float v){
  #pragma unroll
  for (int o = 32; o > 0; o >>= 1) v += __shfl_xor(v, o, 64);
  return v;
}

__device__ __forceinline__ unsigned long long shflx64(unsigned long long v, int m){
  unsigned int lo = (unsigned int)v, hi = (unsigned int)(v >> 32);
  lo = (unsigned int)__shfl_xor((int)lo, m, 64);
  hi = (unsigned int)__shfl_xor((int)hi, m, 64);
  return ((unsigned long long)hi << 32) | lo;
}

// ---------- row sums of A -> dA = (rowsum + 1e-10)^-0.5 ----------
__global__ void k_rowsum(const float* __restrict__ A, float* __restrict__ dA){
  int i = blockIdx.x;
  const float4* row = (const float4*)(A + (size_t)i * N);
  float s = 0.f;
  for (int u = threadIdx.x; u < N/4; u += 256){
    float4 v = row[u];
    s += v.x + v.y + v.z + v.w;
  }
  __shared__ float red[4];
  s = waveRedSum(s);
  int wid = threadIdx.x >> 6, lane = threadIdx.x & 63;
  if (lane == 0) red[wid] = s;
  __syncthreads();
  if (threadIdx.x == 0){
    float t = red[0] + red[1] + red[2] + red[3];
    dA[i] = 1.0f / sqrtf(t + 1e-10f);
  }
}

// ---------- h = leaky(x @ W1^T + b1); also sq, hsum, hs = dA*h ----------
__global__ void k_h(const float* __restrict__ x, const float* __restrict__ W1,
                    const float* __restrict__ b1, const float* __restrict__ dA,
                    float* __restrict__ h, float* __restrict__ hs,
                    float* __restrict__ sq, float* __restrict__ hsum){
  int i = blockIdx.x, t = threadIdx.x;
  __shared__ float xr[DIN];
  xr[t]      = x[(size_t)i*DIN + t];
  xr[t + 64] = x[(size_t)i*DIN + t + 64];
  __syncthreads();
  float acc = b1[t];
  const float4* w  = (const float4*)(W1 + (size_t)t*DIN);
  const float4* xv = (const float4*)xr;
  #pragma unroll
  for (int c = 0; c < DIN/4; c++){
    float4 a = xv[c], b = w[c];
    acc += a.x*b.x + a.y*b.y + a.z*b.z + a.w*b.w;
  }
  float hv = leaky(acc);
  h [(size_t)i*H + t] = hv;
  hs[(size_t)i*H + t] = dA[i]*hv;
  float s2 = waveRedSum(hv*hv);
  float s1 = waveRedSum(hv);
  if (t == 0){ sq[i] = s2; hsum[i] = s1; }
}

// ---------- DOT = h @ h^T  (128x128 tile, 8x8 per thread, K=64) ----------
__global__ __launch_bounds__(256) void k_gram(const float* __restrict__ h,
                                              float* __restrict__ DOT){
  __shared__ float at[32][132];
  __shared__ float bt[32][132];
  int bi = blockIdx.x, bj = blockIdx.y;
  int tid = threadIdx.x;
  int rg = tid >> 4, cg = tid & 15;
  float acc[8][8] = {};
  for (int kc = 0; kc < 64; kc += 32){
    for (int u = tid; u < 1024; u += 256){
      int row = u >> 3, k4 = u & 7;
      float4 v = *(const float4*)(h + (size_t)(bi*128 + row)*H + kc + k4*4);
      at[k4*4+0][row] = v.x; at[k4*4+1][row] = v.y;
      at[k4*4+2][row] = v.z; at[k4*4+3][row] = v.w;
    }
    for (int u = tid; u < 1024; u += 256){
      int row = u >> 3, k4 = u & 7;
      float4 v = *(const float4*)(h + (size_t)(bj*128 + row)*H + kc + k4*4);
      bt[k4*4+0][row] = v.x; bt[k4*4+1][row] = v.y;
      bt[k4*4+2][row] = v.z; bt[k4*4+3][row] = v.w;
    }
    __syncthreads();
    for (int k = 0; k < 32; k++){
      float a[8], b[8];
      *(float4*)&a[0] = *(const float4*)&at[k][rg*8];
      *(float4*)&a[4] = *(const float4*)&at[k][rg*8+4];
      *(float4*)&b[0] = *(const float4*)&bt[k][cg*8];
      *(float4*)&b[4] = *(const float4*)&bt[k][cg*8+4];
      #pragma unroll
      for (int ii = 0; ii < 8; ii++)
        #pragma unroll
        for (int jj = 0; jj < 8; jj++)
          acc[ii][jj] += a[ii]*b[jj];
    }
    __syncthreads();
  }
  #pragma unroll
  for (int ii = 0; ii < 8; ii++){
    int r = bi*128 + rg*8 + ii;
    float* out = DOT + (size_t)r*N + bj*128 + cg*8;
    *(float4*)(out)   = make_float4(acc[ii][0], acc[ii][1], acc[ii][2], acc[ii][3]);
    *(float4*)(out+4) = make_float4(acc[ii][4], acc[ii][5], acc[ii][6], acc[ii][7]);
  }
}

// ---------- per-row top-4 + cos vals + df (fused) ----------
__global__ __launch_bounds__(256) void k_topk(const float* __restrict__ DOT,
      const float* __restrict__ sq, const float* __restrict__ hsum,
      int* __restrict__ nidx, float* __restrict__ ncos, float* __restrict__ df){
  int i = blockIdx.x, tid = threadIdx.x;
  __shared__ unsigned long long cand[1024];
  const float4* row = (const float4*)(DOT + (size_t)i * N);
  const float4* sq4 = (const float4*)sq;
  unsigned long long best[4] = {~0ULL, ~0ULL, ~0ULL, ~0ULL};
  #pragma unroll
  for (int blk = 0; blk < 2; blk++){
    int u = tid + blk*256;
    float4 d = row[u];
    float4 s = sq4[u];
    float kv[4] = { s.x - 2.f*d.x, s.y - 2.f*d.y, s.z - 2.f*d.z, s.w - 2.f*d.w };
    #pragma unroll
    for (int e = 0; e < 4; e++){
      unsigned int j = (unsigned int)(u*4 + e);
      unsigned int uk = __float_as_uint(kv[e]);
      uk = (uk & 0x80000000u) ? ~uk : (uk | 0x80000000u);
      unsigned long long c = ((unsigned long long)uk << 32) | j;
      if (c < best[3]){
        best[3] = c;
        unsigned long long t0;
        if (best[3] < best[2]){ t0 = best[2]; best[2] = best[3]; best[3] = t0; }
        if (best[2] < best[1]){ t0 = best[1]; best[1] = best[2]; best[2] = t0; }
        if (best[1] < best[0]){ t0 = best[0]; best[0] = best[1]; best[1] = t0; }
      }
    }
  }
  #pragma unroll
  for (int e = 0; e < 4; e++) cand[e*256 + tid] = best[e];
  __syncthreads();
  if (tid < 64){
    unsigned long long loc[16];
    #pragma unroll
    for (int e = 0; e < 16; e++) loc[e] = cand[e*64 + tid];
    unsigned long long w0=~0ULL, w1=~0ULL, w2=~0ULL, w3=~0ULL;
    #pragma unroll
    for (int r = 0; r < 4; r++){
      unsigned long long m = loc[0];
      #pragma unroll
      for (int e = 1; e < 16; e++) m = (loc[e] < m) ? loc[e] : m;
      unsigned long long g = m;
      #pragma unroll
      for (int o = 32; o > 0; o >>= 1){
        unsigned long long other = shflx64(g, o);
        if (other < g) g = other;
      }
      #pragma unroll
      for (int e = 0; e < 16; e++) if (loc[e] == g) loc[e] = ~0ULL;
      if (r == 0) w0 = g; else if (r == 1) w1 = g; else if (r == 2) w2 = g; else w3 = g;
    }
    float myc = 0.f;
    if (tid < 4){
      unsigned long long w = (tid==0) ? w0 : (tid==1) ? w1 : (tid==2) ? w2 : w3;
      unsigned int j = (unsigned int)w;
      unsigned int uk = (unsigned int)(w >> 32);
      float key = (uk & 0x80000000u) ? __uint_as_float(uk ^ 0x80000000u)
                                     : __uint_as_float(~uk);
      float sqj = sq[j];
      float dot = (sqj - key) * 0.5f;
      float hni = sqrtf(sq[i]), hnj = sqrtf(sqj);
      float cosv = dot/(hni*hnj)
                 + 1e-10f*(hsum[i]/hni + hsum[j]/hnj)
                 + 64.0f*1e-20f;
      nidx[i*4 + tid] = (int)j;
      ncos[i*4 + tid] = cosv;
      myc = cosv;
    }
    myc += __shfl_xor(myc, 1, 64);
    myc += __shfl_xor(myc, 2, 64);
    if (tid == 0) df[i] = 1.f / sqrtf(myc + 1e-10f);
  }
}

// ---------- C_partial[ks] = A[:, ksl] @ B[ksl, :]  (plain stores) ----------
template<int BM, int BN, int TM, int TN>
__global__ __launch_bounds__((BM/TM)*(BN/TN)) void k_gemm(
    const float* __restrict__ A, const float* __restrict__ B,
    float* __restrict__ Cp, int KC){
  constexpr int NT = (BM/TM)*(BN/TN);
  constexpr int CG = BN/TN;
  __shared__ float at[32][BM+4];
  __shared__ float bs[32][BN+4];
  int bm = blockIdx.x, ks = blockIdx.y;
  int tid = threadIdx.x;
  int rg = tid / CG, cg = tid % CG;
  int m0 = bm*BM, kbase = ks*KC;
  float acc[TM][TN] = {};
  for (int kc = 0; kc < KC; kc += 32){
    for (int u = tid; u < BM*8; u += NT){
      int row = u >> 3, k4 = u & 7;
      float4 v = *(const float4*)(A + (size_t)(m0+row)*N + kbase + kc + k4*4);
      at[k4*4+0][row] = v.x; at[k4*4+1][row] = v.y;
      at[k4*4+2][row] = v.z; at[k4*4+3][row] = v.w;
    }
    for (int u = tid; u < 32*(BN/4); u += NT){
      int kr = u / (BN/4), c4 = u % (BN/4);
      *(float4*)&bs[kr][c4*4] = *(const float4*)(B + (size_t)(kbase+kc+kr)*BN + c4*4);
    }
    __syncthreads();
    for (int k = 0; k < 32; k++){
      float a[TM], b[TN];
      #pragma unroll
      for (int ii = 0; ii < TM/4; ii++)
        *(float4*)&a[ii*4] = *(const float4*)&at[k][rg*TM + ii*4];
      #pragma unroll
      for (int jj = 0; jj < TN/4; jj++)
        *(float4*)&b[jj*4] = *(const float4*)&bs[k][cg*TN + jj*4];
      #pragma unroll
      for (int ii = 0; ii < TM; ii++)
        #pragma unroll
        for (int jj = 0; jj < TN; jj++)
          acc[ii][jj] += a[ii]*b[jj];
    }
    __syncthreads();
  }
  float* C = Cp + (size_t)ks * N * BN;
  #pragma unroll
  for (int ii = 0; ii < TM; ii++)
    #pragma unroll
    for (int jj = 0; jj < TN/4; jj++)
      *(float4*)&C[(size_t)(m0 + rg*TM + ii)*BN + cg*TN + jj*4] =
        make_float4(acc[ii][jj*4], acc[ii][jj*4+1], acc[ii][jj*4+2], acc[ii][jj*4+3]);
}

// ---------- layer 1 fused: wave0 = f-side (z1f,z1cf), wave1 = t-side (Zs) ----------
__global__ void k_z1(const float* __restrict__ h, const int* __restrict__ nidx,
                     const float* __restrict__ ncos, const float* __restrict__ df,
                     const float* __restrict__ Y1p, const float* __restrict__ dA,
                     const float* __restrict__ WF1, const float* __restrict__ bF1,
                     const float* __restrict__ WC1, const float* __restrict__ bC1,
                     const float* __restrict__ WT1, const float* __restrict__ bT1,
                     float* __restrict__ z1f, float* __restrict__ z1cf,
                     float* __restrict__ Zs){
  int i = blockIdx.x, tid = threadIdx.x, w = tid >> 6, t = tid & 63;
  __shared__ float vu[2][H];
  if (w == 0){
    int j0 = nidx[i*4], j1 = nidx[i*4+1], j2 = nidx[i*4+2], j3 = nidx[i*4+3];
    float di = df[i];
    float w0 = ncos[i*4]  *di*df[j0];
    float w1 = ncos[i*4+1]*di*df[j1];
    float w2 = ncos[i*4+2]*di*df[j2];
    float w3 = ncos[i*4+3]*di*df[j3];
    vu[0][t] = w0*h[(size_t)j0*H+t] + w1*h[(size_t)j1*H+t]
             + w2*h[(size_t)j2*H+t] + w3*h[(size_t)j3*H+t];
  } else {
    float y = 0.f;
    #pragma unroll
    for (int p = 0; p < S1; p++) y += Y1p[(size_t)p*(N*H) + (size_t)i*H + t];
    vu[1][t] = dA[i] * y;
  }
  __syncthreads();
  const float* Wx = (w == 0) ? WF1 : WT1;
  const float* bx = (w == 0) ? bF1 : bT1;
  float a1 = bx[t], a2 = bC1[t];
  const float4* wx = (const float4*)(Wx + (size_t)t*H);
  const float4* wc = (const float4*)(WC1 + (size_t)t*H);
  const float4* vv = (const float4*)vu[w];
  #pragma unroll
  for (int c = 0; c < 16; c++){
    float4 x = vv[c], f = wx[c], g = wc[c];
    a1 += x.x*f.x + x.y*f.y + x.z*f.z + x.w*f.w;
    a2 += x.x*g.x + x.y*g.y + x.z*g.z + x.w*g.w;
  }
  if (w == 0){
    z1f [(size_t)i*H+t] = leaky(a1);
    z1cf[(size_t)i*H+t] = leaky(a2);
  } else {
    float di = dA[i];
    Zs[(size_t)i*128 + t]      = di*leaky(a1);
    Zs[(size_t)i*128 + 64 + t] = di*leaky(a2);
  }
}

// ---------- layer 2 fused: waves = (zf | zcf+Lcf | zt | zct+Lct) -> Z6 ----------
__global__ void k_z2(const float* __restrict__ z1f, const float* __restrict__ z1cf,
                     const int* __restrict__ nidx, const float* __restrict__ ncos,
                     const float* __restrict__ df,
                     const float* __restrict__ Y2p, const float* __restrict__ dA,
                     const float* __restrict__ WF2, const float* __restrict__ bF2,
                     const float* __restrict__ WC2, const float* __restrict__ bC2,
                     const float* __restrict__ WT2, const float* __restrict__ bT2,
                     float* __restrict__ Z6){
  int i = blockIdx.x, tid = threadIdx.x, w = tid >> 6, t = tid & 63;
  __shared__ float v[4][H];
  if (w < 2){
    int j0 = nidx[i*4], j1 = nidx[i*4+1], j2 = nidx[i*4+2], j3 = nidx[i*4+3];
    float di = df[i];
    float w0 = ncos[i*4]  *di*df[j0];
    float w1 = ncos[i*4+1]*di*df[j1];
    float w2 = ncos[i*4+2]*di*df[j2];
    float w3 = ncos[i*4+3]*di*df[j3];
    const float* src = (w == 0) ? z1f : z1cf;
    v[w][t] = w0*src[(size_t)j0*H+t] + w1*src[(size_t)j1*H+t]
            + w2*src[(size_t)j2*H+t] + w3*src[(size_t)j3*H+t];
  } else {
    int off = (w == 2) ? 0 : 64;
    float y = 0.f;
    #pragma unroll
    for (int p = 0; p < S2; p++) y += Y2p[(size_t)p*(N*128) + (size_t)i*128 + off + t];
    v[w][t] = dA[i] * y;
  }
  __syncthreads();
  const float* WM = (w == 0) ? WF2 : (w == 2) ? WT2 : WC2;
  const float* bb = (w == 0) ? bF2 : (w == 2) ? bT2 : bC2;
  float a = bb[t];
  const float4* wm = (const float4*)(WM + (size_t)t*H);
  const float4* vv = (const float4*)v[w];
  #pragma unroll
  for (int c = 0; c < 16; c++){
    float4 x = vv[c], f = wm[c];
    a += x.x*f.x + x.y*f.y + x.z*f.z + x.w*f.w;
  }
  float val = leaky(a);
  float* zr = Z6 + (size_t)i*384;
  if (w == 0){
    zr[Z_ZF + t] = val;
  } else if (w == 2){
    zr[Z_ZT + t] = val;
  } else {
    zr[(w == 1) ? Z_ZCF + t : Z_ZCT + t] = val;
    float s = waveRedSum(val*val);
    float m = sqrtf(s*(1.f/64.f)) + 1e-10f;
    zr[(w == 1) ? Z_LCF + t : Z_LCT + t] = val/m;
  }
}

// ---------- k_reduce: 5 products x RS row-splits, 64x64 tile GEMM each ----------
// p0: zt^T@zct (+colsums zt,zct)  p1: zf^T@zcf (+colsums zf,zcf)
// p2: Lcf^T@Lcf   p3: Lcf^T@Lct   p4: Lct^T@Lct
__global__ __launch_bounds__(256) void k_reduce(const float* __restrict__ Z6,
                                                float* __restrict__ redP,
                                                float* __restrict__ colP){
  __shared__ float sa[64][68];
  __shared__ float sb[64][68];
  int p = blockIdx.x >> 5;     // RS = 32
  int s = blockIdx.x & 31;
  int tid = threadIdx.x;
  const int aoffT[5] = {Z_ZT,  Z_ZF,  Z_LCF, Z_LCF, Z_LCT};
  const int boffT[5] = {Z_ZCT, Z_ZCF, Z_LCF, Z_LCT, Z_LCT};
  int aoff = aoffT[p], boff = boffT[p];
  int r0 = s * 64;
  {
    int row = tid >> 4, c4 = (tid & 15) * 4;
    #pragma unroll
    for (int rr = 0; rr < 64; rr += 16){
      const float* zr = Z6 + (size_t)(r0 + row + rr) * 384;
      *(float4*)&sa[row + rr][c4] = *(const float4*)&zr[aoff + c4];
      *(float4*)&sb[row + rr][c4] = *(const float4*)&zr[boff + c4];
    }
  }
  __syncthreads();
  int rg = tid >> 4, cg = tid & 15;
  float acc[4][4] = {};
  #pragma unroll 8
  for (int k = 0; k < 64; k++){
    float a[4], b[4];
    *(float4*)a = *(const float4*)&sa[k][rg*4];
    *(float4*)b = *(const float4*)&sb[k][cg*4];
    #pragma unroll
    for (int ii = 0; ii < 4; ii++)
      #pragma unroll
      for (int jj = 0; jj < 4; jj++)
        acc[ii][jj] += a[ii]*b[jj];
  }
  float* rp = redP + (size_t)blockIdx.x * 4096;
  #pragma unroll
  for (int ii = 0; ii < 4; ii++)
    *(float4*)&rp[(rg*4+ii)*64 + cg*4] =
      make_float4(acc[ii][0], acc[ii][1], acc[ii][2], acc[ii][3]);
  if (p < 2 && tid < 128){
    int t = tid & 63;
    float csum = 0.f;
    if (tid < 64){
      #pragma unroll 16
      for (int r = 0; r < 64; r++) csum += sa[r][t];
    } else {
      #pragma unroll 16
      for (int r = 0; r < 64; r++) csum += sb[r][t];
    }
    colP[((size_t)p*RS + s)*128 + tid] = csum;
  }
}

// ---------- sum partial slabs into red ----------
__global__ void k_combine(const float* __restrict__ redP,
                          const float* __restrict__ colP,
                          float* __restrict__ red){
  int idx = blockIdx.x*256 + threadIdx.x;
  if (idx < 20480){
    int p = idx >> 12, i = idx & 4095;
    float sum = 0.f;
    #pragma unroll 8
    for (int s = 0; s < RS; s++) sum += redP[((size_t)p*RS + s)*4096 + i];
    red[idx] = sum;
  } else if (idx < 20736){
    int j = idx - 20480;            // j = p*128 + seg*64 + t
    int p = j >> 7, rem = j & 127;
    float sum = 0.f;
    #pragma unroll 8
    for (int s = 0; s < RS; s++) sum += colP[((size_t)p*RS + s)*128 + rem];
    red[idx] = sum;
  }
}

// ---------- attention + output projection (reads Z6) ----------
__global__ void k_out(const float* __restrict__ Z6,
                      const float* __restrict__ Wa, const float* __restrict__ ba,
                      const float* __restrict__ q, const float* __restrict__ W2,
                      const float* __restrict__ b2, float* __restrict__ out){
  int i = blockIdx.x, t = threadIdx.x;
  __shared__ float z[3][H];
  __shared__ float zagg[H];
  const float* zr = Z6 + (size_t)i*384;
  float vzf = zr[Z_ZF + t], vzt = zr[Z_ZT + t];
  float vzc = 0.5f*(zr[Z_ZCF + t] + zr[Z_ZCT + t]);
  z[0][t] = vzf; z[1][t] = vzt; z[2][t] = vzc;
  __syncthreads();
  float qt = q[t], bat = ba[t];
  const float4* wa = (const float4*)(Wa + (size_t)t*H);
  float e[3];
  #pragma unroll
  for (int kk = 0; kk < 3; kk++){
    float a = bat;
    const float4* zz = (const float4*)z[kk];
    #pragma unroll
    for (int c = 0; c < 16; c++){
      float4 zv = zz[c], wv = wa[c];
      a += zv.x*wv.x + zv.y*wv.y + zv.z*wv.z + zv.w*wv.w;
    }
    float wk = tanhf(a);
    e[kk] = waveRedSum(wk*qt);
  }
  float mx = fmaxf(e[0], fmaxf(e[1], e[2]));
  float x0 = expf(e[0]-mx), x1 = expf(e[1]-mx), x2 = expf(e[2]-mx);
  float inv = 1.f/(x0+x1+x2);
  float a0 = x0*inv, a1 = x1*inv, a2 = x2*inv;
  zagg[t] = a0*vzf + a1*vzt + a2*vzc;
  __syncthreads();
  if (t < OUTD){
    float a = b2[t];
    const float* w2r = W2 + (size_t)t*H;
    #pragma unroll
    for (int c = 0; c < H; c++) a += zagg[c]*w2r[c];
    out[(size_t)i*OUTD + t] = a;
  }
}

// ---------- final scalars Lc, Ld ----------
__global__ void k_final(const float* __restrict__ red, float* __restrict__ out2){
  int tid = threadIdx.x;
  const float* Stc = red;
  const float* Sfc = red + 4096;
  const float* Cff = red + 8192;
  const float* Cft = red + 12288;
  const float* Ctt = red + 16384;
  const float* cst = red + 20480;
  const float* csct= red + 20544;
  const float* csf = red + 20608;
  const float* cscf= red + 20672;
  float sCff=0, sCft=0, sCtt=0, sM1=0, sM2=0;
  for (int u = tid*16; u < tid*16+16; u++){
    int d = u >> 6, e = u & 63;
    float m1 = Stc[u] - cst[d]*csct[e]*(1.f/2048.f);
    float m2 = Sfc[u] - csf[d]*cscf[e]*(1.f/2048.f);
    sM1 += m1*m1; sM2 += m2*m2;
    float cf = Cff[u], cx = Cft[u], ct = Ctt[u];
    sCff += cf*cf; sCft += cx*cx; sCtt += ct*ct;
  }
  __shared__ float rd[5][4];
  sCff = waveRedSum(sCff); sCft = waveRedSum(sCft); sCtt = waveRedSum(sCtt);
  sM1 = waveRedSum(sM1);   sM2 = waveRedSum(sM2);
  int w = tid >> 6, lane = tid & 63;
  if (lane == 0){ rd[0][w]=sCff; rd[1][w]=sCft; rd[2][w]=sCtt; rd[3][w]=sM1; rd[4][w]=sM2; }
  __syncthreads();
  if (tid == 0){
    float A0 = rd[0][0]+rd[0][1]+rd[0][2]+rd[0][3];
    float A1 = rd[1][0]+rd[1][1]+rd[1][2]+rd[1][3];
    float A2 = rd[2][0]+rd[2][1]+rd[2][2]+rd[2][3];
    float M1 = rd[3][0]+rd[3][1]+rd[3][2]+rd[3][3];
    float M2 = rd[4][0]+rd[4][1]+rd[4][2]+rd[4][3];
    out2[0] = (A0 - 2.f*A1 + A2) * (1.f/(2048.f*2048.f));
    out2[1] = (M1 + M2) * (1.f/(2047.f*2047.f));
  }
}

extern "C" void kernel_launch(void* const* d_in, const int* in_sizes, int n_in,
                              void* d_out, int out_size, void* d_ws, size_t ws_size,
                              hipStream_t stream) {
  const float* x   = (const float*)d_in[0];
  const float* A   = (const float*)d_in[1];
  const float* W1  = (const float*)d_in[3];
  const float* b1  = (const float*)d_in[4];
  const float* WF1 = (const float*)d_in[5];
  const float* bF1 = (const float*)d_in[6];
  const float* WF2 = (const float*)d_in[7];
  const float* bF2 = (const float*)d_in[8];
  const float* WT1 = (const float*)d_in[9];
  const float* bT1 = (const float*)d_in[10];
  const float* WT2 = (const float*)d_in[11];
  const float* bT2 = (const float*)d_in[12];
  const float* WC1 = (const float*)d_in[13];
  const float* bC1 = (const float*)d_in[14];
  const float* WC2 = (const float*)d_in[15];
  const float* bC2 = (const float*)d_in[16];
  const float* Wa  = (const float*)d_in[17];
  const float* ba  = (const float*)d_in[18];
  const float* q   = (const float*)d_in[19];
  const float* W2  = (const float*)d_in[20];
  const float* b2  = (const float*)d_in[21];
  float* out = (float*)d_out;

  float* W = (float*)d_ws;
  // persistent area
  float* h_   = W;                    // N*H
  float* hs   = h_  + N*H;            // N*H
  float* dA   = hs  + N*H;            // N
  float* sq   = dA  + N;              // N
  float* hsum = sq  + N;              // N
  float* df   = hsum+ N;              // N
  int*   nidx = (int*)(df + N);       // N*4
  float* ncos = (float*)(nidx + N*4); // N*4
  float* red  = ncos + N*4;           // 20736
  size_t RB   = (size_t)(red + 20736 - W);
  RB = (RB + 15) & ~(size_t)15;       // 16-float align
  float* DOT  = W + RB;               // N*N; dead after k_topk, overlaid:
  float* Z6   = DOT;                  // N*384               =   786,432 (live to end)
  float* P    = Z6  + (size_t)N*384;  // 2,097,152 shared partial pool
  float* Y1p  = P;                    // S1 * N*H  = 1,048,576 (dead after k_z1)
  float* Y2p  = P;                    // S2 * N*128 = 2,097,152 (dead after k_z2)
  float* redP = P;                    // 160*4096 = 655,360 (after k_z2)
  float* colP = P + 655360;           // 2*RS*128 = 8,192
  float* Zs   = P   + 2097152;        // N*128 = 262,144
  float* z1f  = Zs  + (size_t)N*128;  // N*H
  float* z1cf = z1f + N*H;            // N*H   (ends at 3,407,872 <= N*N)

  k_rowsum<<<N, 256, 0, stream>>>(A, dA);
  k_h<<<N, 64, 0, stream>>>(x, W1, b1, dA, h_, hs, sq, hsum);
  k_gram<<<dim3(16,16), 256, 0, stream>>>(h_, DOT);
  k_topk<<<N, 256, 0, stream>>>(DOT, sq, hsum, nidx, ncos, df);

  k_gemm<64,64,4,4><<<dim3(32,S1), 256, 0, stream>>>(A, hs, Y1p, N/S1);
  k_z1<<<N, 128, 0, stream>>>(h_, nidx, ncos, df, Y1p, dA,
                              WF1, bF1, WC1, bC1, WT1, bT1, z1f, z1cf, Zs);
  k_gemm<64,128,4,8><<<dim3(32,S2), 256, 0, stream>>>(A, Zs, Y2p, N/S2);
  k_z2<<<N, 256, 0, stream>>>(z1f, z1cf, nidx, ncos, df, Y2p, dA,
                              WF2, bF2, WC2, bC2, WT2, bT2, Z6);
  k_reduce<<<5*RS, 256, 0, stream>>>(Z6, redP, colP);
  k_combine<<<81, 256, 0, stream>>>(redP, colP, red);
  k_out<<<N, 64, 0, stream>>>(Z6, Wa, ba, q, W2, b2, out);
  k_final<<<1, 256, 0, stream>>>(red, out + (size_t)N*OUTD);
}

// Round 6
// 235.298 us; speedup vs baseline: 3.1067x; 1.0912x over previous
//
#include <hip/hip_runtime.h>
#include <stdint.h>

#define N 2048
#define DIN 128
#define H 64
#define OUTD 7
#define RS 32    // k_reduce row-splits per product
#define S1 8     // gemm1 K-splits
#define S2 8     // gemm2 K-splits

// Z6 row layout: [zt(64) | zct(64) | zf(64) | zcf(64) | Lcf(64) | Lct(64)]
#define Z_ZT  0
#define Z_ZCT 64
#define Z_ZF  128
#define Z_ZCF 192
#define Z_LCF 256
#define Z_LCT 320

typedef short bf16x8 __attribute__((ext_vector_type(8)));
typedef float floatx4 __attribute__((ext_vector_type(4)));

__device__ __forceinline__ float leaky(float x){ return x > 0.f ? x : 0.1f*x; }

__device__ __forceinline__ unsigned short f2bf(float f){
  unsigned int u = __float_as_uint(f);
  u = u + 0x7FFFu + ((u >> 16) & 1u);   // RNE
  return (unsigned short)(u >> 16);
}

__device__ __forceinline__ float waveRedSum(float v){
  #pragma unroll
  for (int o = 32; o > 0; o >>= 1) v += __shfl_xor(v, o, 64);
  return v;
}

__device__ __forceinline__ unsigned long long shflx64(unsigned long long v, int m){
  unsigned int lo = (unsigned int)v, hi = (unsigned int)(v >> 32);
  lo = (unsigned int)__shfl_xor((int)lo, m, 64);
  hi = (unsigned int)__shfl_xor((int)hi, m, 64);
  return ((unsigned long long)hi << 32) | lo;
}

// ---------- row sums of A -> dA, and cast A -> bf16 (fused; one A read) ----------
__global__ void k_prep(const float* __restrict__ A, float* __restrict__ dA,
                       unsigned short* __restrict__ Abf){
  int i = blockIdx.x;
  const float4* row = (const float4*)(A + (size_t)i * N);
  unsigned short* ob = Abf + (size_t)i * N;
  float s = 0.f;
  #pragma unroll
  for (int it = 0; it < 2; it++){
    int u = threadIdx.x + it*256;
    float4 v = row[u];
    s += v.x + v.y + v.z + v.w;
    ushort4 o;
    o.x = f2bf(v.x); o.y = f2bf(v.y); o.z = f2bf(v.z); o.w = f2bf(v.w);
    *(ushort4*)&ob[u*4] = o;
  }
  __shared__ float red[4];
  s = waveRedSum(s);
  int wid = threadIdx.x >> 6, lane = threadIdx.x & 63;
  if (lane == 0) red[wid] = s;
  __syncthreads();
  if (threadIdx.x == 0){
    float t = red[0] + red[1] + red[2] + red[3];
    dA[i] = 1.0f / sqrtf(t + 1e-10f);
  }
}

// ---------- h = leaky(x @ W1^T + b1); sq, hsum; hsT = (dA*h)^T bf16 ----------
__global__ void k_h(const float* __restrict__ x, const float* __restrict__ W1,
                    const float* __restrict__ b1, const float* __restrict__ dA,
                    float* __restrict__ h, unsigned short* __restrict__ hsT,
                    float* __restrict__ sq, float* __restrict__ hsum){
  int i = blockIdx.x, t = threadIdx.x;
  __shared__ float xr[DIN];
  xr[t]      = x[(size_t)i*DIN + t];
  xr[t + 64] = x[(size_t)i*DIN + t + 64];
  __syncthreads();
  float acc = b1[t];
  const float4* w  = (const float4*)(W1 + (size_t)t*DIN);
  const float4* xv = (const float4*)xr;
  #pragma unroll
  for (int c = 0; c < DIN/4; c++){
    float4 a = xv[c], b = w[c];
    acc += a.x*b.x + a.y*b.y + a.z*b.z + a.w*b.w;
  }
  float hv = leaky(acc);
  h[(size_t)i*H + t] = hv;
  hsT[(size_t)t*N + i] = f2bf(dA[i]*hv);
  float s2 = waveRedSum(hv*hv);
  float s1 = waveRedSum(hv);
  if (t == 0){ sq[i] = s2; hsum[i] = s1; }
}

// ---------- DOT = h @ h^T  (fp32: feeds discrete top-k; 128x128 tile) ----------
__global__ __launch_bounds__(256) void k_gram(const float* __restrict__ h,
                                              float* __restrict__ DOT){
  __shared__ float at[32][132];
  __shared__ float bt[32][132];
  int bi = blockIdx.x, bj = blockIdx.y;
  int tid = threadIdx.x;
  int rg = tid >> 4, cg = tid & 15;
  float acc[8][8] = {};
  for (int kc = 0; kc < 64; kc += 32){
    for (int u = tid; u < 1024; u += 256){
      int row = u >> 3, k4 = u & 7;
      float4 v = *(const float4*)(h + (size_t)(bi*128 + row)*H + kc + k4*4);
      at[k4*4+0][row] = v.x; at[k4*4+1][row] = v.y;
      at[k4*4+2][row] = v.z; at[k4*4+3][row] = v.w;
    }
    for (int u = tid; u < 1024; u += 256){
      int row = u >> 3, k4 = u & 7;
      float4 v = *(const float4*)(h + (size_t)(bj*128 + row)*H + kc + k4*4);
      bt[k4*4+0][row] = v.x; bt[k4*4+1][row] = v.y;
      bt[k4*4+2][row] = v.z; bt[k4*4+3][row] = v.w;
    }
    __syncthreads();
    for (int k = 0; k < 32; k++){
      float a[8], b[8];
      *(float4*)&a[0] = *(const float4*)&at[k][rg*8];
      *(float4*)&a[4] = *(const float4*)&at[k][rg*8+4];
      *(float4*)&b[0] = *(const float4*)&bt[k][cg*8];
      *(float4*)&b[4] = *(const float4*)&bt[k][cg*8+4];
      #pragma unroll
      for (int ii = 0; ii < 8; ii++)
        #pragma unroll
        for (int jj = 0; jj < 8; jj++)
          acc[ii][jj] += a[ii]*b[jj];
    }
    __syncthreads();
  }
  #pragma unroll
  for (int ii = 0; ii < 8; ii++){
    int r = bi*128 + rg*8 + ii;
    float* out = DOT + (size_t)r*N + bj*128 + cg*8;
    *(float4*)(out)   = make_float4(acc[ii][0], acc[ii][1], acc[ii][2], acc[ii][3]);
    *(float4*)(out+4) = make_float4(acc[ii][4], acc[ii][5], acc[ii][6], acc[ii][7]);
  }
}

// ---------- per-row top-4 + cos vals + df (fused) ----------
__global__ __launch_bounds__(256) void k_topk(const float* __restrict__ DOT,
      const float* __restrict__ sq, const float* __restrict__ hsum,
      int* __restrict__ nidx, float* __restrict__ ncos, float* __restrict__ df){
  int i = blockIdx.x, tid = threadIdx.x;
  __shared__ unsigned long long cand[1024];
  const float4* row = (const float4*)(DOT + (size_t)i * N);
  const float4* sq4 = (const float4*)sq;
  unsigned long long best[4] = {~0ULL, ~0ULL, ~0ULL, ~0ULL};
  #pragma unroll
  for (int blk = 0; blk < 2; blk++){
    int u = tid + blk*256;
    float4 d = row[u];
    float4 s = sq4[u];
    float kv[4] = { s.x - 2.f*d.x, s.y - 2.f*d.y, s.z - 2.f*d.z, s.w - 2.f*d.w };
    #pragma unroll
    for (int e = 0; e < 4; e++){
      unsigned int j = (unsigned int)(u*4 + e);
      unsigned int uk = __float_as_uint(kv[e]);
      uk = (uk & 0x80000000u) ? ~uk : (uk | 0x80000000u);
      unsigned long long c = ((unsigned long long)uk << 32) | j;
      if (c < best[3]){
        best[3] = c;
        unsigned long long t0;
        if (best[3] < best[2]){ t0 = best[2]; best[2] = best[3]; best[3] = t0; }
        if (best[2] < best[1]){ t0 = best[1]; best[1] = best[2]; best[2] = t0; }
        if (best[1] < best[0]){ t0 = best[0]; best[0] = best[1]; best[1] = t0; }
      }
    }
  }
  #pragma unroll
  for (int e = 0; e < 4; e++) cand[e*256 + tid] = best[e];
  __syncthreads();
  if (tid < 64){
    unsigned long long loc[16];
    #pragma unroll
    for (int e = 0; e < 16; e++) loc[e] = cand[e*64 + tid];
    unsigned long long w0=~0ULL, w1=~0ULL, w2=~0ULL, w3=~0ULL;
    #pragma unroll
    for (int r = 0; r < 4; r++){
      unsigned long long m = loc[0];
      #pragma unroll
      for (int e = 1; e < 16; e++) m = (loc[e] < m) ? loc[e] : m;
      unsigned long long g = m;
      #pragma unroll
      for (int o = 32; o > 0; o >>= 1){
        unsigned long long other = shflx64(g, o);
        if (other < g) g = other;
      }
      #pragma unroll
      for (int e = 0; e < 16; e++) if (loc[e] == g) loc[e] = ~0ULL;
      if (r == 0) w0 = g; else if (r == 1) w1 = g; else if (r == 2) w2 = g; else w3 = g;
    }
    float myc = 0.f;
    if (tid < 4){
      unsigned long long w = (tid==0) ? w0 : (tid==1) ? w1 : (tid==2) ? w2 : w3;
      unsigned int j = (unsigned int)w;
      unsigned int uk = (unsigned int)(w >> 32);
      float key = (uk & 0x80000000u) ? __uint_as_float(uk ^ 0x80000000u)
                                     : __uint_as_float(~uk);
      float sqj = sq[j];
      float dot = (sqj - key) * 0.5f;
      float hni = sqrtf(sq[i]), hnj = sqrtf(sqj);
      float cosv = dot/(hni*hnj)
                 + 1e-10f*(hsum[i]/hni + hsum[j]/hnj)
                 + 64.0f*1e-20f;
      nidx[i*4 + tid] = (int)j;
      ncos[i*4 + tid] = cosv;
      myc = cosv;
    }
    myc += __shfl_xor(myc, 1, 64);
    myc += __shfl_xor(myc, 2, 64);
    if (tid == 0) df[i] = 1.f / sqrtf(myc + 1e-10f);
  }
}

// ---------- MFMA bf16 GEMM: Cp[ks] = Abf[:,ksl] @ BtG^T[ksl,:] ----------
// BtG is the B operand stored transposed: BtG[n][k], n<BN, k<2048, bf16.
// frag layouts (m89/m92-verified): A[m=lane&15][k=quad*8+j]; B[n=lane&15][k=quad*8+j]
// C/D: col=lane&15, row=quad*4+reg.
template<int BN>
__global__ __launch_bounds__(256) void k_mgemm(
    const unsigned short* __restrict__ Abf, const unsigned short* __restrict__ BtG,
    float* __restrict__ Cp, int KC){
  __shared__ __align__(16) unsigned short Asl[64][72];
  __shared__ __align__(16) unsigned short Bsl[BN][72];
  int m0 = blockIdx.x * 64, kbase = blockIdx.y * KC;
  int tid = threadIdx.x;
  int w = tid >> 6, lane = tid & 63;
  int quad = lane >> 4, ml = lane & 15;
  floatx4 acc[BN/16];
  #pragma unroll
  for (int ct = 0; ct < BN/16; ct++) acc[ct] = (floatx4){0.f,0.f,0.f,0.f};

  for (int kc = 0; kc < KC; kc += 64){
    int kb = kbase + kc;
    #pragma unroll
    for (int u = tid; u < 512; u += 256){
      int r = u >> 3, s = u & 7;
      *(uint4*)&Asl[r][s*8] = *(const uint4*)(Abf + ((size_t)(m0+r) << 11) + kb + s*8);
    }
    #pragma unroll
    for (int u = tid; u < BN*8; u += 256){
      int n = u >> 3, s = u & 7;
      *(uint4*)&Bsl[n][s*8] = *(const uint4*)(BtG + ((size_t)n << 11) + kb + s*8);
    }
    __syncthreads();
    #pragma unroll
    for (int k0 = 0; k0 < 64; k0 += 32){
      bf16x8 af = *(const bf16x8*)&Asl[16*w + ml][k0 + quad*8];
      #pragma unroll
      for (int ct = 0; ct < BN/16; ct++){
        bf16x8 bfr = *(const bf16x8*)&Bsl[16*ct + ml][k0 + quad*8];
        acc[ct] = __builtin_amdgcn_mfma_f32_16x16x32_bf16(af, bfr, acc[ct], 0, 0, 0);
      }
    }
    __syncthreads();
  }
  float* C = Cp + (size_t)blockIdx.y * (N * BN);
  #pragma unroll
  for (int ct = 0; ct < BN/16; ct++)
    #pragma unroll
    for (int r = 0; r < 4; r++){
      int row = m0 + 16*w + quad*4 + r;
      C[(size_t)row*BN + 16*ct + ml] = acc[ct][r];
    }
}

// ---------- layer 1 fused: wave0 = f-side (z1f,z1cf), wave1 = t-side -> ZsT ----------
__global__ void k_z1(const float* __restrict__ h, const int* __restrict__ nidx,
                     const float* __restrict__ ncos, const float* __restrict__ df,
                     const float* __restrict__ Y1p, const float* __restrict__ dA,
                     const float* __restrict__ WF1, const float* __restrict__ bF1,
                     const float* __restrict__ WC1, const float* __restrict__ bC1,
                     const float* __restrict__ WT1, const float* __restrict__ bT1,
                     float* __restrict__ z1f, float* __restrict__ z1cf,
                     unsigned short* __restrict__ ZsT){
  int i = blockIdx.x, tid = threadIdx.x, w = tid >> 6, t = tid & 63;
  __shared__ float vu[2][H];
  if (w == 0){
    int j0 = nidx[i*4], j1 = nidx[i*4+1], j2 = nidx[i*4+2], j3 = nidx[i*4+3];
    float di = df[i];
    float w0 = ncos[i*4]  *di*df[j0];
    float w1 = ncos[i*4+1]*di*df[j1];
    float w2 = ncos[i*4+2]*di*df[j2];
    float w3 = ncos[i*4+3]*di*df[j3];
    vu[0][t] = w0*h[(size_t)j0*H+t] + w1*h[(size_t)j1*H+t]
             + w2*h[(size_t)j2*H+t] + w3*h[(size_t)j3*H+t];
  } else {
    float y = 0.f;
    #pragma unroll
    for (int p = 0; p < S1; p++) y += Y1p[(size_t)p*(N*H) + (size_t)i*H + t];
    vu[1][t] = dA[i] * y;
  }
  __syncthreads();
  const float* Wx = (w == 0) ? WF1 : WT1;
  const float* bx = (w == 0) ? bF1 : bT1;
  float a1 = bx[t], a2 = bC1[t];
  const float4* wx = (const float4*)(Wx + (size_t)t*H);
  const float4* wc = (const float4*)(WC1 + (size_t)t*H);
  const float4* vv = (const float4*)vu[w];
  #pragma unroll
  for (int c = 0; c < 16; c++){
    float4 x = vv[c], f = wx[c], g = wc[c];
    a1 += x.x*f.x + x.y*f.y + x.z*f.z + x.w*f.w;
    a2 += x.x*g.x + x.y*g.y + x.z*g.z + x.w*g.w;
  }
  if (w == 0){
    z1f [(size_t)i*H+t] = leaky(a1);
    z1cf[(size_t)i*H+t] = leaky(a2);
  } else {
    float di = dA[i];
    ZsT[(size_t)t*N + i]        = f2bf(di*leaky(a1));
    ZsT[(size_t)(64+t)*N + i]   = f2bf(di*leaky(a2));
  }
}

// ---------- layer 2 + attention + out, fused.  waves: zf | zcf,Lcf | zt | zct,Lct ----------
__global__ void k_z2o(const float* __restrict__ z1f, const float* __restrict__ z1cf,
                      const int* __restrict__ nidx, const float* __restrict__ ncos,
                      const float* __restrict__ df,
                      const float* __restrict__ Y2p, const float* __restrict__ dA,
                      const float* __restrict__ WF2, const float* __restrict__ bF2,
                      const float* __restrict__ WC2, const float* __restrict__ bC2,
                      const float* __restrict__ WT2, const float* __restrict__ bT2,
                      const float* __restrict__ Wa, const float* __restrict__ ba,
                      const float* __restrict__ q, const float* __restrict__ W2,
                      const float* __restrict__ b2,
                      float* __restrict__ Z6, float* __restrict__ out){
  int i = blockIdx.x, tid = threadIdx.x, w = tid >> 6, t = tid & 63;
  __shared__ float v[4][H];
  __shared__ float zsh[4][H];   // 0:zf 1:zt 2:zcf 3:zct
  __shared__ float esh[3];
  __shared__ float zagg[H];
  if (w < 2){
    int j0 = nidx[i*4], j1 = nidx[i*4+1], j2 = nidx[i*4+2], j3 = nidx[i*4+3];
    float di = df[i];
    float w0 = ncos[i*4]  *di*df[j0];
    float w1 = ncos[i*4+1]*di*df[j1];
    float w2 = ncos[i*4+2]*di*df[j2];
    float w3 = ncos[i*4+3]*di*df[j3];
    const float* src = (w == 0) ? z1f : z1cf;
    v[w][t] = w0*src[(size_t)j0*H+t] + w1*src[(size_t)j1*H+t]
            + w2*src[(size_t)j2*H+t] + w3*src[(size_t)j3*H+t];
  } else {
    int off = (w == 2) ? 0 : 64;
    float y = 0.f;
    #pragma unroll
    for (int p = 0; p < S2; p++) y += Y2p[(size_t)p*(N*128) + (size_t)i*128 + off + t];
    v[w][t] = dA[i] * y;
  }
  __syncthreads();
  const float* WM = (w == 0) ? WF2 : (w == 2) ? WT2 : WC2;
  const float* bb = (w == 0) ? bF2 : (w == 2) ? bT2 : bC2;
  float a = bb[t];
  const float4* wm = (const float4*)(WM + (size_t)t*H);
  const float4* vv = (const float4*)v[w];
  #pragma unroll
  for (int c = 0; c < 16; c++){
    float4 x = vv[c], f = wm[c];
    a += x.x*f.x + x.y*f.y + x.z*f.z + x.w*f.w;
  }
  float val = leaky(a);
  float* zr = Z6 + (size_t)i*384;
  if (w == 0){
    zr[Z_ZF + t] = val;  zsh[0][t] = val;
  } else if (w == 2){
    zr[Z_ZT + t] = val;  zsh[1][t] = val;
  } else {
    int cf = (w == 1);
    zr[(cf ? Z_ZCF : Z_ZCT) + t] = val;
    zsh[cf ? 2 : 3][t] = val;
    float s = waveRedSum(val*val);
    float m = sqrtf(s*(1.f/64.f)) + 1e-10f;
    zr[(cf ? Z_LCF : Z_LCT) + t] = val/m;
  }
  __syncthreads();
  // attention scores: wave k (k<3) handles z_k in {zf, zt, zc}
  if (w < 3){
    float aa = ba[t];
    const float4* wa = (const float4*)(Wa + (size_t)t*H);
    const float4* z0 = (const float4*)zsh[w == 0 ? 0 : (w == 1 ? 1 : 2)];
    const float4* z3 = (const float4*)zsh[3];
    #pragma unroll
    for (int c = 0; c < 16; c++){
      float4 wv = wa[c];
      float4 zv = z0[c];
      if (w == 2){
        float4 z2v = z3[c];
        zv.x = 0.5f*(zv.x + z2v.x); zv.y = 0.5f*(zv.y + z2v.y);
        zv.z = 0.5f*(zv.z + z2v.z); zv.w = 0.5f*(zv.w + z2v.w);
      }
      aa += zv.x*wv.x + zv.y*wv.y + zv.z*wv.z + zv.w*wv.w;
    }
    float wk = tanhf(aa);
    float e = waveRedSum(wk*q[t]);
    if (t == 0) esh[w] = e;
  }
  __syncthreads();
  if (w == 3){
    float e0 = esh[0], e1 = esh[1], e2 = esh[2];
    float mx = fmaxf(e0, fmaxf(e1, e2));
    float x0 = expf(e0-mx), x1 = expf(e1-mx), x2 = expf(e2-mx);
    float inv = 1.f/(x0+x1+x2);
    float a0 = x0*inv, a1 = x1*inv, a2 = x2*inv;
    zagg[t] = a0*zsh[0][t] + a1*zsh[1][t] + a2*0.5f*(zsh[2][t] + zsh[3][t]);
    if (t < OUTD){
      float acc2 = b2[t];
      const float* w2r = W2 + (size_t)t*H;
      #pragma unroll
      for (int c = 0; c < H; c++) acc2 += zagg[c]*w2r[c];
      out[(size_t)i*OUTD + t] = acc2;
    }
  }
}

// ---------- k_reduce: 5 products x RS row-splits, 64x64 tile GEMM each ----------
__global__ __launch_bounds__(256) void k_reduce(const float* __restrict__ Z6,
                                                float* __restrict__ redP,
                                                float* __restrict__ colP){
  __shared__ float sa[64][68];
  __shared__ float sb[64][68];
  int p = blockIdx.x >> 5;     // RS = 32
  int s = blockIdx.x & 31;
  int tid = threadIdx.x;
  const int aoffT[5] = {Z_ZT,  Z_ZF,  Z_LCF, Z_LCF, Z_LCT};
  const int boffT[5] = {Z_ZCT, Z_ZCF, Z_LCF, Z_LCT, Z_LCT};
  int aoff = aoffT[p], boff = boffT[p];
  int r0 = s * 64;
  {
    int row = tid >> 4, c4 = (tid & 15) * 4;
    #pragma unroll
    for (int rr = 0; rr < 64; rr += 16){
      const float* zr = Z6 + (size_t)(r0 + row + rr) * 384;
      *(float4*)&sa[row + rr][c4] = *(const float4*)&zr[aoff + c4];
      *(float4*)&sb[row + rr][c4] = *(const float4*)&zr[boff + c4];
    }
  }
  __syncthreads();
  int rg = tid >> 4, cg = tid & 15;
  float acc[4][4] = {};
  #pragma unroll 8
  for (int k = 0; k < 64; k++){
    float a[4], b[4];
    *(float4*)a = *(const float4*)&sa[k][rg*4];
    *(float4*)b = *(const float4*)&sb[k][cg*4];
    #pragma unroll
    for (int ii = 0; ii < 4; ii++)
      #pragma unroll
      for (int jj = 0; jj < 4; jj++)
        acc[ii][jj] += a[ii]*b[jj];
  }
  float* rp = redP + (size_t)blockIdx.x * 4096;
  #pragma unroll
  for (int ii = 0; ii < 4; ii++)
    *(float4*)&rp[(rg*4+ii)*64 + cg*4] =
      make_float4(acc[ii][0], acc[ii][1], acc[ii][2], acc[ii][3]);
  if (p < 2 && tid < 128){
    int t = tid & 63;
    float csum = 0.f;
    if (tid < 64){
      #pragma unroll 16
      for (int r = 0; r < 64; r++) csum += sa[r][t];
    } else {
      #pragma unroll 16
      for (int r = 0; r < 64; r++) csum += sb[r][t];
    }
    colP[((size_t)p*RS + s)*128 + tid] = csum;
  }
}

// ---------- sum partial slabs into red ----------
__global__ void k_combine(const float* __restrict__ redP,
                          const float* __restrict__ colP,
                          float* __restrict__ red){
  int idx = blockIdx.x*256 + threadIdx.x;
  if (idx < 20480){
    int p = idx >> 12, i = idx & 4095;
    float sum = 0.f;
    #pragma unroll 8
    for (int s = 0; s < RS; s++) sum += redP[((size_t)p*RS + s)*4096 + i];
    red[idx] = sum;
  } else if (idx < 20736){
    int j = idx - 20480;
    int p = j >> 7, rem = j & 127;
    float sum = 0.f;
    #pragma unroll 8
    for (int s = 0; s < RS; s++) sum += colP[((size_t)p*RS + s)*128 + rem];
    red[idx] = sum;
  }
}

// ---------- final scalars Lc, Ld ----------
__global__ void k_final(const float* __restrict__ red, float* __restrict__ out2){
  int tid = threadIdx.x;
  const float* Stc = red;
  const float* Sfc = red + 4096;
  const float* Cff = red + 8192;
  const float* Cft = red + 12288;
  const float* Ctt = red + 16384;
  const float* cst = red + 20480;
  const float* csct= red + 20544;
  const float* csf = red + 20608;
  const float* cscf= red + 20672;
  float sCff=0, sCft=0, sCtt=0, sM1=0, sM2=0;
  for (int u = tid*16; u < tid*16+16; u++){
    int d = u >> 6, e = u & 63;
    float m1 = Stc[u] - cst[d]*csct[e]*(1.f/2048.f);
    float m2 = Sfc[u] - csf[d]*cscf[e]*(1.f/2048.f);
    sM1 += m1*m1; sM2 += m2*m2;
    float cf = Cff[u], cx = Cft[u], ct = Ctt[u];
    sCff += cf*cf; sCft += cx*cx; sCtt += ct*ct;
  }
  __shared__ float rd[5][4];
  sCff = waveRedSum(sCff); sCft = waveRedSum(sCft); sCtt = waveRedSum(sCtt);
  sM1 = waveRedSum(sM1);   sM2 = waveRedSum(sM2);
  int w = tid >> 6, lane = tid & 63;
  if (lane == 0){ rd[0][w]=sCff; rd[1][w]=sCft; rd[2][w]=sCtt; rd[3][w]=sM1; rd[4][w]=sM2; }
  __syncthreads();
  if (tid == 0){
    float A0 = rd[0][0]+rd[0][1]+rd[0][2]+rd[0][3];
    float A1 = rd[1][0]+rd[1][1]+rd[1][2]+rd[1][3];
    float A2 = rd[2][0]+rd[2][1]+rd[2][2]+rd[2][3];
    float M1 = rd[3][0]+rd[3][1]+rd[3][2]+rd[3][3];
    float M2 = rd[4][0]+rd[4][1]+rd[4][2]+rd[4][3];
    out2[0] = (A0 - 2.f*A1 + A2) * (1.f/(2048.f*2048.f));
    out2[1] = (M1 + M2) * (1.f/(2047.f*2047.f));
  }
}

extern "C" void kernel_launch(void* const* d_in, const int* in_sizes, int n_in,
                              void* d_out, int out_size, void* d_ws, size_t ws_size,
                              hipStream_t stream) {
  const float* x   = (const float*)d_in[0];
  const float* A   = (const float*)d_in[1];
  const float* W1  = (const float*)d_in[3];
  const float* b1  = (const float*)d_in[4];
  const float* WF1 = (const float*)d_in[5];
  const float* bF1 = (const float*)d_in[6];
  const float* WF2 = (const float*)d_in[7];
  const float* bF2 = (const float*)d_in[8];
  const float* WT1 = (const float*)d_in[9];
  const float* bT1 = (const float*)d_in[10];
  const float* WT2 = (const float*)d_in[11];
  const float* bT2 = (const float*)d_in[12];
  const float* WC1 = (const float*)d_in[13];
  const float* bC1 = (const float*)d_in[14];
  const float* WC2 = (const float*)d_in[15];
  const float* bC2 = (const float*)d_in[16];
  const float* Wa  = (const float*)d_in[17];
  const float* ba  = (const float*)d_in[18];
  const float* q   = (const float*)d_in[19];
  const float* W2  = (const float*)d_in[20];
  const float* b2  = (const float*)d_in[21];
  float* out = (float*)d_out;

  // workspace is 256 MiB (fill evidence, round 5) — plain linear layout, no overlays
  float* W = (float*)d_ws;
  float* h_   = W;                      // N*H
  float* dA   = h_  + N*H;              // N
  float* sq   = dA  + N;                // N
  float* hsum = sq  + N;                // N
  float* df   = hsum+ N;                // N
  int*   nidx = (int*)(df + N);         // N*4
  float* ncos = (float*)(nidx + N*4);   // N*4
  float* red  = ncos + N*4;             // 20736
  float* DOT  = red + 20736;            // N*N
  float* Z6   = DOT + (size_t)N*N;      // N*384
  float* Y1p  = Z6  + (size_t)N*384;    // S1*N*H
  float* Y2p  = Y1p + (size_t)S1*N*H;   // S2*N*128
  float* z1f  = Y2p + (size_t)S2*N*128; // N*H
  float* z1cf = z1f + N*H;              // N*H
  float* redP = z1cf+ N*H;              // 5*RS*4096 = 655360
  float* colP = redP+ 655360;           // 2*RS*128 = 8192
  unsigned short* Abf = (unsigned short*)(colP + 8192);  // N*N bf16
  unsigned short* hsT = Abf + (size_t)N*N;               // 64*N bf16
  unsigned short* ZsT = hsT + (size_t)H*N;               // 128*N bf16

  k_prep<<<N, 256, 0, stream>>>(A, dA, Abf);
  k_h<<<N, 64, 0, stream>>>(x, W1, b1, dA, h_, hsT, sq, hsum);
  k_gram<<<dim3(16,16), 256, 0, stream>>>(h_, DOT);
  k_topk<<<N, 256, 0, stream>>>(DOT, sq, hsum, nidx, ncos, df);

  k_mgemm<64><<<dim3(32,S1), 256, 0, stream>>>(Abf, hsT, Y1p, N/S1);
  k_z1<<<N, 128, 0, stream>>>(h_, nidx, ncos, df, Y1p, dA,
                              WF1, bF1, WC1, bC1, WT1, bT1, z1f, z1cf, ZsT);
  k_mgemm<128><<<dim3(32,S2), 256, 0, stream>>>(Abf, ZsT, Y2p, N/S2);
  k_z2o<<<N, 256, 0, stream>>>(z1f, z1cf, nidx, ncos, df, Y2p, dA,
                               WF2, bF2, WC2, bC2, WT2, bT2,
                               Wa, ba, q, W2, b2, Z6, out);
  k_reduce<<<5*RS, 256, 0, stream>>>(Z6, redP, colP);
  k_combine<<<81, 256, 0, stream>>>(redP, colP, red);
  k_final<<<1, 256, 0, stream>>>(red, out + (size_t)N*OUTD);
}

// Round 7
// 232.553 us; speedup vs baseline: 3.1434x; 1.0118x over previous
//
#include <hip/hip_runtime.h>
#include <stdint.h>

#define N 2048
#define DIN 128
#define H 64
#define OUTD 7
#define RS 32    // k_reduce row-splits per product
#define S1 8     // gemm1 K-splits
#define S2 8     // gemm2 K-splits

// Z6 row layout: [zt(64) | zct(64) | zf(64) | zcf(64) | Lcf(64) | Lct(64)]
#define Z_ZT  0
#define Z_ZCT 64
#define Z_ZF  128
#define Z_ZCF 192
#define Z_LCF 256
#define Z_LCT 320

typedef short bf16x8 __attribute__((ext_vector_type(8)));
typedef float floatx4 __attribute__((ext_vector_type(4)));

__device__ __forceinline__ float leaky(float x){ return x > 0.f ? x : 0.1f*x; }

__device__ __forceinline__ unsigned short f2bf(float f){
  unsigned int u = __float_as_uint(f);
  u = u + 0x7FFFu + ((u >> 16) & 1u);   // RNE
  return (unsigned short)(u >> 16);
}

__device__ __forceinline__ float waveRedSum(float v){
  #pragma unroll
  for (int o = 32; o > 0; o >>= 1) v += __shfl_xor(v, o, 64);
  return v;
}

__device__ __forceinline__ unsigned long long shflx64(unsigned long long v, int m){
  unsigned int lo = (unsigned int)v, hi = (unsigned int)(v >> 32);
  lo = (unsigned int)__shfl_xor((int)lo, m, 64);
  hi = (unsigned int)__shfl_xor((int)hi, m, 64);
  return ((unsigned long long)hi << 32) | lo;
}

// ---------- row sums of A -> dA, and cast A -> bf16 (fused; one A read) ----------
__global__ void k_prep(const float* __restrict__ A, float* __restrict__ dA,
                       unsigned short* __restrict__ Abf){
  int i = blockIdx.x;
  const float4* row = (const float4*)(A + (size_t)i * N);
  unsigned short* ob = Abf + (size_t)i * N;
  float s = 0.f;
  #pragma unroll
  for (int it = 0; it < 2; it++){
    int u = threadIdx.x + it*256;
    float4 v = row[u];
    s += v.x + v.y + v.z + v.w;
    ushort4 o;
    o.x = f2bf(v.x); o.y = f2bf(v.y); o.z = f2bf(v.z); o.w = f2bf(v.w);
    *(ushort4*)&ob[u*4] = o;
  }
  __shared__ float red[4];
  s = waveRedSum(s);
  int wid = threadIdx.x >> 6, lane = threadIdx.x & 63;
  if (lane == 0) red[wid] = s;
  __syncthreads();
  if (threadIdx.x == 0){
    float t = red[0] + red[1] + red[2] + red[3];
    dA[i] = 1.0f / sqrtf(t + 1e-10f);
  }
}

// ---------- h: 16 rows/block, W1 transposed in LDS; coalesced hsT ----------
__global__ __launch_bounds__(256) void k_h(const float* __restrict__ x,
                    const float* __restrict__ W1g, const float* __restrict__ b1,
                    const float* __restrict__ dA,
                    float* __restrict__ h, unsigned short* __restrict__ hsT,
                    float* __restrict__ sq, float* __restrict__ hsum){
  __shared__ float W1t[DIN][H+1];            // W1t[c][t] = W1[t][c]
  __shared__ float xb[4][DIN];
  __shared__ __align__(16) unsigned short hTb[H][16];
  int tid = threadIdx.x, w = tid >> 6, t = tid & 63;
  int i0 = blockIdx.x * 16;
  for (int u = tid; u < 2048; u += 256){
    float4 g = ((const float4*)W1g)[u];
    int row = u >> 5, c0 = (u & 31) * 4;     // row = t, 32 float4 per row
    W1t[c0+0][row] = g.x; W1t[c0+1][row] = g.y;
    W1t[c0+2][row] = g.z; W1t[c0+3][row] = g.w;
  }
  __syncthreads();
  float bt = b1[t];
  for (int rr = 0; rr < 4; rr++){
    int i = i0 + w*4 + rr;
    xb[w][t]      = x[(size_t)i*DIN + t];
    xb[w][t + 64] = x[(size_t)i*DIN + t + 64];
    float acc = bt;
    #pragma unroll
    for (int c4 = 0; c4 < DIN/4; c4++){
      float xv[4]; *(float4*)xv = *(const float4*)&xb[w][c4*4];
      acc += xv[0]*W1t[c4*4+0][t] + xv[1]*W1t[c4*4+1][t]
           + xv[2]*W1t[c4*4+2][t] + xv[3]*W1t[c4*4+3][t];
    }
    float hv = leaky(acc);
    h[(size_t)i*H + t] = hv;
    hTb[t][w*4+rr] = f2bf(dA[i]*hv);
    float s2 = waveRedSum(hv*hv);
    float s1 = waveRedSum(hv);
    if (t == 0){ sq[i] = s2; hsum[i] = s1; }
  }
  __syncthreads();
  { int c = tid >> 2, qq = tid & 3;
    ushort4 v = *(ushort4*)&hTb[c][qq*4];
    *(ushort4*)&hsT[(size_t)c*N + i0 + qq*4] = v; }
}

// ---------- DOT = h @ h^T  (fp32: feeds discrete top-k; 128x128 tile) ----------
__global__ __launch_bounds__(256) void k_gram(const float* __restrict__ h,
                                              float* __restrict__ DOT){
  __shared__ float at[32][132];
  __shared__ float bt[32][132];
  int bi = blockIdx.x, bj = blockIdx.y;
  int tid = threadIdx.x;
  int rg = tid >> 4, cg = tid & 15;
  float acc[8][8] = {};
  for (int kc = 0; kc < 64; kc += 32){
    for (int u = tid; u < 1024; u += 256){
      int row = u >> 3, k4 = u & 7;
      float4 v = *(const float4*)(h + (size_t)(bi*128 + row)*H + kc + k4*4);
      at[k4*4+0][row] = v.x; at[k4*4+1][row] = v.y;
      at[k4*4+2][row] = v.z; at[k4*4+3][row] = v.w;
    }
    for (int u = tid; u < 1024; u += 256){
      int row = u >> 3, k4 = u & 7;
      float4 v = *(const float4*)(h + (size_t)(bj*128 + row)*H + kc + k4*4);
      bt[k4*4+0][row] = v.x; bt[k4*4+1][row] = v.y;
      bt[k4*4+2][row] = v.z; bt[k4*4+3][row] = v.w;
    }
    __syncthreads();
    for (int k = 0; k < 32; k++){
      float a[8], b[8];
      *(float4*)&a[0] = *(const float4*)&at[k][rg*8];
      *(float4*)&a[4] = *(const float4*)&at[k][rg*8+4];
      *(float4*)&b[0] = *(const float4*)&bt[k][cg*8];
      *(float4*)&b[4] = *(const float4*)&bt[k][cg*8+4];
      #pragma unroll
      for (int ii = 0; ii < 8; ii++)
        #pragma unroll
        for (int jj = 0; jj < 8; jj++)
          acc[ii][jj] += a[ii]*b[jj];
    }
    __syncthreads();
  }
  #pragma unroll
  for (int ii = 0; ii < 8; ii++){
    int r = bi*128 + rg*8 + ii;
    float* out = DOT + (size_t)r*N + bj*128 + cg*8;
    *(float4*)(out)   = make_float4(acc[ii][0], acc[ii][1], acc[ii][2], acc[ii][3]);
    *(float4*)(out+4) = make_float4(acc[ii][4], acc[ii][5], acc[ii][6], acc[ii][7]);
  }
}

// ---------- per-row top-4 + cos vals + df (fused) ----------
__global__ __launch_bounds__(256) void k_topk(const float* __restrict__ DOT,
      const float* __restrict__ sq, const float* __restrict__ hsum,
      int* __restrict__ nidx, float* __restrict__ ncos, float* __restrict__ df){
  int i = blockIdx.x, tid = threadIdx.x;
  __shared__ unsigned long long cand[1024];
  const float4* row = (const float4*)(DOT + (size_t)i * N);
  const float4* sq4 = (const float4*)sq;
  unsigned long long best[4] = {~0ULL, ~0ULL, ~0ULL, ~0ULL};
  #pragma unroll
  for (int blk = 0; blk < 2; blk++){
    int u = tid + blk*256;
    float4 d = row[u];
    float4 s = sq4[u];
    float kv[4] = { s.x - 2.f*d.x, s.y - 2.f*d.y, s.z - 2.f*d.z, s.w - 2.f*d.w };
    #pragma unroll
    for (int e = 0; e < 4; e++){
      unsigned int j = (unsigned int)(u*4 + e);
      unsigned int uk = __float_as_uint(kv[e]);
      uk = (uk & 0x80000000u) ? ~uk : (uk | 0x80000000u);
      unsigned long long c = ((unsigned long long)uk << 32) | j;
      if (c < best[3]){
        best[3] = c;
        unsigned long long t0;
        if (best[3] < best[2]){ t0 = best[2]; best[2] = best[3]; best[3] = t0; }
        if (best[2] < best[1]){ t0 = best[1]; best[1] = best[2]; best[2] = t0; }
        if (best[1] < best[0]){ t0 = best[0]; best[0] = best[1]; best[1] = t0; }
      }
    }
  }
  #pragma unroll
  for (int e = 0; e < 4; e++) cand[e*256 + tid] = best[e];
  __syncthreads();
  if (tid < 64){
    unsigned long long loc[16];
    #pragma unroll
    for (int e = 0; e < 16; e++) loc[e] = cand[e*64 + tid];
    unsigned long long w0=~0ULL, w1=~0ULL, w2=~0ULL, w3=~0ULL;
    #pragma unroll
    for (int r = 0; r < 4; r++){
      unsigned long long m = loc[0];
      #pragma unroll
      for (int e = 1; e < 16; e++) m = (loc[e] < m) ? loc[e] : m;
      unsigned long long g = m;
      #pragma unroll
      for (int o = 32; o > 0; o >>= 1){
        unsigned long long other = shflx64(g, o);
        if (other < g) g = other;
      }
      #pragma unroll
      for (int e = 0; e < 16; e++) if (loc[e] == g) loc[e] = ~0ULL;
      if (r == 0) w0 = g; else if (r == 1) w1 = g; else if (r == 2) w2 = g; else w3 = g;
    }
    float myc = 0.f;
    if (tid < 4){
      unsigned long long w = (tid==0) ? w0 : (tid==1) ? w1 : (tid==2) ? w2 : w3;
      unsigned int j = (unsigned int)w;
      unsigned int uk = (unsigned int)(w >> 32);
      float key = (uk & 0x80000000u) ? __uint_as_float(uk ^ 0x80000000u)
                                     : __uint_as_float(~uk);
      float sqj = sq[j];
      float dot = (sqj - key) * 0.5f;
      float hni = sqrtf(sq[i]), hnj = sqrtf(sqj);
      float cosv = dot/(hni*hnj)
                 + 1e-10f*(hsum[i]/hni + hsum[j]/hnj)
                 + 64.0f*1e-20f;
      nidx[i*4 + tid] = (int)j;
      ncos[i*4 + tid] = cosv;
      myc = cosv;
    }
    myc += __shfl_xor(myc, 1, 64);
    myc += __shfl_xor(myc, 2, 64);
    if (tid == 0) df[i] = 1.f / sqrtf(myc + 1e-10f);
  }
}

// ---------- MFMA bf16 GEMM: Cp[ks] = Abf[:, ksl] @ BtG^T[ksl, :] ----------
template<int BN>
__global__ __launch_bounds__(256) void k_mgemm(
    const unsigned short* __restrict__ Abf, const unsigned short* __restrict__ BtG,
    float* __restrict__ Cp, int KC){
  __shared__ __align__(16) unsigned short Asl[64][72];
  __shared__ __align__(16) unsigned short Bsl[BN][72];
  int m0 = blockIdx.x * 64, kbase = blockIdx.y * KC;
  int tid = threadIdx.x;
  int w = tid >> 6, lane = tid & 63;
  int quad = lane >> 4, ml = lane & 15;
  floatx4 acc[BN/16];
  #pragma unroll
  for (int ct = 0; ct < BN/16; ct++) acc[ct] = (floatx4){0.f,0.f,0.f,0.f};

  for (int kc = 0; kc < KC; kc += 64){
    int kb = kbase + kc;
    #pragma unroll
    for (int u = tid; u < 512; u += 256){
      int r = u >> 3, s = u & 7;
      *(uint4*)&Asl[r][s*8] = *(const uint4*)(Abf + ((size_t)(m0+r) << 11) + kb + s*8);
    }
    #pragma unroll
    for (int u = tid; u < BN*8; u += 256){
      int n = u >> 3, s = u & 7;
      *(uint4*)&Bsl[n][s*8] = *(const uint4*)(BtG + ((size_t)n << 11) + kb + s*8);
    }
    __syncthreads();
    #pragma unroll
    for (int k0 = 0; k0 < 64; k0 += 32){
      bf16x8 af = *(const bf16x8*)&Asl[16*w + ml][k0 + quad*8];
      #pragma unroll
      for (int ct = 0; ct < BN/16; ct++){
        bf16x8 bfr = *(const bf16x8*)&Bsl[16*ct + ml][k0 + quad*8];
        acc[ct] = __builtin_amdgcn_mfma_f32_16x16x32_bf16(af, bfr, acc[ct], 0, 0, 0);
      }
    }
    __syncthreads();
  }
  float* C = Cp + (size_t)blockIdx.y * (N * BN);
  #pragma unroll
  for (int ct = 0; ct < BN/16; ct++)
    #pragma unroll
    for (int r = 0; r < 4; r++){
      int row = m0 + 16*w + quad*4 + r;
      C[(size_t)row*BN + 16*ct + ml] = acc[ct][r];
    }
}

// ---------- coalesced partial sums: Y1s[i][t] = dA[i] * sum_p Y1p ----------
__global__ __launch_bounds__(256) void k_sumY1(const float* __restrict__ Y1p,
    const float* __restrict__ dA, float* __restrict__ Y1s){
  int idx4 = blockIdx.x*256 + threadIdx.x;     // N*H/4 = 32768
  int i = idx4 >> 4;
  float4 s = ((const float4*)Y1p)[idx4];
  #pragma unroll
  for (int p = 1; p < S1; p++){
    float4 v = ((const float4*)Y1p)[(size_t)p*(N*H/4) + idx4];
    s.x += v.x; s.y += v.y; s.z += v.z; s.w += v.w;
  }
  float d = dA[i];
  s.x *= d; s.y *= d; s.z *= d; s.w *= d;
  ((float4*)Y1s)[idx4] = s;
}

__global__ __launch_bounds__(256) void k_sumY2(const float* __restrict__ Y2p,
    const float* __restrict__ dA, float* __restrict__ Y2s){
  int idx4 = blockIdx.x*256 + threadIdx.x;     // N*128/4 = 65536
  int i = idx4 >> 5;
  float4 s = ((const float4*)Y2p)[idx4];
  #pragma unroll
  for (int p = 1; p < S2; p++){
    float4 v = ((const float4*)Y2p)[(size_t)p*(N*128/4) + idx4];
    s.x += v.x; s.y += v.y; s.z += v.z; s.w += v.w;
  }
  float d = dA[i];
  s.x *= d; s.y *= d; s.z *= d; s.w *= d;
  ((float4*)Y2s)[idx4] = s;
}

// ---------- layer 1: 16 rows/block, weights in LDS, coalesced ZsT ----------
__global__ __launch_bounds__(256) void k_z1(const float* __restrict__ h,
                     const int* __restrict__ nidx, const float* __restrict__ ncos,
                     const float* __restrict__ df, const float* __restrict__ Y1s,
                     const float* __restrict__ dA,
                     const float* __restrict__ WF1g, const float* __restrict__ bF1,
                     const float* __restrict__ WC1g, const float* __restrict__ bC1,
                     const float* __restrict__ WT1g, const float* __restrict__ bT1,
                     float* __restrict__ z1f, float* __restrict__ z1cf,
                     unsigned short* __restrict__ ZsT){
  __shared__ float Wf[H][H+1], Wc[H][H+1], Wt[H][H+1];   // W*[c][t]
  __shared__ float vb[4][H], ub[4][H];
  __shared__ __align__(16) unsigned short Zb[128][16];
  int tid = threadIdx.x, w = tid >> 6, t = tid & 63;
  int i0 = blockIdx.x * 16;
  for (int u = tid; u < 1024; u += 256){
    int row = u >> 4, c0 = (u & 15) * 4;
    float4 f = ((const float4*)WF1g)[u];
    Wf[c0+0][row]=f.x; Wf[c0+1][row]=f.y; Wf[c0+2][row]=f.z; Wf[c0+3][row]=f.w;
    float4 g = ((const float4*)WC1g)[u];
    Wc[c0+0][row]=g.x; Wc[c0+1][row]=g.y; Wc[c0+2][row]=g.z; Wc[c0+3][row]=g.w;
    float4 e = ((const float4*)WT1g)[u];
    Wt[c0+0][row]=e.x; Wt[c0+1][row]=e.y; Wt[c0+2][row]=e.z; Wt[c0+3][row]=e.w;
  }
  __syncthreads();
  float bfv = bF1[t], bcv = bC1[t], btv = bT1[t];
  for (int rr = 0; rr < 4; rr++){
    int i = i0 + w*4 + rr;
    int j0 = nidx[i*4], j1 = nidx[i*4+1], j2 = nidx[i*4+2], j3 = nidx[i*4+3];
    float di = df[i];
    float w0 = ncos[i*4]  *di*df[j0];
    float w1 = ncos[i*4+1]*di*df[j1];
    float w2 = ncos[i*4+2]*di*df[j2];
    float w3 = ncos[i*4+3]*di*df[j3];
    vb[w][t] = w0*h[(size_t)j0*H+t] + w1*h[(size_t)j1*H+t]
             + w2*h[(size_t)j2*H+t] + w3*h[(size_t)j3*H+t];
    ub[w][t] = Y1s[(size_t)i*H + t];
    float a1 = bfv, a2 = bcv, a3 = btv, a4 = bcv;
    #pragma unroll
    for (int c4 = 0; c4 < 16; c4++){
      float vv[4], uv[4];
      *(float4*)vv = *(const float4*)&vb[w][c4*4];
      *(float4*)uv = *(const float4*)&ub[w][c4*4];
      #pragma unroll
      for (int e = 0; e < 4; e++){
        int c = c4*4 + e;
        float wfv = Wf[c][t], wcv = Wc[c][t], wtv = Wt[c][t];
        a1 += vv[e]*wfv; a2 += vv[e]*wcv;
        a3 += uv[e]*wtv; a4 += uv[e]*wcv;
      }
    }
    z1f [(size_t)i*H+t] = leaky(a1);
    z1cf[(size_t)i*H+t] = leaky(a2);
    float dai = dA[i];
    int lr = w*4 + rr;
    Zb[t][lr]      = f2bf(dai*leaky(a3));
    Zb[64+t][lr]   = f2bf(dai*leaky(a4));
  }
  __syncthreads();
  { int c = tid >> 1, hh = tid & 1;
    uint4 v = *(uint4*)&Zb[c][hh*8];
    *(uint4*)&ZsT[(size_t)c*N + i0 + hh*8] = v; }
}

// ---------- layer 2 + attention + out: 16 rows/block, weights in LDS ----------
__global__ __launch_bounds__(256) void k_z2o(const float* __restrict__ z1f,
                      const float* __restrict__ z1cf,
                      const int* __restrict__ nidx, const float* __restrict__ ncos,
                      const float* __restrict__ df, const float* __restrict__ Y2s,
                      const float* __restrict__ WF2g, const float* __restrict__ bF2,
                      const float* __restrict__ WC2g, const float* __restrict__ bC2,
                      const float* __restrict__ WT2g, const float* __restrict__ bT2,
                      const float* __restrict__ Wag, const float* __restrict__ ba,
                      const float* __restrict__ q,  const float* __restrict__ W2,
                      const float* __restrict__ b2,
                      float* __restrict__ Z6, float* __restrict__ out){
  __shared__ float Wf[H][H+1], Wc[H][H+1], Wt2[H][H+1], Wal[H][H+1];
  __shared__ float vf[4][H], vc[4][H], ut[4][H], uc[4][H];
  __shared__ float zfb[4][H], ztb[4][H], zcb[4][H], zab[4][H];
  int tid = threadIdx.x, w = tid >> 6, t = tid & 63;
  int i0 = blockIdx.x * 16;
  for (int u = tid; u < 1024; u += 256){
    int row = u >> 4, c0 = (u & 15) * 4;
    float4 f = ((const float4*)WF2g)[u];
    Wf[c0+0][row]=f.x; Wf[c0+1][row]=f.y; Wf[c0+2][row]=f.z; Wf[c0+3][row]=f.w;
    float4 g = ((const float4*)WC2g)[u];
    Wc[c0+0][row]=g.x; Wc[c0+1][row]=g.y; Wc[c0+2][row]=g.z; Wc[c0+3][row]=g.w;
    float4 e = ((const float4*)WT2g)[u];
    Wt2[c0+0][row]=e.x; Wt2[c0+1][row]=e.y; Wt2[c0+2][row]=e.z; Wt2[c0+3][row]=e.w;
    float4 a = ((const float4*)Wag)[u];
    Wal[c0+0][row]=a.x; Wal[c0+1][row]=a.y; Wal[c0+2][row]=a.z; Wal[c0+3][row]=a.w;
  }
  __syncthreads();
  float bfv = bF2[t], bcv = bC2[t], btv = bT2[t];
  float bav = ba[t], qv = q[t];
  for (int rr = 0; rr < 4; rr++){
    int i = i0 + w*4 + rr;
    int j0 = nidx[i*4], j1 = nidx[i*4+1], j2 = nidx[i*4+2], j3 = nidx[i*4+3];
    float di = df[i];
    float w0 = ncos[i*4]  *di*df[j0];
    float w1 = ncos[i*4+1]*di*df[j1];
    float w2 = ncos[i*4+2]*di*df[j2];
    float w3 = ncos[i*4+3]*di*df[j3];
    vf[w][t] = w0*z1f[(size_t)j0*H+t] + w1*z1f[(size_t)j1*H+t]
             + w2*z1f[(size_t)j2*H+t] + w3*z1f[(size_t)j3*H+t];
    vc[w][t] = w0*z1cf[(size_t)j0*H+t] + w1*z1cf[(size_t)j1*H+t]
             + w2*z1cf[(size_t)j2*H+t] + w3*z1cf[(size_t)j3*H+t];
    ut[w][t] = Y2s[(size_t)i*128 + t];
    uc[w][t] = Y2s[(size_t)i*128 + 64 + t];
    float a1 = bfv, a2 = bcv, a3 = btv, a4 = bcv;
    #pragma unroll
    for (int c4 = 0; c4 < 16; c4++){
      float fv[4], cv[4], tv[4], uv[4];
      *(float4*)fv = *(const float4*)&vf[w][c4*4];
      *(float4*)cv = *(const float4*)&vc[w][c4*4];
      *(float4*)tv = *(const float4*)&ut[w][c4*4];
      *(float4*)uv = *(const float4*)&uc[w][c4*4];
      #pragma unroll
      for (int e = 0; e < 4; e++){
        int c = c4*4 + e;
        float wfv = Wf[c][t], wcv = Wc[c][t], wtv = Wt2[c][t];
        a1 += fv[e]*wfv; a2 += cv[e]*wcv;
        a3 += tv[e]*wtv; a4 += uv[e]*wcv;
      }
    }
    float zfv = leaky(a1), zcfv = leaky(a2), ztv = leaky(a3), zctv = leaky(a4);
    float* zr = Z6 + (size_t)i*384;
    zr[Z_ZF + t] = zfv;  zr[Z_ZT + t] = ztv;
    zr[Z_ZCF + t] = zcfv; zr[Z_ZCT + t] = zctv;
    float scf = waveRedSum(zcfv*zcfv);
    float mcf = sqrtf(scf*(1.f/64.f)) + 1e-10f;
    zr[Z_LCF + t] = zcfv/mcf;
    float sct = waveRedSum(zctv*zctv);
    float mct = sqrtf(sct*(1.f/64.f)) + 1e-10f;
    zr[Z_LCT + t] = zctv/mct;
    float zcv = 0.5f*(zcfv + zctv);
    zfb[w][t] = zfv; ztb[w][t] = ztv; zcb[w][t] = zcv;
    // attention scores (per-wave; no barrier needed — within-wave LDS)
    float ev[3];
    #pragma unroll
    for (int kk = 0; kk < 3; kk++){
      const float* zsrc = (kk == 0) ? zfb[w] : (kk == 1) ? ztb[w] : zcb[w];
      float aa = bav;
      #pragma unroll
      for (int c4 = 0; c4 < 16; c4++){
        float zv[4]; *(float4*)zv = *(const float4*)&zsrc[c4*4];
        #pragma unroll
        for (int e = 0; e < 4; e++) aa += zv[e]*Wal[c4*4+e][t];
      }
      ev[kk] = waveRedSum(tanhf(aa)*qv);
    }
    float mx = fmaxf(ev[0], fmaxf(ev[1], ev[2]));
    float x0 = expf(ev[0]-mx), x1 = expf(ev[1]-mx), x2 = expf(ev[2]-mx);
    float inv = 1.f/(x0+x1+x2);
    float zagg = x0*inv*zfv + x1*inv*ztv + x2*inv*zcv;
    zab[w][t] = zagg;
    if (t < OUTD){
      float acc2 = b2[t];
      const float4* w2r = (const float4*)(W2 + (size_t)t*H);
      #pragma unroll
      for (int c4 = 0; c4 < 16; c4++){
        float4 wv = w2r[c4];
        float zv[4]; *(float4*)zv = *(const float4*)&zab[w][c4*4];
        acc2 += zv[0]*wv.x + zv[1]*wv.y + zv[2]*wv.z + zv[3]*wv.w;
      }
      out[(size_t)i*OUTD + t] = acc2;
    }
  }
}

// ---------- k_reduce: 5 products x RS row-splits, 64x64 tile GEMM each ----------
__global__ __launch_bounds__(256) void k_reduce(const float* __restrict__ Z6,
                                                float* __restrict__ redP,
                                                float* __restrict__ colP){
  __shared__ float sa[64][68];
  __shared__ float sb[64][68];
  int p = blockIdx.x >> 5;     // RS = 32
  int s = blockIdx.x & 31;
  int tid = threadIdx.x;
  const int aoffT[5] = {Z_ZT,  Z_ZF,  Z_LCF, Z_LCF, Z_LCT};
  const int boffT[5] = {Z_ZCT, Z_ZCF, Z_LCF, Z_LCT, Z_LCT};
  int aoff = aoffT[p], boff = boffT[p];
  int r0 = s * 64;
  {
    int row = tid >> 4, c4 = (tid & 15) * 4;
    #pragma unroll
    for (int rr = 0; rr < 64; rr += 16){
      const float* zr = Z6 + (size_t)(r0 + row + rr) * 384;
      *(float4*)&sa[row + rr][c4] = *(const float4*)&zr[aoff + c4];
      *(float4*)&sb[row + rr][c4] = *(const float4*)&zr[boff + c4];
    }
  }
  __syncthreads();
  int rg = tid >> 4, cg = tid & 15;
  float acc[4][4] = {};
  #pragma unroll 8
  for (int k = 0; k < 64; k++){
    float a[4], b[4];
    *(float4*)a = *(const float4*)&sa[k][rg*4];
    *(float4*)b = *(const float4*)&sb[k][cg*4];
    #pragma unroll
    for (int ii = 0; ii < 4; ii++)
      #pragma unroll
      for (int jj = 0; jj < 4; jj++)
        acc[ii][jj] += a[ii]*b[jj];
  }
  float* rp = redP + (size_t)blockIdx.x * 4096;
  #pragma unroll
  for (int ii = 0; ii < 4; ii++)
    *(float4*)&rp[(rg*4+ii)*64 + cg*4] =
      make_float4(acc[ii][0], acc[ii][1], acc[ii][2], acc[ii][3]);
  if (p < 2 && tid < 128){
    int t = tid & 63;
    float csum = 0.f;
    if (tid < 64){
      #pragma unroll 16
      for (int r = 0; r < 64; r++) csum += sa[r][t];
    } else {
      #pragma unroll 16
      for (int r = 0; r < 64; r++) csum += sb[r][t];
    }
    colP[((size_t)p*RS + s)*128 + tid] = csum;
  }
}

// ---------- sum partial slabs into red ----------
__global__ void k_combine(const float* __restrict__ redP,
                          const float* __restrict__ colP,
                          float* __restrict__ red){
  int idx = blockIdx.x*256 + threadIdx.x;
  if (idx < 20480){
    int p = idx >> 12, i = idx & 4095;
    float sum = 0.f;
    #pragma unroll 8
    for (int s = 0; s < RS; s++) sum += redP[((size_t)p*RS + s)*4096 + i];
    red[idx] = sum;
  } else if (idx < 20736){
    int j = idx - 20480;
    int p = j >> 7, rem = j & 127;
    float sum = 0.f;
    #pragma unroll 8
    for (int s = 0; s < RS; s++) sum += colP[((size_t)p*RS + s)*128 + rem];
    red[idx] = sum;
  }
}

// ---------- final scalars Lc, Ld ----------
__global__ void k_final(const float* __restrict__ red, float* __restrict__ out2){
  int tid = threadIdx.x;
  const float* Stc = red;
  const float* Sfc = red + 4096;
  const float* Cff = red + 8192;
  const float* Cft = red + 12288;
  const float* Ctt = red + 16384;
  const float* cst = red + 20480;
  const float* csct= red + 20544;
  const float* csf = red + 20608;
  const float* cscf= red + 20672;
  float sCff=0, sCft=0, sCtt=0, sM1=0, sM2=0;
  for (int u = tid*16; u < tid*16+16; u++){
    int d = u >> 6, e = u & 63;
    float m1 = Stc[u] - cst[d]*csct[e]*(1.f/2048.f);
    float m2 = Sfc[u] - csf[d]*cscf[e]*(1.f/2048.f);
    sM1 += m1*m1; sM2 += m2*m2;
    float cf = Cff[u], cx = Cft[u], ct = Ctt[u];
    sCff += cf*cf; sCft += cx*cx; sCtt += ct*ct;
  }
  __shared__ float rd[5][4];
  sCff = waveRedSum(sCff); sCft = waveRedSum(sCft); sCtt = waveRedSum(sCtt);
  sM1 = waveRedSum(sM1);   sM2 = waveRedSum(sM2);
  int w = tid >> 6, lane = tid & 63;
  if (lane == 0){ rd[0][w]=sCff; rd[1][w]=sCft; rd[2][w]=sCtt; rd[3][w]=sM1; rd[4][w]=sM2; }
  __syncthreads();
  if (tid == 0){
    float A0 = rd[0][0]+rd[0][1]+rd[0][2]+rd[0][3];
    float A1 = rd[1][0]+rd[1][1]+rd[1][2]+rd[1][3];
    float A2 = rd[2][0]+rd[2][1]+rd[2][2]+rd[2][3];
    float M1 = rd[3][0]+rd[3][1]+rd[3][2]+rd[3][3];
    float M2 = rd[4][0]+rd[4][1]+rd[4][2]+rd[4][3];
    out2[0] = (A0 - 2.f*A1 + A2) * (1.f/(2048.f*2048.f));
    out2[1] = (M1 + M2) * (1.f/(2047.f*2047.f));
  }
}

extern "C" void kernel_launch(void* const* d_in, const int* in_sizes, int n_in,
                              void* d_out, int out_size, void* d_ws, size_t ws_size,
                              hipStream_t stream) {
  const float* x   = (const float*)d_in[0];
  const float* A   = (const float*)d_in[1];
  const float* W1  = (const float*)d_in[3];
  const float* b1  = (const float*)d_in[4];
  const float* WF1 = (const float*)d_in[5];
  const float* bF1 = (const float*)d_in[6];
  const float* WF2 = (const float*)d_in[7];
  const float* bF2 = (const float*)d_in[8];
  const float* WT1 = (const float*)d_in[9];
  const float* bT1 = (const float*)d_in[10];
  const float* WT2 = (const float*)d_in[11];
  const float* bT2 = (const float*)d_in[12];
  const float* WC1 = (const float*)d_in[13];
  const float* bC1 = (const float*)d_in[14];
  const float* WC2 = (const float*)d_in[15];
  const float* bC2 = (const float*)d_in[16];
  const float* Wa  = (const float*)d_in[17];
  const float* ba  = (const float*)d_in[18];
  const float* q   = (const float*)d_in[19];
  const float* W2  = (const float*)d_in[20];
  const float* b2  = (const float*)d_in[21];
  float* out = (float*)d_out;

  float* W = (float*)d_ws;
  float* h_   = W;                      // N*H
  float* dA   = h_  + N*H;              // N
  float* sq   = dA  + N;                // N
  float* hsum = sq  + N;                // N
  float* df   = hsum+ N;                // N
  int*   nidx = (int*)(df + N);         // N*4
  float* ncos = (float*)(nidx + N*4);   // N*4
  float* red  = ncos + N*4;             // 20736
  float* DOT  = red + 20736;            // N*N
  float* Z6   = DOT + (size_t)N*N;      // N*384
  float* Y1p  = Z6  + (size_t)N*384;    // S1*N*H
  float* Y2p  = Y1p + (size_t)S1*N*H;   // S2*N*128
  float* Y1s  = Y2p + (size_t)S2*N*128; // N*H
  float* Y2s  = Y1s + (size_t)N*H;      // N*128
  float* z1f  = Y2s + (size_t)N*128;    // N*H
  float* z1cf = z1f + N*H;              // N*H
  float* redP = z1cf+ N*H;              // 5*RS*4096 = 655360
  float* colP = redP+ 655360;           // 2*RS*128 = 8192
  unsigned short* Abf = (unsigned short*)(colP + 8192);  // N*N bf16
  unsigned short* hsT = Abf + (size_t)N*N;               // 64*N bf16
  unsigned short* ZsT = hsT + (size_t)H*N;               // 128*N bf16

  k_prep<<<N, 256, 0, stream>>>(A, dA, Abf);
  k_h<<<128, 256, 0, stream>>>(x, W1, b1, dA, h_, hsT, sq, hsum);
  k_gram<<<dim3(16,16), 256, 0, stream>>>(h_, DOT);
  k_topk<<<N, 256, 0, stream>>>(DOT, sq, hsum, nidx, ncos, df);

  k_mgemm<64><<<dim3(32,S1), 256, 0, stream>>>(Abf, hsT, Y1p, N/S1);
  k_sumY1<<<128, 256, 0, stream>>>(Y1p, dA, Y1s);
  k_z1<<<128, 256, 0, stream>>>(h_, nidx, ncos, df, Y1s, dA,
                                WF1, bF1, WC1, bC1, WT1, bT1, z1f, z1cf, ZsT);
  k_mgemm<128><<<dim3(32,S2), 256, 0, stream>>>(Abf, ZsT, Y2p, N/S2);
  k_sumY2<<<256, 256, 0, stream>>>(Y2p, dA, Y2s);
  k_z2o<<<128, 256, 0, stream>>>(z1f, z1cf, nidx, ncos, df, Y2s,
                                 WF2, bF2, WC2, bC2, WT2, bT2,
                                 Wa, ba, q, W2, b2, Z6, out);
  k_reduce<<<5*RS, 256, 0, stream>>>(Z6, redP, colP);
  k_combine<<<81, 256, 0, stream>>>(redP, colP, red);
  k_final<<<1, 256, 0, stream>>>(red, out + (size_t)N*OUTD);
}

// Round 8
// 204.062 us; speedup vs baseline: 3.5823x; 1.1396x over previous
//
#include <hip/hip_runtime.h>
#include <stdint.h>

#define N 2048
#define DIN 128
#define H 64
#define OUTD 7
#define RS 32    // k_reduce row-splits per product
#define S1 8     // gemm1 K-splits
#define S2 8     // gemm2 K-splits

// Z6 row layout: [zt(64) | zct(64) | zf(64) | zcf(64) | Lcf(64) | Lct(64)]
#define Z_ZT  0
#define Z_ZCT 64
#define Z_ZF  128
#define Z_ZCF 192
#define Z_LCF 256
#define Z_LCT 320

typedef short bf16x8 __attribute__((ext_vector_type(8)));
typedef float floatx4 __attribute__((ext_vector_type(4)));

__device__ __forceinline__ float leaky(float x){ return x > 0.f ? x : 0.1f*x; }

__device__ __forceinline__ unsigned short f2bf(float f){
  unsigned int u = __float_as_uint(f);
  u = u + 0x7FFFu + ((u >> 16) & 1u);   // RNE
  return (unsigned short)(u >> 16);
}

__device__ __forceinline__ float waveRedSum(float v){
  #pragma unroll
  for (int o = 32; o > 0; o >>= 1) v += __shfl_xor(v, o, 64);
  return v;
}

__device__ __forceinline__ unsigned long long shflx64(unsigned long long v, int m){
  unsigned int lo = (unsigned int)v, hi = (unsigned int)(v >> 32);
  lo = (unsigned int)__shfl_xor((int)lo, m, 64);
  hi = (unsigned int)__shfl_xor((int)hi, m, 64);
  return ((unsigned long long)hi << 32) | lo;
}

// ---------- row sums of A -> dA, and cast A -> bf16 (fused; one A read) ----------
__global__ void k_prep(const float* __restrict__ A, float* __restrict__ dA,
                       unsigned short* __restrict__ Abf){
  int i = blockIdx.x;
  const float4* row = (const float4*)(A + (size_t)i * N);
  unsigned short* ob = Abf + (size_t)i * N;
  float s = 0.f;
  #pragma unroll
  for (int it = 0; it < 2; it++){
    int u = threadIdx.x + it*256;
    float4 v = row[u];
    s += v.x + v.y + v.z + v.w;
    ushort4 o;
    o.x = f2bf(v.x); o.y = f2bf(v.y); o.z = f2bf(v.z); o.w = f2bf(v.w);
    *(ushort4*)&ob[u*4] = o;
  }
  __shared__ float red[4];
  s = waveRedSum(s);
  int wid = threadIdx.x >> 6, lane = threadIdx.x & 63;
  if (lane == 0) red[wid] = s;
  __syncthreads();
  if (threadIdx.x == 0){
    float t = red[0] + red[1] + red[2] + red[3];
    dA[i] = 1.0f / sqrtf(t + 1e-10f);
  }
}

// ---------- h: 16 rows/block, W1 transposed in LDS; coalesced hsT ----------
__global__ __launch_bounds__(256) void k_h(const float* __restrict__ x,
                    const float* __restrict__ W1g, const float* __restrict__ b1,
                    const float* __restrict__ dA,
                    float* __restrict__ h, unsigned short* __restrict__ hsT,
                    float* __restrict__ sq, float* __restrict__ hsum){
  __shared__ float W1t[DIN][H+1];            // W1t[c][t] = W1[t][c]
  __shared__ float xb[4][DIN];
  __shared__ __align__(16) unsigned short hTb[H][16];
  int tid = threadIdx.x, w = tid >> 6, t = tid & 63;
  int i0 = blockIdx.x * 16;
  for (int u = tid; u < 2048; u += 256){
    float4 g = ((const float4*)W1g)[u];
    int row = u >> 5, c0 = (u & 31) * 4;
    W1t[c0+0][row] = g.x; W1t[c0+1][row] = g.y;
    W1t[c0+2][row] = g.z; W1t[c0+3][row] = g.w;
  }
  __syncthreads();
  float bt = b1[t];
  for (int rr = 0; rr < 4; rr++){
    int i = i0 + w*4 + rr;
    xb[w][t]      = x[(size_t)i*DIN + t];
    xb[w][t + 64] = x[(size_t)i*DIN + t + 64];
    float acc = bt;
    #pragma unroll
    for (int c4 = 0; c4 < DIN/4; c4++){
      float xv[4]; *(float4*)xv = *(const float4*)&xb[w][c4*4];
      acc += xv[0]*W1t[c4*4+0][t] + xv[1]*W1t[c4*4+1][t]
           + xv[2]*W1t[c4*4+2][t] + xv[3]*W1t[c4*4+3][t];
    }
    float hv = leaky(acc);
    h[(size_t)i*H + t] = hv;
    hTb[t][w*4+rr] = f2bf(dA[i]*hv);
    float s2 = waveRedSum(hv*hv);
    float s1 = waveRedSum(hv);
    if (t == 0){ sq[i] = s2; hsum[i] = s1; }
  }
  __syncthreads();
  { int c = tid >> 2, qq = tid & 3;
    ushort4 v = *(ushort4*)&hTb[c][qq*4];
    *(ushort4*)&hsT[(size_t)c*N + i0 + qq*4] = v; }
}

// ---------- DOT = h @ h^T  (fp32: feeds discrete top-k; 128x128 tile) ----------
__global__ __launch_bounds__(256) void k_gram(const float* __restrict__ h,
                                              float* __restrict__ DOT){
  __shared__ float at[32][132];
  __shared__ float bt[32][132];
  int bi = blockIdx.x, bj = blockIdx.y;
  int tid = threadIdx.x;
  int rg = tid >> 4, cg = tid & 15;
  float acc[8][8] = {};
  for (int kc = 0; kc < 64; kc += 32){
    for (int u = tid; u < 1024; u += 256){
      int row = u >> 3, k4 = u & 7;
      float4 v = *(const float4*)(h + (size_t)(bi*128 + row)*H + kc + k4*4);
      at[k4*4+0][row] = v.x; at[k4*4+1][row] = v.y;
      at[k4*4+2][row] = v.z; at[k4*4+3][row] = v.w;
    }
    for (int u = tid; u < 1024; u += 256){
      int row = u >> 3, k4 = u & 7;
      float4 v = *(const float4*)(h + (size_t)(bj*128 + row)*H + kc + k4*4);
      bt[k4*4+0][row] = v.x; bt[k4*4+1][row] = v.y;
      bt[k4*4+2][row] = v.z; bt[k4*4+3][row] = v.w;
    }
    __syncthreads();
    for (int k = 0; k < 32; k++){
      float a[8], b[8];
      *(float4*)&a[0] = *(const float4*)&at[k][rg*8];
      *(float4*)&a[4] = *(const float4*)&at[k][rg*8+4];
      *(float4*)&b[0] = *(const float4*)&bt[k][cg*8];
      *(float4*)&b[4] = *(const float4*)&bt[k][cg*8+4];
      #pragma unroll
      for (int ii = 0; ii < 8; ii++)
        #pragma unroll
        for (int jj = 0; jj < 8; jj++)
          acc[ii][jj] += a[ii]*b[jj];
    }
    __syncthreads();
  }
  #pragma unroll
  for (int ii = 0; ii < 8; ii++){
    int r = bi*128 + rg*8 + ii;
    float* out = DOT + (size_t)r*N + bj*128 + cg*8;
    *(float4*)(out)   = make_float4(acc[ii][0], acc[ii][1], acc[ii][2], acc[ii][3]);
    *(float4*)(out+4) = make_float4(acc[ii][4], acc[ii][5], acc[ii][6], acc[ii][7]);
  }
}

// ---------- per-row top-4 + cos vals + df (fused) ----------
__global__ __launch_bounds__(256) void k_topk(const float* __restrict__ DOT,
      const float* __restrict__ sq, const float* __restrict__ hsum,
      int* __restrict__ nidx, float* __restrict__ ncos, float* __restrict__ df){
  int i = blockIdx.x, tid = threadIdx.x;
  __shared__ unsigned long long cand[1024];
  const float4* row = (const float4*)(DOT + (size_t)i * N);
  const float4* sq4 = (const float4*)sq;
  unsigned long long best[4] = {~0ULL, ~0ULL, ~0ULL, ~0ULL};
  #pragma unroll
  for (int blk = 0; blk < 2; blk++){
    int u = tid + blk*256;
    float4 d = row[u];
    float4 s = sq4[u];
    float kv[4] = { s.x - 2.f*d.x, s.y - 2.f*d.y, s.z - 2.f*d.z, s.w - 2.f*d.w };
    #pragma unroll
    for (int e = 0; e < 4; e++){
      unsigned int j = (unsigned int)(u*4 + e);
      unsigned int uk = __float_as_uint(kv[e]);
      uk = (uk & 0x80000000u) ? ~uk : (uk | 0x80000000u);
      unsigned long long c = ((unsigned long long)uk << 32) | j;
      if (c < best[3]){
        best[3] = c;
        unsigned long long t0;
        if (best[3] < best[2]){ t0 = best[2]; best[2] = best[3]; best[3] = t0; }
        if (best[2] < best[1]){ t0 = best[1]; best[1] = best[2]; best[2] = t0; }
        if (best[1] < best[0]){ t0 = best[0]; best[0] = best[1]; best[1] = t0; }
      }
    }
  }
  #pragma unroll
  for (int e = 0; e < 4; e++) cand[e*256 + tid] = best[e];
  __syncthreads();
  if (tid < 64){
    unsigned long long loc[16];
    #pragma unroll
    for (int e = 0; e < 16; e++) loc[e] = cand[e*64 + tid];
    unsigned long long w0=~0ULL, w1=~0ULL, w2=~0ULL, w3=~0ULL;
    #pragma unroll
    for (int r = 0; r < 4; r++){
      unsigned long long m = loc[0];
      #pragma unroll
      for (int e = 1; e < 16; e++) m = (loc[e] < m) ? loc[e] : m;
      unsigned long long g = m;
      #pragma unroll
      for (int o = 32; o > 0; o >>= 1){
        unsigned long long other = shflx64(g, o);
        if (other < g) g = other;
      }
      #pragma unroll
      for (int e = 0; e < 16; e++) if (loc[e] == g) loc[e] = ~0ULL;
      if (r == 0) w0 = g; else if (r == 1) w1 = g; else if (r == 2) w2 = g; else w3 = g;
    }
    float myc = 0.f;
    if (tid < 4){
      unsigned long long w = (tid==0) ? w0 : (tid==1) ? w1 : (tid==2) ? w2 : w3;
      unsigned int j = (unsigned int)w;
      unsigned int uk = (unsigned int)(w >> 32);
      float key = (uk & 0x80000000u) ? __uint_as_float(uk ^ 0x80000000u)
                                     : __uint_as_float(~uk);
      float sqj = sq[j];
      float dot = (sqj - key) * 0.5f;
      float hni = sqrtf(sq[i]), hnj = sqrtf(sqj);
      float cosv = dot/(hni*hnj)
                 + 1e-10f*(hsum[i]/hni + hsum[j]/hnj)
                 + 64.0f*1e-20f;
      nidx[i*4 + tid] = (int)j;
      ncos[i*4 + tid] = cosv;
      myc = cosv;
    }
    myc += __shfl_xor(myc, 1, 64);
    myc += __shfl_xor(myc, 2, 64);
    if (tid == 0) df[i] = 1.f / sqrtf(myc + 1e-10f);
  }
}

// ---------- MFMA bf16 GEMM: Cp[ks] = Abf[:, ksl] @ BtG^T[ksl, :] ----------
template<int BN>
__global__ __launch_bounds__(256) void k_mgemm(
    const unsigned short* __restrict__ Abf, const unsigned short* __restrict__ BtG,
    float* __restrict__ Cp, int KC){
  __shared__ __align__(16) unsigned short Asl[64][72];
  __shared__ __align__(16) unsigned short Bsl[BN][72];
  int m0 = blockIdx.x * 64, kbase = blockIdx.y * KC;
  int tid = threadIdx.x;
  int w = tid >> 6, lane = tid & 63;
  int quad = lane >> 4, ml = lane & 15;
  floatx4 acc[BN/16];
  #pragma unroll
  for (int ct = 0; ct < BN/16; ct++) acc[ct] = (floatx4){0.f,0.f,0.f,0.f};

  for (int kc = 0; kc < KC; kc += 64){
    int kb = kbase + kc;
    #pragma unroll
    for (int u = tid; u < 512; u += 256){
      int r = u >> 3, s = u & 7;
      *(uint4*)&Asl[r][s*8] = *(const uint4*)(Abf + ((size_t)(m0+r) << 11) + kb + s*8);
    }
    #pragma unroll
    for (int u = tid; u < BN*8; u += 256){
      int n = u >> 3, s = u & 7;
      *(uint4*)&Bsl[n][s*8] = *(const uint4*)(BtG + ((size_t)n << 11) + kb + s*8);
    }
    __syncthreads();
    #pragma unroll
    for (int k0 = 0; k0 < 64; k0 += 32){
      bf16x8 af = *(const bf16x8*)&Asl[16*w + ml][k0 + quad*8];
      #pragma unroll
      for (int ct = 0; ct < BN/16; ct++){
        bf16x8 bfr = *(const bf16x8*)&Bsl[16*ct + ml][k0 + quad*8];
        acc[ct] = __builtin_amdgcn_mfma_f32_16x16x32_bf16(af, bfr, acc[ct], 0, 0, 0);
      }
    }
    __syncthreads();
  }
  float* C = Cp + (size_t)blockIdx.y * (N * BN);
  #pragma unroll
  for (int ct = 0; ct < BN/16; ct++)
    #pragma unroll
    for (int r = 0; r < 4; r++){
      int row = m0 + 16*w + quad*4 + r;
      C[(size_t)row*BN + 16*ct + ml] = acc[ct][r];
    }
}

// ---------- coalesced partial sums -> dA-scaled bf16 ----------
__global__ __launch_bounds__(256) void k_sumY1(const float* __restrict__ Y1p,
    const float* __restrict__ dA, unsigned short* __restrict__ Ub1){
  int idx4 = blockIdx.x*256 + threadIdx.x;     // N*H/4 = 32768
  int i = idx4 >> 4;
  float4 s = ((const float4*)Y1p)[idx4];
  #pragma unroll
  for (int p = 1; p < S1; p++){
    float4 v = ((const float4*)Y1p)[(size_t)p*(N*H/4) + idx4];
    s.x += v.x; s.y += v.y; s.z += v.z; s.w += v.w;
  }
  float d = dA[i];
  ushort4 o;
  o.x = f2bf(s.x*d); o.y = f2bf(s.y*d); o.z = f2bf(s.z*d); o.w = f2bf(s.w*d);
  ((ushort4*)Ub1)[idx4] = o;
}

__global__ __launch_bounds__(256) void k_sumY2(const float* __restrict__ Y2p,
    const float* __restrict__ dA, unsigned short* __restrict__ Ub2){
  int idx4 = blockIdx.x*256 + threadIdx.x;     // N*128/4 = 65536
  int i = idx4 >> 5;
  float4 s = ((const float4*)Y2p)[idx4];
  #pragma unroll
  for (int p = 1; p < S2; p++){
    float4 v = ((const float4*)Y2p)[(size_t)p*(N*128/4) + idx4];
    s.x += v.x; s.y += v.y; s.z += v.z; s.w += v.w;
  }
  float d = dA[i];
  ushort4 o;
  o.x = f2bf(s.x*d); o.y = f2bf(s.y*d); o.z = f2bf(s.z*d); o.w = f2bf(s.w*d);
  ((ushort4*)Ub2)[idx4] = o;
}

// ---------- gather 1: vf = Af @ h  -> bf16 row-major (1 row per wave) ----------
__global__ __launch_bounds__(256) void k_gather1(const float* __restrict__ h,
    const int* __restrict__ nidx, const float* __restrict__ ncos,
    const float* __restrict__ df, unsigned short* __restrict__ Vb1){
  int tid = threadIdx.x, w = tid >> 6, t = tid & 63;
  int i = blockIdx.x*4 + w;
  int j0 = nidx[i*4], j1 = nidx[i*4+1], j2 = nidx[i*4+2], j3 = nidx[i*4+3];
  float di = df[i];
  float w0 = ncos[i*4]  *di*df[j0];
  float w1 = ncos[i*4+1]*di*df[j1];
  float w2 = ncos[i*4+2]*di*df[j2];
  float w3 = ncos[i*4+3]*di*df[j3];
  float v = w0*h[(size_t)j0*H+t] + w1*h[(size_t)j1*H+t]
          + w2*h[(size_t)j2*H+t] + w3*h[(size_t)j3*H+t];
  Vb1[(size_t)i*H + t] = f2bf(v);
}

// ---------- gather 2: vf2 = Af @ z1f, vc2 = Af @ z1cf ----------
__global__ __launch_bounds__(256) void k_gather2(const float* __restrict__ z1f,
    const float* __restrict__ z1cf,
    const int* __restrict__ nidx, const float* __restrict__ ncos,
    const float* __restrict__ df,
    unsigned short* __restrict__ Vf2, unsigned short* __restrict__ Vc2){
  int tid = threadIdx.x, w = tid >> 6, t = tid & 63;
  int i = blockIdx.x*4 + w;
  int j0 = nidx[i*4], j1 = nidx[i*4+1], j2 = nidx[i*4+2], j3 = nidx[i*4+3];
  float di = df[i];
  float w0 = ncos[i*4]  *di*df[j0];
  float w1 = ncos[i*4+1]*di*df[j1];
  float w2 = ncos[i*4+2]*di*df[j2];
  float w3 = ncos[i*4+3]*di*df[j3];
  float vf = w0*z1f[(size_t)j0*H+t] + w1*z1f[(size_t)j1*H+t]
           + w2*z1f[(size_t)j2*H+t] + w3*z1f[(size_t)j3*H+t];
  float vc = w0*z1cf[(size_t)j0*H+t] + w1*z1cf[(size_t)j1*H+t]
           + w2*z1cf[(size_t)j2*H+t] + w3*z1cf[(size_t)j3*H+t];
  Vf2[(size_t)i*H + t] = f2bf(vf);
  Vc2[(size_t)i*H + t] = f2bf(vc);
}

// ---------- z1 linear layers via MFMA: grid (32 row-groups, 4 products) ----------
// p0: z1f = leaky(Vb1@WF1^T+bF1)   p1: z1cf = leaky(Vb1@WC1^T+bC1)
// p2: ZsT[0:64]  = dA*leaky(Ub1@WT1^T+bT1)  (transposed bf16)
// p3: ZsT[64:128]= dA*leaky(Ub1@WC1^T+bC1)
__global__ __launch_bounds__(256) void k_z1m(
    const unsigned short* __restrict__ Vb1, const unsigned short* __restrict__ Ub1,
    const float* __restrict__ WF1, const float* __restrict__ WC1,
    const float* __restrict__ WT1, const float* __restrict__ bF1,
    const float* __restrict__ bC1, const float* __restrict__ bT1,
    const float* __restrict__ dA,
    float* __restrict__ z1f, float* __restrict__ z1cf,
    unsigned short* __restrict__ ZsT){
  __shared__ __align__(16) unsigned short Vs[64][72];
  __shared__ __align__(16) unsigned short Ws[64][72];
  __shared__ __align__(16) unsigned short Tb[64][72];
  __shared__ float bias[64], dAl[64];
  int p = blockIdx.y, i0 = blockIdx.x * 64, tid = threadIdx.x;
  const unsigned short* Vsrc = (p < 2) ? Vb1 : Ub1;
  const float* Wsrc = (p == 0) ? WF1 : (p == 2) ? WT1 : WC1;
  const float* bsrc = (p == 0) ? bF1 : (p == 2) ? bT1 : bC1;
  #pragma unroll
  for (int u = tid; u < 512; u += 256){
    int r = u >> 3, s = u & 7;
    *(uint4*)&Vs[r][s*8] = *(const uint4*)(Vsrc + (size_t)(i0+r)*H + s*8);
  }
  for (int u = tid; u < 1024; u += 256){
    int r = u >> 4, c4 = (u & 15)*4;
    float4 f = *(const float4*)(Wsrc + (size_t)r*H + c4);
    Ws[r][c4+0] = f2bf(f.x); Ws[r][c4+1] = f2bf(f.y);
    Ws[r][c4+2] = f2bf(f.z); Ws[r][c4+3] = f2bf(f.w);
  }
  if (tid < 64){ bias[tid] = bsrc[tid]; dAl[tid] = dA[i0 + tid]; }
  __syncthreads();
  int w = tid >> 6, lane = tid & 63, quad = lane >> 4, ml = lane & 15;
  floatx4 acc[4];
  #pragma unroll
  for (int ct = 0; ct < 4; ct++) acc[ct] = (floatx4){0.f,0.f,0.f,0.f};
  #pragma unroll
  for (int k0 = 0; k0 < 64; k0 += 32){
    bf16x8 af = *(const bf16x8*)&Vs[16*w + ml][k0 + quad*8];
    #pragma unroll
    for (int ct = 0; ct < 4; ct++){
      bf16x8 bfr = *(const bf16x8*)&Ws[16*ct + ml][k0 + quad*8];
      acc[ct] = __builtin_amdgcn_mfma_f32_16x16x32_bf16(af, bfr, acc[ct], 0, 0, 0);
    }
  }
  if (p < 2){
    float* dst = (p == 0) ? z1f : z1cf;
    #pragma unroll
    for (int ct = 0; ct < 4; ct++){
      int col = 16*ct + ml;
      #pragma unroll
      for (int r = 0; r < 4; r++){
        int row = 16*w + quad*4 + r;
        dst[(size_t)(i0+row)*H + col] = leaky(acc[ct][r] + bias[col]);
      }
    }
  } else {
    #pragma unroll
    for (int ct = 0; ct < 4; ct++){
      int col = 16*ct + ml;
      #pragma unroll
      for (int r = 0; r < 4; r++){
        int row = 16*w + quad*4 + r;
        Tb[col][row] = f2bf(dAl[row] * leaky(acc[ct][r] + bias[col]));
      }
    }
    __syncthreads();
    int zb = (p == 2) ? 0 : 64;
    #pragma unroll
    for (int u = tid; u < 512; u += 256){
      int c = u >> 3, s = u & 7;
      *(uint4*)&ZsT[(size_t)(zb + c)*N + i0 + s*8] = *(uint4*)&Tb[c][s*8];
    }
  }
}

// ---------- z2 linear layers via MFMA: grid (32, 4) -> Z6 (+norms) ----------
// p0: zf = Vf2@WF2 -> Z_ZF    p1: zcf = Vc2@WC2 -> Z_ZCF + Z_LCF
// p2: zt = Ub2[:, :64]@WT2 -> Z_ZT   p3: zct = Ub2[:,64:]@WC2 -> Z_ZCT + Z_LCT
__global__ __launch_bounds__(256) void k_z2m(
    const unsigned short* __restrict__ Vf2, const unsigned short* __restrict__ Vc2,
    const unsigned short* __restrict__ Ub2,
    const float* __restrict__ WF2, const float* __restrict__ WC2,
    const float* __restrict__ WT2, const float* __restrict__ bF2,
    const float* __restrict__ bC2, const float* __restrict__ bT2,
    float* __restrict__ Z6){
  __shared__ __align__(16) unsigned short Vs[64][72];
  __shared__ __align__(16) unsigned short Ws[64][72];
  __shared__ float bias[64];
  int p = blockIdx.y, i0 = blockIdx.x * 64, tid = threadIdx.x;
  const unsigned short* vptr = (p == 0) ? Vf2 : (p == 1) ? Vc2 : Ub2;
  int vstride = (p < 2) ? 64 : 128;
  int voff = (p == 3) ? 64 : 0;
  const float* Wsrc = (p == 0) ? WF2 : (p == 2) ? WT2 : WC2;
  const float* bsrc = (p == 0) ? bF2 : (p == 2) ? bT2 : bC2;
  #pragma unroll
  for (int u = tid; u < 512; u += 256){
    int r = u >> 3, s = u & 7;
    *(uint4*)&Vs[r][s*8] = *(const uint4*)(vptr + (size_t)(i0+r)*vstride + voff + s*8);
  }
  for (int u = tid; u < 1024; u += 256){
    int r = u >> 4, c4 = (u & 15)*4;
    float4 f = *(const float4*)(Wsrc + (size_t)r*H + c4);
    Ws[r][c4+0] = f2bf(f.x); Ws[r][c4+1] = f2bf(f.y);
    Ws[r][c4+2] = f2bf(f.z); Ws[r][c4+3] = f2bf(f.w);
  }
  if (tid < 64) bias[tid] = bsrc[tid];
  __syncthreads();
  int w = tid >> 6, lane = tid & 63, quad = lane >> 4, ml = lane & 15;
  floatx4 acc[4];
  #pragma unroll
  for (int ct = 0; ct < 4; ct++) acc[ct] = (floatx4){0.f,0.f,0.f,0.f};
  #pragma unroll
  for (int k0 = 0; k0 < 64; k0 += 32){
    bf16x8 af = *(const bf16x8*)&Vs[16*w + ml][k0 + quad*8];
    #pragma unroll
    for (int ct = 0; ct < 4; ct++){
      bf16x8 bfr = *(const bf16x8*)&Ws[16*ct + ml][k0 + quad*8];
      acc[ct] = __builtin_amdgcn_mfma_f32_16x16x32_bf16(af, bfr, acc[ct], 0, 0, 0);
    }
  }
  int zoff = (p == 0) ? Z_ZF : (p == 1) ? Z_ZCF : (p == 2) ? Z_ZT : Z_ZCT;
  float val[4][4];
  #pragma unroll
  for (int ct = 0; ct < 4; ct++){
    int col = 16*ct + ml;
    #pragma unroll
    for (int r = 0; r < 4; r++){
      val[ct][r] = leaky(acc[ct][r] + bias[col]);
      int row = 16*w + quad*4 + r;
      Z6[(size_t)(i0+row)*384 + zoff + col] = val[ct][r];
    }
  }
  if (p == 1 || p == 3){
    int loff = (p == 1) ? Z_LCF : Z_LCT;
    #pragma unroll
    for (int r = 0; r < 4; r++){
      float s = val[0][r]*val[0][r] + val[1][r]*val[1][r]
              + val[2][r]*val[2][r] + val[3][r]*val[3][r];
      s += __shfl_xor(s, 1, 64); s += __shfl_xor(s, 2, 64);
      s += __shfl_xor(s, 4, 64); s += __shfl_xor(s, 8, 64);
      float m = sqrtf(s*(1.f/64.f)) + 1e-10f;
      int row = 16*w + quad*4 + r;
      #pragma unroll
      for (int ct = 0; ct < 4; ct++)
        Z6[(size_t)(i0+row)*384 + loff + 16*ct + ml] = val[ct][r]/m;
    }
  }
}

// ---------- attention + out projection: 1 row per wave ----------
__global__ __launch_bounds__(256) void k_att(const float* __restrict__ Z6,
    const float* __restrict__ Wag, const float* __restrict__ ba,
    const float* __restrict__ q, const float* __restrict__ W2g,
    const float* __restrict__ b2, float* __restrict__ out){
  __shared__ float Wal[64][65];
  __shared__ float W2l[448];
  __shared__ float zbuf[4][3][66];
  __shared__ float zagg[4][66];
  int tid = threadIdx.x, w = tid >> 6, t = tid & 63;
  for (int u = tid; u < 1024; u += 256){
    int r = u >> 4, c4 = (u & 15)*4;
    float4 f = ((const float4*)Wag)[u];
    Wal[r][c4+0]=f.x; Wal[r][c4+1]=f.y; Wal[r][c4+2]=f.z; Wal[r][c4+3]=f.w;
  }
  if (tid < 112) *(float4*)&W2l[tid*4] = ((const float4*)W2g)[tid];
  __syncthreads();
  int i = blockIdx.x*4 + w;
  const float* zr = Z6 + (size_t)i*384;
  float zf = zr[Z_ZF + t], zt = zr[Z_ZT + t];
  float zc = 0.5f*(zr[Z_ZCF + t] + zr[Z_ZCT + t]);
  zbuf[w][0][t] = zf; zbuf[w][1][t] = zt; zbuf[w][2][t] = zc;
  __syncthreads();
  float bav = ba[t], qv = q[t];
  float e[3];
  #pragma unroll
  for (int k = 0; k < 3; k++){
    float S = bav;
    #pragma unroll 8
    for (int c = 0; c < 64; c++) S += zbuf[w][k][c] * Wal[t][c];
    e[k] = waveRedSum(tanhf(S)*qv);
  }
  float mx = fmaxf(e[0], fmaxf(e[1], e[2]));
  float x0 = expf(e[0]-mx), x1 = expf(e[1]-mx), x2 = expf(e[2]-mx);
  float inv = 1.f/(x0+x1+x2);
  zagg[w][t] = x0*inv*zf + x1*inv*zt + x2*inv*zc;
  __syncthreads();
  if (t < OUTD){
    float acc = b2[t];
    #pragma unroll 8
    for (int c = 0; c < 64; c++) acc += zagg[w][c]*W2l[t*64 + c];
    out[(size_t)i*OUTD + t] = acc;
  }
}

// ---------- k_reduce: 5 products x RS row-splits, 64x64 tile GEMM each ----------
__global__ __launch_bounds__(256) void k_reduce(const float* __restrict__ Z6,
                                                float* __restrict__ redP,
                                                float* __restrict__ colP){
  __shared__ float sa[64][68];
  __shared__ float sb[64][68];
  int p = blockIdx.x >> 5;     // RS = 32
  int s = blockIdx.x & 31;
  int tid = threadIdx.x;
  const int aoffT[5] = {Z_ZT,  Z_ZF,  Z_LCF, Z_LCF, Z_LCT};
  const int boffT[5] = {Z_ZCT, Z_ZCF, Z_LCF, Z_LCT, Z_LCT};
  int aoff = aoffT[p], boff = boffT[p];
  int r0 = s * 64;
  {
    int row = tid >> 4, c4 = (tid & 15) * 4;
    #pragma unroll
    for (int rr = 0; rr < 64; rr += 16){
      const float* zr = Z6 + (size_t)(r0 + row + rr) * 384;
      *(float4*)&sa[row + rr][c4] = *(const float4*)&zr[aoff + c4];
      *(float4*)&sb[row + rr][c4] = *(const float4*)&zr[boff + c4];
    }
  }
  __syncthreads();
  int rg = tid >> 4, cg = tid & 15;
  float acc[4][4] = {};
  #pragma unroll 8
  for (int k = 0; k < 64; k++){
    float a[4], b[4];
    *(float4*)a = *(const float4*)&sa[k][rg*4];
    *(float4*)b = *(const float4*)&sb[k][cg*4];
    #pragma unroll
    for (int ii = 0; ii < 4; ii++)
      #pragma unroll
      for (int jj = 0; jj < 4; jj++)
        acc[ii][jj] += a[ii]*b[jj];
  }
  float* rp = redP + (size_t)blockIdx.x * 4096;
  #pragma unroll
  for (int ii = 0; ii < 4; ii++)
    *(float4*)&rp[(rg*4+ii)*64 + cg*4] =
      make_float4(acc[ii][0], acc[ii][1], acc[ii][2], acc[ii][3]);
  if (p < 2 && tid < 128){
    int t = tid & 63;
    float csum = 0.f;
    if (tid < 64){
      #pragma unroll 16
      for (int r = 0; r < 64; r++) csum += sa[r][t];
    } else {
      #pragma unroll 16
      for (int r = 0; r < 64; r++) csum += sb[r][t];
    }
    colP[((size_t)p*RS + s)*128 + tid] = csum;
  }
}

// ---------- sum partial slabs into red ----------
__global__ void k_combine(const float* __restrict__ redP,
                          const float* __restrict__ colP,
                          float* __restrict__ red){
  int idx = blockIdx.x*256 + threadIdx.x;
  if (idx < 20480){
    int p = idx >> 12, i = idx & 4095;
    float sum = 0.f;
    #pragma unroll 8
    for (int s = 0; s < RS; s++) sum += redP[((size_t)p*RS + s)*4096 + i];
    red[idx] = sum;
  } else if (idx < 20736){
    int j = idx - 20480;
    int p = j >> 7, rem = j & 127;
    float sum = 0.f;
    #pragma unroll 8
    for (int s = 0; s < RS; s++) sum += colP[((size_t)p*RS + s)*128 + rem];
    red[idx] = sum;
  }
}

// ---------- final scalars Lc, Ld ----------
__global__ void k_final(const float* __restrict__ red, float* __restrict__ out2){
  int tid = threadIdx.x;
  const float* Stc = red;
  const float* Sfc = red + 4096;
  const float* Cff = red + 8192;
  const float* Cft = red + 12288;
  const float* Ctt = red + 16384;
  const float* cst = red + 20480;
  const float* csct= red + 20544;
  const float* csf = red + 20608;
  const float* cscf= red + 20672;
  float sCff=0, sCft=0, sCtt=0, sM1=0, sM2=0;
  for (int u = tid*16; u < tid*16+16; u++){
    int d = u >> 6, e = u & 63;
    float m1 = Stc[u] - cst[d]*csct[e]*(1.f/2048.f);
    float m2 = Sfc[u] - csf[d]*cscf[e]*(1.f/2048.f);
    sM1 += m1*m1; sM2 += m2*m2;
    float cf = Cff[u], cx = Cft[u], ct = Ctt[u];
    sCff += cf*cf; sCft += cx*cx; sCtt += ct*ct;
  }
  __shared__ float rd[5][4];
  sCff = waveRedSum(sCff); sCft = waveRedSum(sCft); sCtt = waveRedSum(sCtt);
  sM1 = waveRedSum(sM1);   sM2 = waveRedSum(sM2);
  int w = tid >> 6, lane = tid & 63;
  if (lane == 0){ rd[0][w]=sCff; rd[1][w]=sCft; rd[2][w]=sCtt; rd[3][w]=sM1; rd[4][w]=sM2; }
  __syncthreads();
  if (tid == 0){
    float A0 = rd[0][0]+rd[0][1]+rd[0][2]+rd[0][3];
    float A1 = rd[1][0]+rd[1][1]+rd[1][2]+rd[1][3];
    float A2 = rd[2][0]+rd[2][1]+rd[2][2]+rd[2][3];
    float M1 = rd[3][0]+rd[3][1]+rd[3][2]+rd[3][3];
    float M2 = rd[4][0]+rd[4][1]+rd[4][2]+rd[4][3];
    out2[0] = (A0 - 2.f*A1 + A2) * (1.f/(2048.f*2048.f));
    out2[1] = (M1 + M2) * (1.f/(2047.f*2047.f));
  }
}

extern "C" void kernel_launch(void* const* d_in, const int* in_sizes, int n_in,
                              void* d_out, int out_size, void* d_ws, size_t ws_size,
                              hipStream_t stream) {
  const float* x   = (const float*)d_in[0];
  const float* A   = (const float*)d_in[1];
  const float* W1  = (const float*)d_in[3];
  const float* b1  = (const float*)d_in[4];
  const float* WF1 = (const float*)d_in[5];
  const float* bF1 = (const float*)d_in[6];
  const float* WF2 = (const float*)d_in[7];
  const float* bF2 = (const float*)d_in[8];
  const float* WT1 = (const float*)d_in[9];
  const float* bT1 = (const float*)d_in[10];
  const float* WT2 = (const float*)d_in[11];
  const float* bT2 = (const float*)d_in[12];
  const float* WC1 = (const float*)d_in[13];
  const float* bC1 = (const float*)d_in[14];
  const float* WC2 = (const float*)d_in[15];
  const float* bC2 = (const float*)d_in[16];
  const float* Wa  = (const float*)d_in[17];
  const float* ba  = (const float*)d_in[18];
  const float* q   = (const float*)d_in[19];
  const float* W2  = (const float*)d_in[20];
  const float* b2  = (const float*)d_in[21];
  float* out = (float*)d_out;

  float* W = (float*)d_ws;
  float* h_   = W;                      // N*H
  float* dA   = h_  + N*H;              // N
  float* sq   = dA  + N;                // N
  float* hsum = sq  + N;                // N
  float* df   = hsum+ N;                // N
  int*   nidx = (int*)(df + N);         // N*4
  float* ncos = (float*)(nidx + N*4);   // N*4
  float* red  = ncos + N*4;             // 20736
  float* DOT  = red + 20736;            // N*N
  float* Z6   = DOT + (size_t)N*N;      // N*384
  float* Y1p  = Z6  + (size_t)N*384;    // S1*N*H
  float* Y2p  = Y1p + (size_t)S1*N*H;   // S2*N*128
  float* z1f  = Y2p + (size_t)S2*N*128; // N*H
  float* z1cf = z1f + N*H;              // N*H
  float* redP = z1cf+ N*H;              // 5*RS*4096 = 655360
  float* colP = redP+ 655360;           // 2*RS*128 = 8192
  unsigned short* Abf = (unsigned short*)(colP + 8192);  // N*N bf16
  unsigned short* hsT = Abf + (size_t)N*N;               // 64*N
  unsigned short* ZsT = hsT + (size_t)H*N;               // 128*N
  unsigned short* Vb1 = ZsT + (size_t)128*N;             // N*64
  unsigned short* Ub1 = Vb1 + (size_t)N*H;               // N*64
  unsigned short* Vf2 = Ub1 + (size_t)N*H;               // N*64
  unsigned short* Vc2 = Vf2 + (size_t)N*H;               // N*64
  unsigned short* Ub2 = Vc2 + (size_t)N*H;               // N*128

  k_prep<<<N, 256, 0, stream>>>(A, dA, Abf);
  k_h<<<128, 256, 0, stream>>>(x, W1, b1, dA, h_, hsT, sq, hsum);
  k_gram<<<dim3(16,16), 256, 0, stream>>>(h_, DOT);
  k_topk<<<N, 256, 0, stream>>>(DOT, sq, hsum, nidx, ncos, df);
  k_gather1<<<512, 256, 0, stream>>>(h_, nidx, ncos, df, Vb1);

  k_mgemm<64><<<dim3(32,S1), 256, 0, stream>>>(Abf, hsT, Y1p, N/S1);
  k_sumY1<<<128, 256, 0, stream>>>(Y1p, dA, Ub1);
  k_z1m<<<dim3(32,4), 256, 0, stream>>>(Vb1, Ub1, WF1, WC1, WT1, bF1, bC1, bT1,
                                        dA, z1f, z1cf, ZsT);
  k_mgemm<128><<<dim3(32,S2), 256, 0, stream>>>(Abf, ZsT, Y2p, N/S2);
  k_sumY2<<<256, 256, 0, stream>>>(Y2p, dA, Ub2);
  k_gather2<<<512, 256, 0, stream>>>(z1f, z1cf, nidx, ncos, df, Vf2, Vc2);
  k_z2m<<<dim3(32,4), 256, 0, stream>>>(Vf2, Vc2, Ub2, WF2, WC2, WT2,
                                        bF2, bC2, bT2, Z6);
  k_att<<<512, 256, 0, stream>>>(Z6, Wa, ba, q, W2, b2, out);
  k_reduce<<<5*RS, 256, 0, stream>>>(Z6, redP, colP);
  k_combine<<<81, 256, 0, stream>>>(redP, colP, red);
  k_final<<<1, 256, 0, stream>>>(red, out + (size_t)N*OUTD);
}

// Round 9
// 197.204 us; speedup vs baseline: 3.7069x; 1.0348x over previous
//
#include <hip/hip_runtime.h>
#include <stdint.h>

#define N 2048
#define DIN 128
#define H 64
#define OUTD 7
#define RS 32    // k_reduce row-splits per product
#define S1 8     // gemm1 K-splits
#define S2 8     // gemm2 K-splits

// Z6 row layout: [zt(64) | zct(64) | zf(64) | zcf(64) | Lcf(64) | Lct(64)]
#define Z_ZT  0
#define Z_ZCT 64
#define Z_ZF  128
#define Z_ZCF 192
#define Z_LCF 256
#define Z_LCT 320

typedef short bf16x8 __attribute__((ext_vector_type(8)));
typedef float floatx4 __attribute__((ext_vector_type(4)));

__device__ __forceinline__ float leaky(float x){ return x > 0.f ? x : 0.1f*x; }

__device__ __forceinline__ unsigned short f2bf(float f){
  unsigned int u = __float_as_uint(f);
  u = u + 0x7FFFu + ((u >> 16) & 1u);   // RNE
  return (unsigned short)(u >> 16);
}

__device__ __forceinline__ float bf2f(unsigned short u){
  return __uint_as_float((unsigned int)u << 16);
}

__device__ __forceinline__ float waveRedSum(float v){
  #pragma unroll
  for (int o = 32; o > 0; o >>= 1) v += __shfl_xor(v, o, 64);
  return v;
}

__device__ __forceinline__ unsigned long long shflx64(unsigned long long v, int m){
  unsigned int lo = (unsigned int)v, hi = (unsigned int)(v >> 32);
  lo = (unsigned int)__shfl_xor((int)lo, m, 64);
  hi = (unsigned int)__shfl_xor((int)hi, m, 64);
  return ((unsigned long long)hi << 32) | lo;
}

// ---------- row sums of A -> dA, and cast A -> bf16 (fused; one A read) ----------
__global__ void k_prep(const float* __restrict__ A, float* __restrict__ dA,
                       unsigned short* __restrict__ Abf){
  int i = blockIdx.x;
  const float4* row = (const float4*)(A + (size_t)i * N);
  unsigned short* ob = Abf + (size_t)i * N;
  float s = 0.f;
  #pragma unroll
  for (int it = 0; it < 2; it++){
    int u = threadIdx.x + it*256;
    float4 v = row[u];
    s += v.x + v.y + v.z + v.w;
    ushort4 o;
    o.x = f2bf(v.x); o.y = f2bf(v.y); o.z = f2bf(v.z); o.w = f2bf(v.w);
    *(ushort4*)&ob[u*4] = o;
  }
  __shared__ float red[4];
  s = waveRedSum(s);
  int wid = threadIdx.x >> 6, lane = threadIdx.x & 63;
  if (lane == 0) red[wid] = s;
  __syncthreads();
  if (threadIdx.x == 0){
    float t = red[0] + red[1] + red[2] + red[3];
    dA[i] = 1.0f / sqrtf(t + 1e-10f);
  }
}

// ---------- h: 16 rows/block; emits hb_hi/hb_lo (split bf16), hsT, sq, hsum ----------
__global__ __launch_bounds__(256) void k_h(const float* __restrict__ x,
                    const float* __restrict__ W1g, const float* __restrict__ b1,
                    const float* __restrict__ dA,
                    unsigned short* __restrict__ hb_hi,
                    unsigned short* __restrict__ hb_lo,
                    unsigned short* __restrict__ hsT,
                    float* __restrict__ sq, float* __restrict__ hsum){
  __shared__ float W1t[DIN][H+1];            // W1t[c][t] = W1[t][c]
  __shared__ float xb[4][DIN];
  __shared__ __align__(16) unsigned short hTb[H][16];
  int tid = threadIdx.x, w = tid >> 6, t = tid & 63;
  int i0 = blockIdx.x * 16;
  for (int u = tid; u < 2048; u += 256){
    float4 g = ((const float4*)W1g)[u];
    int row = u >> 5, c0 = (u & 31) * 4;
    W1t[c0+0][row] = g.x; W1t[c0+1][row] = g.y;
    W1t[c0+2][row] = g.z; W1t[c0+3][row] = g.w;
  }
  __syncthreads();
  float bt = b1[t];
  for (int rr = 0; rr < 4; rr++){
    int i = i0 + w*4 + rr;
    xb[w][t]      = x[(size_t)i*DIN + t];
    xb[w][t + 64] = x[(size_t)i*DIN + t + 64];
    float acc = bt;
    #pragma unroll
    for (int c4 = 0; c4 < DIN/4; c4++){
      float xv[4]; *(float4*)xv = *(const float4*)&xb[w][c4*4];
      acc += xv[0]*W1t[c4*4+0][t] + xv[1]*W1t[c4*4+1][t]
           + xv[2]*W1t[c4*4+2][t] + xv[3]*W1t[c4*4+3][t];
    }
    float hv = leaky(acc);
    unsigned short hi = f2bf(hv);
    hb_hi[(size_t)i*H + t] = hi;
    hb_lo[(size_t)i*H + t] = f2bf(hv - bf2f(hi));
    hTb[t][w*4+rr] = f2bf(dA[i]*hv);
    float s2 = waveRedSum(hv*hv);
    float s1 = waveRedSum(hv);
    if (t == 0){ sq[i] = s2; hsum[i] = s1; }
  }
  __syncthreads();
  { int c = tid >> 2, qq = tid & 3;
    ushort4 v = *(ushort4*)&hTb[c][qq*4];
    *(ushort4*)&hsT[(size_t)c*N + i0 + qq*4] = v; }
}

// ---------- DOT = h @ h^T via split-bf16 MFMA (fp32-accurate) ----------
__global__ __launch_bounds__(256) void k_gram2(
    const unsigned short* __restrict__ Hhi, const unsigned short* __restrict__ Hlo,
    float* __restrict__ DOT){
  __shared__ __align__(16) unsigned short Bh[128][72];
  __shared__ __align__(16) unsigned short Bl[128][72];
  int bi = blockIdx.x, bj = blockIdx.y, tid = threadIdx.x;
  for (int u = tid; u < 1024; u += 256){
    int r = u >> 3, s = u & 7;
    *(uint4*)&Bh[r][s*8] = *(const uint4*)(Hhi + (size_t)(bj*128+r)*H + s*8);
    *(uint4*)&Bl[r][s*8] = *(const uint4*)(Hlo + (size_t)(bj*128+r)*H + s*8);
  }
  __syncthreads();
  int w = tid >> 6, lane = tid & 63, quad = lane >> 4, ml = lane & 15;
  floatx4 acc[2][8];
  #pragma unroll
  for (int rt = 0; rt < 2; rt++)
    #pragma unroll
    for (int ct = 0; ct < 8; ct++) acc[rt][ct] = (floatx4){0.f,0.f,0.f,0.f};
  #pragma unroll
  for (int rt = 0; rt < 2; rt++){
    int arow = bi*128 + (2*w + rt)*16 + ml;
    #pragma unroll
    for (int k0 = 0; k0 < 64; k0 += 32){
      bf16x8 ah = *(const bf16x8*)(Hhi + (size_t)arow*H + k0 + quad*8);
      bf16x8 al = *(const bf16x8*)(Hlo + (size_t)arow*H + k0 + quad*8);
      #pragma unroll
      for (int ct = 0; ct < 8; ct++){
        bf16x8 bh = *(const bf16x8*)&Bh[ct*16 + ml][k0 + quad*8];
        bf16x8 bl = *(const bf16x8*)&Bl[ct*16 + ml][k0 + quad*8];
        acc[rt][ct] = __builtin_amdgcn_mfma_f32_16x16x32_bf16(ah, bh, acc[rt][ct], 0,0,0);
        acc[rt][ct] = __builtin_amdgcn_mfma_f32_16x16x32_bf16(ah, bl, acc[rt][ct], 0,0,0);
        acc[rt][ct] = __builtin_amdgcn_mfma_f32_16x16x32_bf16(al, bh, acc[rt][ct], 0,0,0);
      }
    }
  }
  #pragma unroll
  for (int rt = 0; rt < 2; rt++)
    #pragma unroll
    for (int ct = 0; ct < 8; ct++)
      #pragma unroll
      for (int r = 0; r < 4; r++){
        int row = bi*128 + (2*w+rt)*16 + quad*4 + r;
        DOT[(size_t)row*N + bj*128 + ct*16 + ml] = acc[rt][ct][r];
      }
}

// ---------- per-row top-4 + cos vals + df: 4 rows/block, 1 row/wave ----------
__global__ __launch_bounds__(256) void k_topk(const float* __restrict__ DOT,
      const float* __restrict__ sq, const float* __restrict__ hsum,
      int* __restrict__ nidx, float* __restrict__ ncos, float* __restrict__ df){
  int tid = threadIdx.x, w = tid >> 6, lane = tid & 63;
  int i = blockIdx.x*4 + w;
  const float4* row = (const float4*)(DOT + (size_t)i * N);
  const float4* sq4 = (const float4*)sq;
  unsigned long long best[4] = {~0ULL, ~0ULL, ~0ULL, ~0ULL};
  #pragma unroll
  for (int it = 0; it < 8; it++){
    int u = it*64 + lane;
    float4 d = row[u];
    float4 s = sq4[u];
    float kv[4] = { s.x - 2.f*d.x, s.y - 2.f*d.y, s.z - 2.f*d.z, s.w - 2.f*d.w };
    #pragma unroll
    for (int e = 0; e < 4; e++){
      unsigned int j = (unsigned int)(u*4 + e);
      unsigned int uk = __float_as_uint(kv[e]);
      uk = (uk & 0x80000000u) ? ~uk : (uk | 0x80000000u);
      unsigned long long c = ((unsigned long long)uk << 32) | j;
      if (c < best[3]){
        best[3] = c;
        unsigned long long t0;
        if (best[3] < best[2]){ t0 = best[2]; best[2] = best[3]; best[3] = t0; }
        if (best[2] < best[1]){ t0 = best[1]; best[1] = best[2]; best[2] = t0; }
        if (best[1] < best[0]){ t0 = best[0]; best[0] = best[1]; best[1] = t0; }
      }
    }
  }
  unsigned long long win[4];
  #pragma unroll
  for (int r = 0; r < 4; r++){
    unsigned long long m = best[0];
    #pragma unroll
    for (int o = 1; o < 64; o <<= 1){
      unsigned long long other = shflx64(m, o);
      if (other < m) m = other;
    }
    win[r] = m;
    if      (best[0]==m){best[0]=best[1];best[1]=best[2];best[2]=best[3];best[3]=~0ULL;}
    else if (best[1]==m){best[1]=best[2];best[2]=best[3];best[3]=~0ULL;}
    else if (best[2]==m){best[2]=best[3];best[3]=~0ULL;}
    else if (best[3]==m){best[3]=~0ULL;}
  }
  float myc = 0.f;
  if (lane < 4){
    unsigned long long wv = win[lane];
    unsigned int j = (unsigned int)wv;
    unsigned int uk = (unsigned int)(wv >> 32);
    float key = (uk & 0x80000000u) ? __uint_as_float(uk ^ 0x80000000u)
                                   : __uint_as_float(~uk);
    float sqj = sq[j];
    float dot = (sqj - key) * 0.5f;
    float hni = sqrtf(sq[i]), hnj = sqrtf(sqj);
    float cosv = dot/(hni*hnj)
               + 1e-10f*(hsum[i]/hni + hsum[j]/hnj)
               + 64.0f*1e-20f;
    nidx[i*4 + lane] = (int)j;
    ncos[i*4 + lane] = cosv;
    myc = cosv;
  }
  myc += __shfl_xor(myc, 1, 64);
  myc += __shfl_xor(myc, 2, 64);
  if (lane == 0) df[i] = 1.f / sqrtf(myc + 1e-10f);
}

// ---------- MFMA bf16 GEMM: Cp[ks] = Abf[:, ksl] @ BtG^T[ksl, :] ----------
template<int BN>
__global__ __launch_bounds__(256) void k_mgemm(
    const unsigned short* __restrict__ Abf, const unsigned short* __restrict__ BtG,
    float* __restrict__ Cp, int KC){
  __shared__ __align__(16) unsigned short Asl[64][72];
  __shared__ __align__(16) unsigned short Bsl[BN][72];
  int m0 = blockIdx.x * 64, kbase = blockIdx.y * KC;
  int tid = threadIdx.x;
  int w = tid >> 6, lane = tid & 63;
  int quad = lane >> 4, ml = lane & 15;
  floatx4 acc[BN/16];
  #pragma unroll
  for (int ct = 0; ct < BN/16; ct++) acc[ct] = (floatx4){0.f,0.f,0.f,0.f};

  for (int kc = 0; kc < KC; kc += 64){
    int kb = kbase + kc;
    #pragma unroll
    for (int u = tid; u < 512; u += 256){
      int r = u >> 3, s = u & 7;
      *(uint4*)&Asl[r][s*8] = *(const uint4*)(Abf + ((size_t)(m0+r) << 11) + kb + s*8);
    }
    #pragma unroll
    for (int u = tid; u < BN*8; u += 256){
      int n = u >> 3, s = u & 7;
      *(uint4*)&Bsl[n][s*8] = *(const uint4*)(BtG + ((size_t)n << 11) + kb + s*8);
    }
    __syncthreads();
    #pragma unroll
    for (int k0 = 0; k0 < 64; k0 += 32){
      bf16x8 af = *(const bf16x8*)&Asl[16*w + ml][k0 + quad*8];
      #pragma unroll
      for (int ct = 0; ct < BN/16; ct++){
        bf16x8 bfr = *(const bf16x8*)&Bsl[16*ct + ml][k0 + quad*8];
        acc[ct] = __builtin_amdgcn_mfma_f32_16x16x32_bf16(af, bfr, acc[ct], 0, 0, 0);
      }
    }
    __syncthreads();
  }
  float* C = Cp + (size_t)blockIdx.y * (N * BN);
  #pragma unroll
  for (int ct = 0; ct < BN/16; ct++)
    #pragma unroll
    for (int r = 0; r < 4; r++){
      int row = m0 + 16*w + quad*4 + r;
      C[(size_t)row*BN + 16*ct + ml] = acc[ct][r];
    }
}

// ---------- z1 layers via MFMA, fused gather (p0/p1) + partial-sum (p2/p3) ----------
// p0: z1f = leaky(gather(hb)@WF1^T+bF1)   p1: z1cf = ...WC1...
// p2: ZsT[0:64]  = dA*leaky((dA*sumY1)@WT1^T+bT1)
// p3: ZsT[64:128]= dA*leaky((dA*sumY1)@WC1^T+bC1)
__global__ __launch_bounds__(256) void k_z1m(
    const unsigned short* __restrict__ hb,
    const int* __restrict__ nidx, const float* __restrict__ ncos,
    const float* __restrict__ df,
    const float* __restrict__ Y1p, const float* __restrict__ dA,
    const float* __restrict__ WF1, const float* __restrict__ WC1,
    const float* __restrict__ WT1, const float* __restrict__ bF1,
    const float* __restrict__ bC1, const float* __restrict__ bT1,
    float* __restrict__ z1f, float* __restrict__ z1cf,
    unsigned short* __restrict__ ZsT){
  __shared__ __align__(16) unsigned short Vs[64][72];
  __shared__ __align__(16) unsigned short Ws[64][72];
  __shared__ __align__(16) unsigned short Tb[64][72];
  __shared__ float bias[64], dAl[64];
  int p = blockIdx.y, i0 = blockIdx.x * 64, tid = threadIdx.x;
  int w = tid >> 6, lane = tid & 63;
  const float* Wsrc = (p == 0) ? WF1 : (p == 2) ? WT1 : WC1;
  const float* bsrc = (p == 0) ? bF1 : (p == 2) ? bT1 : bC1;
  for (int u = tid; u < 1024; u += 256){
    int r = u >> 4, c4 = (u & 15)*4;
    float4 f = *(const float4*)(Wsrc + (size_t)r*H + c4);
    Ws[r][c4+0] = f2bf(f.x); Ws[r][c4+1] = f2bf(f.y);
    Ws[r][c4+2] = f2bf(f.z); Ws[r][c4+3] = f2bf(f.w);
  }
  if (tid < 64){ bias[tid] = bsrc[tid]; dAl[tid] = dA[i0 + tid]; }
  if (p < 2){
    for (int rr = 0; rr < 16; rr++){
      int r = w*16 + rr, i = i0 + r;
      int j0 = nidx[i*4], j1 = nidx[i*4+1], j2 = nidx[i*4+2], j3 = nidx[i*4+3];
      float di = df[i];
      float w0 = ncos[i*4]  *di*df[j0];
      float w1 = ncos[i*4+1]*di*df[j1];
      float w2 = ncos[i*4+2]*di*df[j2];
      float w3 = ncos[i*4+3]*di*df[j3];
      float v = w0*bf2f(hb[(size_t)j0*H+lane]) + w1*bf2f(hb[(size_t)j1*H+lane])
              + w2*bf2f(hb[(size_t)j2*H+lane]) + w3*bf2f(hb[(size_t)j3*H+lane]);
      Vs[r][lane] = f2bf(v);
    }
  } else {
    for (int u = tid; u < 1024; u += 256){
      int r = u >> 4, k4 = u & 15;
      const float* base = Y1p + (size_t)(i0 + r)*H + k4*4;
      float4 s = *(const float4*)base;
      #pragma unroll
      for (int pp = 1; pp < S1; pp++){
        float4 v2 = *(const float4*)(base + (size_t)pp*N*H);
        s.x += v2.x; s.y += v2.y; s.z += v2.z; s.w += v2.w;
      }
      float d = dA[i0 + r];
      Vs[r][k4*4+0] = f2bf(s.x*d); Vs[r][k4*4+1] = f2bf(s.y*d);
      Vs[r][k4*4+2] = f2bf(s.z*d); Vs[r][k4*4+3] = f2bf(s.w*d);
    }
  }
  __syncthreads();
  int quad = lane >> 4, ml = lane & 15;
  floatx4 acc[4];
  #pragma unroll
  for (int ct = 0; ct < 4; ct++) acc[ct] = (floatx4){0.f,0.f,0.f,0.f};
  #pragma unroll
  for (int k0 = 0; k0 < 64; k0 += 32){
    bf16x8 af = *(const bf16x8*)&Vs[16*w + ml][k0 + quad*8];
    #pragma unroll
    for (int ct = 0; ct < 4; ct++){
      bf16x8 bfr = *(const bf16x8*)&Ws[16*ct + ml][k0 + quad*8];
      acc[ct] = __builtin_amdgcn_mfma_f32_16x16x32_bf16(af, bfr, acc[ct], 0, 0, 0);
    }
  }
  if (p < 2){
    float* dst = (p == 0) ? z1f : z1cf;
    #pragma unroll
    for (int ct = 0; ct < 4; ct++){
      int col = 16*ct + ml;
      #pragma unroll
      for (int r = 0; r < 4; r++){
        int row = 16*w + quad*4 + r;
        dst[(size_t)(i0+row)*H + col] = leaky(acc[ct][r] + bias[col]);
      }
    }
  } else {
    #pragma unroll
    for (int ct = 0; ct < 4; ct++){
      int col = 16*ct + ml;
      #pragma unroll
      for (int r = 0; r < 4; r++){
        int row = 16*w + quad*4 + r;
        Tb[col][row] = f2bf(dAl[row] * leaky(acc[ct][r] + bias[col]));
      }
    }
    __syncthreads();
    int zb = (p == 2) ? 0 : 64;
    #pragma unroll
    for (int u = tid; u < 512; u += 256){
      int c = u >> 3, s = u & 7;
      *(uint4*)&ZsT[(size_t)(zb + c)*N + i0 + s*8] = *(uint4*)&Tb[c][s*8];
    }
  }
}

// ---------- z2 layers via MFMA, fused gather (p0/p1) + partial-sum (p2/p3) ----------
// p0: zf -> Z_ZF   p1: zcf -> Z_ZCF + Z_LCF   p2: zt -> Z_ZT   p3: zct -> Z_ZCT + Z_LCT
__global__ __launch_bounds__(256) void k_z2m(
    const float* __restrict__ z1f, const float* __restrict__ z1cf,
    const int* __restrict__ nidx, const float* __restrict__ ncos,
    const float* __restrict__ df,
    const float* __restrict__ Y2p, const float* __restrict__ dA,
    const float* __restrict__ WF2, const float* __restrict__ WC2,
    const float* __restrict__ WT2, const float* __restrict__ bF2,
    const float* __restrict__ bC2, const float* __restrict__ bT2,
    float* __restrict__ Z6){
  __shared__ __align__(16) unsigned short Vs[64][72];
  __shared__ __align__(16) unsigned short Ws[64][72];
  __shared__ float bias[64];
  int p = blockIdx.y, i0 = blockIdx.x * 64, tid = threadIdx.x;
  int w = tid >> 6, lane = tid & 63;
  const float* Wsrc = (p == 0) ? WF2 : (p == 2) ? WT2 : WC2;
  const float* bsrc = (p == 0) ? bF2 : (p == 2) ? bT2 : bC2;
  for (int u = tid; u < 1024; u += 256){
    int r = u >> 4, c4 = (u & 15)*4;
    float4 f = *(const float4*)(Wsrc + (size_t)r*H + c4);
    Ws[r][c4+0] = f2bf(f.x); Ws[r][c4+1] = f2bf(f.y);
    Ws[r][c4+2] = f2bf(f.z); Ws[r][c4+3] = f2bf(f.w);
  }
  if (tid < 64) bias[tid] = bsrc[tid];
  if (p < 2){
    const float* src = (p == 0) ? z1f : z1cf;
    for (int rr = 0; rr < 16; rr++){
      int r = w*16 + rr, i = i0 + r;
      int j0 = nidx[i*4], j1 = nidx[i*4+1], j2 = nidx[i*4+2], j3 = nidx[i*4+3];
      float di = df[i];
      float w0 = ncos[i*4]  *di*df[j0];
      float w1 = ncos[i*4+1]*di*df[j1];
      float w2 = ncos[i*4+2]*di*df[j2];
      float w3 = ncos[i*4+3]*di*df[j3];
      float v = w0*src[(size_t)j0*H+lane] + w1*src[(size_t)j1*H+lane]
              + w2*src[(size_t)j2*H+lane] + w3*src[(size_t)j3*H+lane];
      Vs[r][lane] = f2bf(v);
    }
  } else {
    int off = (p == 2) ? 0 : 64;
    for (int u = tid; u < 1024; u += 256){
      int r = u >> 4, k4 = u & 15;
      const float* base = Y2p + (size_t)(i0 + r)*128 + off + k4*4;
      float4 s = *(const float4*)base;
      #pragma unroll
      for (int pp = 1; pp < S2; pp++){
        float4 v2 = *(const float4*)(base + (size_t)pp*N*128);
        s.x += v2.x; s.y += v2.y; s.z += v2.z; s.w += v2.w;
      }
      float d = dA[i0 + r];
      Vs[r][k4*4+0] = f2bf(s.x*d); Vs[r][k4*4+1] = f2bf(s.y*d);
      Vs[r][k4*4+2] = f2bf(s.z*d); Vs[r][k4*4+3] = f2bf(s.w*d);
    }
  }
  __syncthreads();
  int quad = lane >> 4, ml = lane & 15;
  floatx4 acc[4];
  #pragma unroll
  for (int ct = 0; ct < 4; ct++) acc[ct] = (floatx4){0.f,0.f,0.f,0.f};
  #pragma unroll
  for (int k0 = 0; k0 < 64; k0 += 32){
    bf16x8 af = *(const bf16x8*)&Vs[16*w + ml][k0 + quad*8];
    #pragma unroll
    for (int ct = 0; ct < 4; ct++){
      bf16x8 bfr = *(const bf16x8*)&Ws[16*ct + ml][k0 + quad*8];
      acc[ct] = __builtin_amdgcn_mfma_f32_16x16x32_bf16(af, bfr, acc[ct], 0, 0, 0);
    }
  }
  int zoff = (p == 0) ? Z_ZF : (p == 1) ? Z_ZCF : (p == 2) ? Z_ZT : Z_ZCT;
  float val[4][4];
  #pragma unroll
  for (int ct = 0; ct < 4; ct++){
    int col = 16*ct + ml;
    #pragma unroll
    for (int r = 0; r < 4; r++){
      val[ct][r] = leaky(acc[ct][r] + bias[col]);
      int row = 16*w + quad*4 + r;
      Z6[(size_t)(i0+row)*384 + zoff + col] = val[ct][r];
    }
  }
  if (p == 1 || p == 3){
    int loff = (p == 1) ? Z_LCF : Z_LCT;
    #pragma unroll
    for (int r = 0; r < 4; r++){
      float s = val[0][r]*val[0][r] + val[1][r]*val[1][r]
              + val[2][r]*val[2][r] + val[3][r]*val[3][r];
      s += __shfl_xor(s, 1, 64); s += __shfl_xor(s, 2, 64);
      s += __shfl_xor(s, 4, 64); s += __shfl_xor(s, 8, 64);
      float m = sqrtf(s*(1.f/64.f)) + 1e-10f;
      int row = 16*w + quad*4 + r;
      #pragma unroll
      for (int ct = 0; ct < 4; ct++)
        Z6[(size_t)(i0+row)*384 + loff + 16*ct + ml] = val[ct][r]/m;
    }
  }
}

// ---------- attention + out projection: 1 row per wave ----------
__global__ __launch_bounds__(256) void k_att(const float* __restrict__ Z6,
    const float* __restrict__ Wag, const float* __restrict__ ba,
    const float* __restrict__ q, const float* __restrict__ W2g,
    const float* __restrict__ b2, float* __restrict__ out){
  __shared__ float Wal[64][65];
  __shared__ float W2l[448];
  __shared__ float zbuf[4][3][66];
  __shared__ float zagg[4][66];
  int tid = threadIdx.x, w = tid >> 6, t = tid & 63;
  for (int u = tid; u < 1024; u += 256){
    int r = u >> 4, c4 = (u & 15)*4;
    float4 f = ((const float4*)Wag)[u];
    Wal[r][c4+0]=f.x; Wal[r][c4+1]=f.y; Wal[r][c4+2]=f.z; Wal[r][c4+3]=f.w;
  }
  if (tid < 112) *(float4*)&W2l[tid*4] = ((const float4*)W2g)[tid];
  __syncthreads();
  int i = blockIdx.x*4 + w;
  const float* zr = Z6 + (size_t)i*384;
  float zf = zr[Z_ZF + t], zt = zr[Z_ZT + t];
  float zc = 0.5f*(zr[Z_ZCF + t] + zr[Z_ZCT + t]);
  zbuf[w][0][t] = zf; zbuf[w][1][t] = zt; zbuf[w][2][t] = zc;
  __syncthreads();
  float bav = ba[t], qv = q[t];
  float e[3];
  #pragma unroll
  for (int k = 0; k < 3; k++){
    float S = bav;
    #pragma unroll 8
    for (int c = 0; c < 64; c++) S += zbuf[w][k][c] * Wal[t][c];
    e[k] = waveRedSum(tanhf(S)*qv);
  }
  float mx = fmaxf(e[0], fmaxf(e[1], e[2]));
  float x0 = expf(e[0]-mx), x1 = expf(e[1]-mx), x2 = expf(e[2]-mx);
  float inv = 1.f/(x0+x1+x2);
  zagg[w][t] = x0*inv*zf + x1*inv*zt + x2*inv*zc;
  __syncthreads();
  if (t < OUTD){
    float acc = b2[t];
    #pragma unroll 8
    for (int c = 0; c < 64; c++) acc += zagg[w][c]*W2l[t*64 + c];
    out[(size_t)i*OUTD + t] = acc;
  }
}

// ---------- k_reduce: 5 products x RS row-splits, 64x64 tile GEMM each ----------
__global__ __launch_bounds__(256) void k_reduce(const float* __restrict__ Z6,
                                                float* __restrict__ redP,
                                                float* __restrict__ colP){
  __shared__ float sa[64][68];
  __shared__ float sb[64][68];
  int p = blockIdx.x >> 5;     // RS = 32
  int s = blockIdx.x & 31;
  int tid = threadIdx.x;
  const int aoffT[5] = {Z_ZT,  Z_ZF,  Z_LCF, Z_LCF, Z_LCT};
  const int boffT[5] = {Z_ZCT, Z_ZCF, Z_LCF, Z_LCT, Z_LCT};
  int aoff = aoffT[p], boff = boffT[p];
  int r0 = s * 64;
  {
    int row = tid >> 4, c4 = (tid & 15) * 4;
    #pragma unroll
    for (int rr = 0; rr < 64; rr += 16){
      const float* zr = Z6 + (size_t)(r0 + row + rr) * 384;
      *(float4*)&sa[row + rr][c4] = *(const float4*)&zr[aoff + c4];
      *(float4*)&sb[row + rr][c4] = *(const float4*)&zr[boff + c4];
    }
  }
  __syncthreads();
  int rg = tid >> 4, cg = tid & 15;
  float acc[4][4] = {};
  #pragma unroll 8
  for (int k = 0; k < 64; k++){
    float a[4], b[4];
    *(float4*)a = *(const float4*)&sa[k][rg*4];
    *(float4*)b = *(const float4*)&sb[k][cg*4];
    #pragma unroll
    for (int ii = 0; ii < 4; ii++)
      #pragma unroll
      for (int jj = 0; jj < 4; jj++)
        acc[ii][jj] += a[ii]*b[jj];
  }
  float* rp = redP + (size_t)blockIdx.x * 4096;
  #pragma unroll
  for (int ii = 0; ii < 4; ii++)
    *(float4*)&rp[(rg*4+ii)*64 + cg*4] =
      make_float4(acc[ii][0], acc[ii][1], acc[ii][2], acc[ii][3]);
  if (p < 2 && tid < 128){
    int t = tid & 63;
    float csum = 0.f;
    if (tid < 64){
      #pragma unroll 16
      for (int r = 0; r < 64; r++) csum += sa[r][t];
    } else {
      #pragma unroll 16
      for (int r = 0; r < 64; r++) csum += sb[r][t];
    }
    colP[((size_t)p*RS + s)*128 + tid] = csum;
  }
}

// ---------- sum partial slabs into red ----------
__global__ void k_combine(const float* __restrict__ redP,
                          const float* __restrict__ colP,
                          float* __restrict__ red){
  int idx = blockIdx.x*256 + threadIdx.x;
  if (idx < 20480){
    int p = idx >> 12, i = idx & 4095;
    float sum = 0.f;
    #pragma unroll 8
    for (int s = 0; s < RS; s++) sum += redP[((size_t)p*RS + s)*4096 + i];
    red[idx] = sum;
  } else if (idx < 20736){
    int j = idx - 20480;
    int p = j >> 7, rem = j & 127;
    float sum = 0.f;
    #pragma unroll 8
    for (int s = 0; s < RS; s++) sum += colP[((size_t)p*RS + s)*128 + rem];
    red[idx] = sum;
  }
}

// ---------- final scalars Lc, Ld ----------
__global__ void k_final(const float* __restrict__ red, float* __restrict__ out2){
  int tid = threadIdx.x;
  const float* Stc = red;
  const float* Sfc = red + 4096;
  const float* Cff = red + 8192;
  const float* Cft = red + 12288;
  const float* Ctt = red + 16384;
  const float* cst = red + 20480;
  const float* csct= red + 20544;
  const float* csf = red + 20608;
  const float* cscf= red + 20672;
  float sCff=0, sCft=0, sCtt=0, sM1=0, sM2=0;
  for (int u = tid*16; u < tid*16+16; u++){
    int d = u >> 6, e = u & 63;
    float m1 = Stc[u] - cst[d]*csct[e]*(1.f/2048.f);
    float m2 = Sfc[u] - csf[d]*cscf[e]*(1.f/2048.f);
    sM1 += m1*m1; sM2 += m2*m2;
    float cf = Cff[u], cx = Cft[u], ct = Ctt[u];
    sCff += cf*cf; sCft += cx*cx; sCtt += ct*ct;
  }
  __shared__ float rd[5][4];
  sCff = waveRedSum(sCff); sCft = waveRedSum(sCft); sCtt = waveRedSum(sCtt);
  sM1 = waveRedSum(sM1);   sM2 = waveRedSum(sM2);
  int w = tid >> 6, lane = tid & 63;
  if (lane == 0){ rd[0][w]=sCff; rd[1][w]=sCft; rd[2][w]=sCtt; rd[3][w]=sM1; rd[4][w]=sM2; }
  __syncthreads();
  if (tid == 0){
    float A0 = rd[0][0]+rd[0][1]+rd[0][2]+rd[0][3];
    float A1 = rd[1][0]+rd[1][1]+rd[1][2]+rd[1][3];
    float A2 = rd[2][0]+rd[2][1]+rd[2][2]+rd[2][3];
    float M1 = rd[3][0]+rd[3][1]+rd[3][2]+rd[3][3];
    float M2 = rd[4][0]+rd[4][1]+rd[4][2]+rd[4][3];
    out2[0] = (A0 - 2.f*A1 + A2) * (1.f/(2048.f*2048.f));
    out2[1] = (M1 + M2) * (1.f/(2047.f*2047.f));
  }
}

extern "C" void kernel_launch(void* const* d_in, const int* in_sizes, int n_in,
                              void* d_out, int out_size, void* d_ws, size_t ws_size,
                              hipStream_t stream) {
  const float* x   = (const float*)d_in[0];
  const float* A   = (const float*)d_in[1];
  const float* W1  = (const float*)d_in[3];
  const float* b1  = (const float*)d_in[4];
  const float* WF1 = (const float*)d_in[5];
  const float* bF1 = (const float*)d_in[6];
  const float* WF2 = (const float*)d_in[7];
  const float* bF2 = (const float*)d_in[8];
  const float* WT1 = (const float*)d_in[9];
  const float* bT1 = (const float*)d_in[10];
  const float* WT2 = (const float*)d_in[11];
  const float* bT2 = (const float*)d_in[12];
  const float* WC1 = (const float*)d_in[13];
  const float* bC1 = (const float*)d_in[14];
  const float* WC2 = (const float*)d_in[15];
  const float* bC2 = (const float*)d_in[16];
  const float* Wa  = (const float*)d_in[17];
  const float* ba  = (const float*)d_in[18];
  const float* q   = (const float*)d_in[19];
  const float* W2  = (const float*)d_in[20];
  const float* b2  = (const float*)d_in[21];
  float* out = (float*)d_out;

  float* W = (float*)d_ws;
  float* dA   = W;                      // N
  float* sq   = dA  + N;                // N
  float* hsum = sq  + N;                // N
  float* df   = hsum+ N;                // N
  int*   nidx = (int*)(df + N);         // N*4
  float* ncos = (float*)(nidx + N*4);   // N*4
  float* red  = ncos + N*4;             // 20736
  float* DOT  = red + 20736;            // N*N
  float* Z6   = DOT + (size_t)N*N;      // N*384
  float* Y1p  = Z6  + (size_t)N*384;    // S1*N*H
  float* Y2p  = Y1p + (size_t)S1*N*H;   // S2*N*128
  float* z1f  = Y2p + (size_t)S2*N*128; // N*H
  float* z1cf = z1f + N*H;              // N*H
  float* redP = z1cf+ N*H;              // 5*RS*4096 = 655360
  float* colP = redP+ 655360;           // 2*RS*128 = 8192
  unsigned short* Abf  = (unsigned short*)(colP + 8192);  // N*N bf16
  unsigned short* hsT  = Abf + (size_t)N*N;               // 64*N
  unsigned short* ZsT  = hsT + (size_t)H*N;               // 128*N
  unsigned short* hbHi = ZsT + (size_t)128*N;             // N*64
  unsigned short* hbLo = hbHi + (size_t)N*H;              // N*64

  k_prep<<<N, 256, 0, stream>>>(A, dA, Abf);
  k_h<<<128, 256, 0, stream>>>(x, W1, b1, dA, hbHi, hbLo, hsT, sq, hsum);
  k_gram2<<<dim3(16,16), 256, 0, stream>>>(hbHi, hbLo, DOT);
  k_topk<<<512, 256, 0, stream>>>(DOT, sq, hsum, nidx, ncos, df);

  k_mgemm<64><<<dim3(32,S1), 256, 0, stream>>>(Abf, hsT, Y1p, N/S1);
  k_z1m<<<dim3(32,4), 256, 0, stream>>>(hbHi, nidx, ncos, df, Y1p, dA,
                                        WF1, WC1, WT1, bF1, bC1, bT1,
                                        z1f, z1cf, ZsT);
  k_mgemm<128><<<dim3(32,S2), 256, 0, stream>>>(Abf, ZsT, Y2p, N/S2);
  k_z2m<<<dim3(32,4), 256, 0, stream>>>(z1f, z1cf, nidx, ncos, df, Y2p, dA,
                                        WF2, WC2, WT2, bF2, bC2, bT2, Z6);
  k_att<<<512, 256, 0, stream>>>(Z6, Wa, ba, q, W2, b2, out);
  k_reduce<<<5*RS, 256, 0, stream>>>(Z6, redP, colP);
  k_combine<<<81, 256, 0, stream>>>(redP, colP, red);
  k_final<<<1, 256, 0, stream>>>(red, out + (size_t)N*OUTD);
}